// Round 2
// baseline (4134.098 us; speedup 1.0000x reference)
//
#include <hip/hip_runtime.h>
#include <cstdint>
#include <cstddef>

// ---------------- problem constants ----------------
#define BB   4      // batch
#define CIN  64     // input channels
#define HD   128    // h_dim
#define NH   4      // heads
#define CHW  32     // channels per head
#define CB   8      // channels per branch
#define IMG  192    // H = W
#define SSH  4      // shift
#define NWS  24     // windows per side
#define NWIN 576    // windows total
#define KK   64     // window elements (8x8)
#define HWP  (IMG*IMG)

// per-batch buffer sizes (floats)
static const size_t NWINEL = (size_t)NH*NWIN*KK*CHW;  // 4,718,592 windowed q/k/v
static const size_t NSP    = (size_t)HD*HWP;          // 4,718,592 spatial 128ch
static const size_t NATTNB = (size_t)NH*NWIN*KK*KK;   // 9,437,184
static const size_t NATTNL = (size_t)NH*NWIN*64;      // 147,456
static const size_t NATTNG = (size_t)NH*KK*64;        // 16,384
static const size_t NATTNR = (size_t)NH*CB*KK*KK;     // 131,072

// ---------------- helpers ----------------
__device__ inline float wave_max(float v){
  #pragma unroll
  for (int s=1;s<64;s<<=1) v = fmaxf(v, __shfl_xor(v, s));
  return v;
}
__device__ inline float wave_sum(float v){
  #pragma unroll
  for (int s=1;s<64;s<<=1) v += __shfl_xor(v, s);
  return v;
}
__device__ inline float g8_max(float v){
  v = fmaxf(v, __shfl_xor(v,1)); v = fmaxf(v, __shfl_xor(v,2)); v = fmaxf(v, __shfl_xor(v,4));
  return v;
}
__device__ inline float g8_sum(float v){
  v += __shfl_xor(v,1); v += __shfl_xor(v,2); v += __shfl_xor(v,4);
  return v;
}
// Swin region id for an image coordinate (0..191): [0,184)=0, [184,188)=1, [188,192)=2
__device__ inline int regionc(int y){ return (y < IMG-8) ? 0 : ((y < IMG-4) ? 1 : 2); }

// per-batch windowed index: [h][n][i][c]  (c in 0..31)
__device__ inline size_t widx(int h,int n,int i,int c){
  return (((size_t)h*NWIN + n)*KK + i)*CHW + c;
}

// ---------------- K1: pointwise projections -> q/k/v (windowed, shifted) + u (spatial) ----------------
// grid: IMG*3 blocks (64 pixels of one row each), 256 threads
__global__ __launch_bounds__(256) void k1_proj(
    const float* __restrict__ x, const float* __restrict__ wquz, const float* __restrict__ wkv,
    float* __restrict__ qw, float* __restrict__ kw, float* __restrict__ vw, float* __restrict__ u,
    int bsel)
{
  __shared__ float xs[64][64];      // [c][px]
  __shared__ int pn[64], pi[64];
  int blk = blockIdx.x;
  int xc = blk % 3;
  int y  = blk/3;
  int x0 = xc*64;
  int t  = threadIdx.x;
  for (int l = t; l < 64*64; l += 256){
    int c = l >> 6, px = l & 63;
    xs[c][px] = x[((size_t)(bsel*CIN + c)*IMG + y)*IMG + x0 + px];
  }
  if (t < 64){
    int X   = x0 + t;
    int py  = (y + IMG - SSH) % IMG;   // window coordinate after roll(-4)
    int pxx = (X + IMG - SSH) % IMG;
    int hw = py >> 3, kh = py & 7, ww = pxx >> 3, kwd = pxx & 7;
    pn[t] = hw*NWS + ww;
    pi[t] = kh*8 + kwd;
  }
  __syncthreads();

  // each thread: o = t (q ch / u ch) and o = t+384 (k ch / v ch). z range [256,384) skipped.
  for (int oi = 0; oi < 2; ++oi){
    int o = (oi == 0) ? t : (t + 384);
    const float* wr = (o < 384) ? (wquz + (size_t)o*CIN) : (wkv + (size_t)(o-384)*CIN);
    for (int g = 0; g < 4; ++g){
      float acc[16];
      #pragma unroll
      for (int p = 0; p < 16; ++p) acc[p] = 0.f;
      for (int c = 0; c < 64; ++c){
        float wv2 = wr[c];
        #pragma unroll
        for (int p = 0; p < 16; ++p) acc[p] += wv2 * xs[c][g*16 + p];
      }
      #pragma unroll
      for (int p = 0; p < 16; ++p){
        int px = g*16 + p;
        float val = acc[p];
        if (o < 128){                       // q
          int h = o >> 5, c = o & 31;
          qw[widx(h,pn[px],pi[px],c)] = val;
        } else if (o < 256){                // u (spatial, per-batch)
          u[((size_t)(o-128)*IMG + y)*IMG + x0 + px] = val;
        } else if (o < 512){                // k
          int oc = o - 384; int h = oc >> 5, c = oc & 31;
          kw[widx(h,pn[px],pi[px],c)] = val;
        } else {                            // v
          int oc = o - 512; int h = oc >> 5, c = oc & 31;
          vw[widx(h,pn[px],pi[px],c)] = val;
        }
      }
    }
  }
}

// ---------------- K2: L2-normalizations in place on qw,kw (per batch) ----------------
// a) branch b: norm over c (ch 0..7), per (h,n,i)
__global__ __launch_bounds__(256) void k2a(float* qw, float* kw){
  const int total = NH*NWIN*KK;   // 147456
  int tid = blockIdx.x*256 + threadIdx.x;
  if (tid >= 2*total) return;
  float* p = ((tid < total) ? qw : kw) + (size_t)(tid % total)*CHW;
  float s = 0.f;
  #pragma unroll
  for (int c = 0; c < CB; ++c){ float v = p[c]; s += v*v; }
  float inv = 1.f / fmaxf(sqrtf(s), 1e-12f);
  #pragma unroll
  for (int c = 0; c < CB; ++c) p[c] *= inv;
}
// b) branch l: norm over i (kk=64), per (h,n,c), ch 8..15
__global__ __launch_bounds__(256) void k2b(float* qw, float* kw){
  const int total = NH*NWIN*CB;   // 18432
  int tid = blockIdx.x*256 + threadIdx.x;
  if (tid >= 2*total) return;
  int r = tid % total;
  int c = r % CB; int hn = r / CB;
  float* p = ((tid < total) ? qw : kw) + (size_t)hn*KK*CHW + 8 + c;
  float s = 0.f;
  for (int i = 0; i < KK; ++i){ float v = p[(size_t)i*CHW]; s += v*v; }
  float inv = 1.f / fmaxf(sqrtf(s), 1e-12f);
  for (int i = 0; i < KK; ++i) p[(size_t)i*CHW] *= inv;
}
// c) branches g,r: norm over n (576), per (h,i,c16), ch 16..31
__global__ __launch_bounds__(256) void k2c(float* qw, float* kw){
  const int total = NH*KK*16;     // 4096
  int tid = blockIdx.x*256 + threadIdx.x;
  if (tid >= 2*total) return;
  int r = tid % total;
  int c = r % 16; int rem = r / 16; int i = rem % KK; int h = rem / KK;
  float* p = ((tid < total) ? qw : kw) + ((size_t)h*NWIN*KK + i)*CHW + 16 + c;
  float s = 0.f;
  for (int n = 0; n < NWIN; ++n){ float v = p[(size_t)n*KK*CHW]; s += v*v; }
  float inv = 1.f / fmaxf(sqrtf(s), 1e-12f);
  for (int n = 0; n < NWIN; ++n) p[(size_t)n*KK*CHW] *= inv;
}

// ---------------- K3: attn_b = qb@kb^T * temp ----------------
// grid NH*NWIN, 64 threads (j)
__global__ __launch_bounds__(64) void k3_attnb(
    const float* __restrict__ qw, const float* __restrict__ kw,
    const float* __restrict__ temp, float* __restrict__ attnB)
{
  int n = blockIdx.x % NWIN; int h = blockIdx.x / NWIN;
  __shared__ float qs[KK][CB], ks2[KK][CB];
  int j = threadIdx.x;
  size_t base = widx(h,n,j,0);
  #pragma unroll
  for (int c = 0; c < CB; ++c){ qs[j][c] = qw[base + c]; ks2[j][c] = kw[base + c]; }
  __syncthreads();
  float kr[CB];
  #pragma unroll
  for (int c = 0; c < CB; ++c) kr[c] = ks2[j][c];
  float tmp = temp[0*NH + h];
  float* orow = attnB + ((size_t)(h*NWIN + n)*KK)*KK;
  for (int i = 0; i < KK; ++i){
    float a = 0.f;
    #pragma unroll
    for (int c = 0; c < CB; ++c) a += qs[i][c]*kr[c];
    orow[(size_t)i*KK + j] = a * tmp;
  }
}

// ---------------- K4: b-branch talk-conv + mask + softmax + PV, fused ----------------
// grid NWIN*KK (n,i), 256 threads = 4 waves (out-head) x 64 lanes (j)
__global__ __launch_bounds__(256) void k4_bconv(
    const float* __restrict__ attnB, const float* __restrict__ wtalk,
    const float* __restrict__ vw, float* __restrict__ outa)
{
  int n = blockIdx.x / KK, i = blockIdx.x % KK;
  int hw = n / NWS, ww = n % NWS;
  __shared__ float rows[NH][9][KK];
  __shared__ float wt[NH*NH*9];
  int t = threadIdx.x;
  if (t < NH*NH*9) wt[t] = wtalk[t];
  for (int l = t; l < NH*9*KK; l += 256){
    int h = l / (9*KK); int nb = (l / KK) % 9; int j = l & 63;
    int dy = nb/3 - 1, dx = nb%3 - 1;
    int hw2 = hw + dy, ww2 = ww + dx;
    float v = 0.f;
    if (hw2 >= 0 && hw2 < NWS && ww2 >= 0 && ww2 < NWS)
      v = attnB[((size_t)(h*NWIN + hw2*NWS + ww2)*KK + i)*KK + j];
    rows[h][nb][j] = v;
  }
  __syncthreads();
  int wv = t >> 6;   // output head after talking
  int j  = t & 63;
  float a = 0.f;
  #pragma unroll
  for (int h = 0; h < NH; ++h)
    #pragma unroll
    for (int nb = 0; nb < 9; ++nb)
      a += wt[(wv*NH + h)*9 + nb] * rows[h][nb][j];
  // shifted-window mask (analytic)
  int kh = i >> 3, kwd = i & 7;
  int cntI = regionc(hw*8 + kh)*3 + regionc(ww*8 + kwd);
  int cntJ = regionc(hw*8 + (j>>3))*3 + regionc(ww*8 + (j&7));
  if (cntI != cntJ) a -= 100.f;
  // softmax over j (full wave)
  float m = wave_max(a);
  float e = __expf(a - m);
  float p = e / wave_sum(e);
  // PV: out[c] = sum_j p[j]*vb[j,c]
  size_t vbase = widx(wv, n, j, 0);
  float pv[CB];
  #pragma unroll
  for (int c = 0; c < CB; ++c) pv[c] = p * vw[vbase + c];
  #pragma unroll
  for (int c = 0; c < CB; ++c) pv[c] = wave_sum(pv[c]);
  if (j == 0){
    int Y = (hw*8 + kh + SSH) % IMG;
    int X = (ww*8 + kwd + SSH) % IMG;
    #pragma unroll
    for (int c = 0; c < CB; ++c)
      outa[((size_t)(wv*CB + c)*IMG + Y)*IMG + X] = pv[c];
  }
}

// ---------------- K5a: attn_l = ql^T@kl * temp ----------------
// grid NH*NWIN, 64 threads (c,d)
__global__ __launch_bounds__(64) void k5a(
    const float* __restrict__ qw, const float* __restrict__ kw,
    const float* __restrict__ temp, float* __restrict__ attnL)
{
  int n = blockIdx.x % NWIN; int h = blockIdx.x / NWIN;
  __shared__ float qs[KK][CB], ks2[KK][CB];
  int t = threadIdx.x;
  size_t base = ((size_t)h*NWIN + n)*KK*CHW + (size_t)t*CHW + 8;
  #pragma unroll
  for (int c = 0; c < CB; ++c){ qs[t][c] = qw[base + c]; ks2[t][c] = kw[base + c]; }
  __syncthreads();
  int c = t >> 3, d = t & 7;
  float a = 0.f;
  for (int i = 0; i < KK; ++i) a += qs[i][c]*ks2[i][d];
  attnL[(size_t)h*NWIN*64 + (size_t)n*64 + t] = a * temp[NH + h];
}

// ---------------- K5b: l-branch talk-conv + softmax(d) + PV, fused ----------------
// grid NWIN, 256 threads
__global__ __launch_bounds__(256) void k5b(
    const float* __restrict__ attnL, const float* __restrict__ wtalk,
    const float* __restrict__ vw, float* __restrict__ outa)
{
  int n = blockIdx.x;
  int hw = n/NWS, ww = n%NWS;
  __shared__ float rows[NH][9][64];
  __shared__ float wt[NH*NH*9];
  __shared__ float P[NH][CB][CB];
  int t = threadIdx.x;
  if (t < NH*NH*9) wt[t] = wtalk[t];
  for (int l = t; l < NH*9*64; l += 256){
    int h = l/(9*64); int nb = (l/64)%9; int cd = l & 63;
    int dy = nb/3-1, dx = nb%3-1; int hw2 = hw+dy, ww2 = ww+dx;
    float v = 0.f;
    if (hw2>=0 && hw2<NWS && ww2>=0 && ww2<NWS)
      v = attnL[((size_t)h*NWIN + hw2*NWS + ww2)*64 + cd];
    rows[h][nb][cd] = v;
  }
  __syncthreads();
  int tt = t >> 6; int cd = t & 63; int c = cd >> 3, d = cd & 7;
  float a = 0.f;
  #pragma unroll
  for (int h = 0; h < NH; ++h)
    #pragma unroll
    for (int nb = 0; nb < 9; ++nb)
      a += wt[(tt*NH + h)*9 + nb] * rows[h][nb][cd];
  float m = g8_max(a);
  float e = __expf(a - m);
  P[tt][c][d] = e / g8_sum(e);
  __syncthreads();
  // PV: thread (tt, i): out[c] = sum_d P[tt][c][d]*vl[i][d]
  int i = t & 63;
  size_t vbase = widx(tt, n, i, 8);
  float vl[CB];
  #pragma unroll
  for (int d2 = 0; d2 < CB; ++d2) vl[d2] = vw[vbase + d2];
  int kh = i>>3, kwd = i&7;
  int Y = (hw*8+kh+SSH)%IMG, X = (ww*8+kwd+SSH)%IMG;
  #pragma unroll
  for (int c2 = 0; c2 < CB; ++c2){
    float o = 0.f;
    #pragma unroll
    for (int d2 = 0; d2 < CB; ++d2) o += P[tt][c2][d2]*vl[d2];
    outa[((size_t)(32 + tt*CB + c2)*IMG + Y)*IMG + X] = o;
  }
}

// ---------------- K6a: attn_g[h,i,c,d] = sum_n qg*kg * temp ----------------
// grid NH*KK, 64 threads (c,d)
__global__ __launch_bounds__(64) void k6a(
    const float* __restrict__ qw, const float* __restrict__ kw,
    const float* __restrict__ temp, float* __restrict__ attnG)
{
  int i = blockIdx.x % KK; int h = blockIdx.x / KK;
  __shared__ float qs[64][CB], ks2[64][CB];
  int t = threadIdx.x; int c = t >> 3, d = t & 7;
  float a = 0.f;
  for (int n0 = 0; n0 < NWIN; n0 += 64){
    __syncthreads();
    size_t base = ((size_t)h*NWIN + n0 + t)*KK*CHW + (size_t)i*CHW + 16;
    #pragma unroll
    for (int cc = 0; cc < CB; ++cc){ qs[t][cc] = qw[base+cc]; ks2[t][cc] = kw[base+cc]; }
    __syncthreads();
    for (int l = 0; l < 64; ++l) a += qs[l][c]*ks2[l][d];
  }
  attnG[(size_t)h*KK*64 + (size_t)i*64 + t] = a * temp[2*NH + h];
}

// ---------------- K6b: g talking + softmax(d) ----------------
// grid NH*KK (t2,l), 64 threads (c,d)
__global__ __launch_bounds__(64) void k6b(
    const float* __restrict__ attnG, const float* __restrict__ gtalk, float* __restrict__ attnGp)
{
  int l = blockIdx.x % KK; int t2 = blockIdx.x / KK;
  int cd = threadIdx.x;
  float a = 0.f;
  for (int h = 0; h < NH; ++h)
    for (int k = 0; k < KK; ++k)
      a += gtalk[((size_t)(h*KK + k)*KK + l)*NH + t2] * attnG[((size_t)h*KK + k)*64 + cd];
  float m = g8_max(a);
  float e = __expf(a - m);
  attnGp[((size_t)t2*KK + l)*64 + cd] = e / g8_sum(e);
}

// ---------------- K6c: out_g PV ----------------
// grid NH*NWIN, 256 threads
__global__ __launch_bounds__(256) void k6c(
    const float* __restrict__ attnGp, const float* __restrict__ vw, float* __restrict__ outa)
{
  int n = blockIdx.x % NWIN; int t2 = blockIdx.x / NWIN;
  __shared__ float P[KK*64];
  int t = threadIdx.x;
  for (int l = t; l < KK*64; l += 256) P[l] = attnGp[(size_t)t2*KK*64 + l];
  __syncthreads();
  int i = t >> 2; int c0 = (t & 3)*2;
  size_t vbase = widx(t2, n, i, 16);
  float vg[8];
  #pragma unroll
  for (int d = 0; d < 8; ++d) vg[d] = vw[vbase + d];
  int hw = n/NWS, ww = n%NWS; int kh = i>>3, kwd = i&7;
  int Y = (hw*8+kh+SSH)%IMG, X = (ww*8+kwd+SSH)%IMG;
  for (int c = c0; c < c0+2; ++c){
    float o = 0.f;
    #pragma unroll
    for (int d = 0; d < 8; ++d) o += P[(i*8 + c)*8 + d]*vg[d];
    outa[((size_t)(64 + t2*CB + c)*IMG + Y)*IMG + X] = o;
  }
}

// ---------------- K7a: attn_r[h,c,i,j] = sum_n qr*kr * temp ----------------
// grid NH*CB, 256 threads
__global__ __launch_bounds__(256) void k7a(
    const float* __restrict__ qw, const float* __restrict__ kw,
    const float* __restrict__ temp, float* __restrict__ attnR)
{
  int c = blockIdx.x % CB; int h = blockIdx.x / CB;
  __shared__ float qs[64][64];   // [n][i]
  __shared__ float ks2[64][64];  // [n][j]
  int t = threadIdx.x;
  int j = t & 63; int ig = t >> 6;
  float acc[16];
  #pragma unroll
  for (int p = 0; p < 16; ++p) acc[p] = 0.f;
  for (int n0 = 0; n0 < NWIN; n0 += 64){
    __syncthreads();
    for (int l = t; l < 4096; l += 256){
      int nn = l >> 6, ii = l & 63;
      size_t base = ((size_t)h*NWIN + n0 + nn)*KK*CHW + (size_t)ii*CHW + 24 + c;
      qs[nn][ii] = qw[base]; ks2[nn][ii] = kw[base];
    }
    __syncthreads();
    for (int nn = 0; nn < 64; ++nn){
      float kv = ks2[nn][j];
      #pragma unroll
      for (int p = 0; p < 16; ++p) acc[p] += qs[nn][ig*16+p]*kv;
    }
  }
  float tmp = temp[3*NH + h];
  #pragma unroll
  for (int p = 0; p < 16; ++p){
    int i = ig*16 + p;
    attnR[(((size_t)h*CB + c)*KK + i)*KK + j] = acc[p]*tmp;
  }
}

// ---------------- K7b: r talking + softmax(j) ----------------
// grid NH*CB (t2,d), 256 threads
__global__ __launch_bounds__(256) void k7b(
    const float* __restrict__ attnR, const float* __restrict__ rtalk, float* __restrict__ attnRp)
{
  int d = blockIdx.x % CB; int t2 = blockIdx.x / CB;
  __shared__ float S[64][64];
  __shared__ float wr2[32];
  int t = threadIdx.x;
  if (t < 32){ int h = t >> 3, c = t & 7; wr2[t] = rtalk[((size_t)(h*CB + c)*CB + d)*NH + t2]; }
  __syncthreads();
  int j = t & 63; int ig = t >> 6;
  float acc[16];
  #pragma unroll
  for (int p = 0; p < 16; ++p) acc[p] = 0.f;
  for (int hc = 0; hc < 32; ++hc){
    int h = hc >> 3, c = hc & 7;
    float w = wr2[hc];
    const float* Ar = attnR + ((size_t)h*CB + c)*KK*KK;
    #pragma unroll
    for (int p = 0; p < 16; ++p) acc[p] += w * Ar[(size_t)(ig*16+p)*KK + j];
  }
  #pragma unroll
  for (int p = 0; p < 16; ++p) S[ig*16+p][j] = acc[p];
  __syncthreads();
  for (int r = ig; r < 64; r += 4){
    float a = S[r][j];
    float m = wave_max(a);
    float e = __expf(a - m);
    attnRp[(((size_t)t2*CB + d)*KK + r)*KK + j] = e / wave_sum(e);
  }
}

// ---------------- K7c: out_r PV ----------------
// grid NH*NWIN, 256 threads
__global__ __launch_bounds__(256) void k7c(
    const float* __restrict__ attnRp, const float* __restrict__ vw, float* __restrict__ outa)
{
  int n = blockIdx.x % NWIN; int t2 = blockIdx.x / NWIN;
  __shared__ float vr[KK][CB];
  int t = threadIdx.x;
  for (int l = t; l < KK*CB; l += 256){
    int j = l >> 3, c = l & 7;
    vr[j][c] = vw[widx(t2, n, j, 24 + c)];
  }
  __syncthreads();
  int i = t & 63; int cg = t >> 6;
  int hw = n/NWS, ww = n%NWS; int kh = i>>3, kwd = i&7;
  int Y = (hw*8+kh+SSH)%IMG, X = (ww*8+kwd+SSH)%IMG;
  for (int c = cg*2; c < cg*2+2; ++c){
    const float* Pr = attnRp + (((size_t)t2*CB + c)*KK + i)*KK;
    float o = 0.f;
    for (int j = 0; j < KK; ++j) o += Pr[j]*vr[j][c];
    outa[((size_t)(96 + t2*CB + c)*IMG + Y)*IMG + X] = o;
  }
}

// ---------------- K8: channel means + sca ----------------
__global__ __launch_bounds__(256) void k8_mean(const float* __restrict__ outa, float* __restrict__ meanb){
  int ch = blockIdx.x;
  const float* p = outa + (size_t)ch*HWP;
  float s = 0.f;
  for (int l = threadIdx.x; l < HWP; l += 256) s += p[l];
  __shared__ float red[256];
  red[threadIdx.x] = s; __syncthreads();
  for (int k = 128; k > 0; k >>= 1){
    if (threadIdx.x < k) red[threadIdx.x] += red[threadIdx.x + k];
    __syncthreads();
  }
  if (threadIdx.x == 0) meanb[ch] = red[0] / (float)HWP;
}
__global__ __launch_bounds__(128) void k8b(const float* __restrict__ meanb, const float* __restrict__ scaw,
                                           const float* __restrict__ scab, float* __restrict__ svec){
  int o = threadIdx.x;
  float s = scab[o];
  for (int c = 0; c < HD; ++c) s += scaw[(size_t)o*HD + c]*meanb[c];
  svec[o] = s;
}

// ---------------- K9: epilogue: project(out*s) + dwconv(u), * z, project_out ----------------
// grid IMG*12 (16 pixels each), 128 threads
__global__ __launch_bounds__(128) void k9_final(
    const float* __restrict__ outa, const float* __restrict__ svec,
    const float* __restrict__ projw, const float* __restrict__ projow,
    const float* __restrict__ wquz, const float* __restrict__ x,
    const float* __restrict__ u, const float* __restrict__ dww, float* __restrict__ dout,
    int bsel)
{
  int blk = blockIdx.x;
  int xc = blk % 12; int y = blk/12;
  int x0 = xc*16;
  __shared__ float tv[HD][16];
  __shared__ float xs[CIN][16];
  __shared__ float pz[HD][16];
  int t = threadIdx.x;
  for (int l = t; l < HD*16; l += 128){
    int ch = l >> 4, px = l & 15;
    tv[ch][px] = outa[((size_t)ch*IMG + y)*IMG + x0 + px] * svec[ch];
  }
  for (int l = t; l < CIN*16; l += 128){
    int c = l >> 4, px = l & 15;
    xs[c][px] = x[((size_t)(bsel*CIN+c)*IMG + y)*IMG + x0 + px];
  }
  __syncthreads();
  int o = t;
  float pacc[16];
  #pragma unroll
  for (int p = 0; p < 16; ++p) pacc[p] = 0.f;
  for (int c = 0; c < HD; ++c){
    float w = projw[(size_t)o*HD + c];
    #pragma unroll
    for (int p = 0; p < 16; ++p) pacc[p] += w*tv[c][p];
  }
  // depthwise 3x3 on u, channel o
  float dwk[9];
  #pragma unroll
  for (int k = 0; k < 9; ++k) dwk[k] = dww[o*9 + k];
  for (int p = 0; p < 16; ++p){
    int X = x0 + p; float dv = 0.f;
    #pragma unroll
    for (int dy = -1; dy <= 1; ++dy){
      int yy = y + dy; if (yy < 0 || yy >= IMG) continue;
      #pragma unroll
      for (int dx = -1; dx <= 1; ++dx){
        int xx = X + dx; if (xx < 0 || xx >= IMG) continue;
        dv += dwk[(dy+1)*3 + dx+1]*u[((size_t)o*IMG + yy)*IMG + xx];
      }
    }
    pacc[p] += dv;
  }
  // z recompute: z[o] = dot(wquz[256+o], x-pixel)
  float zacc[16];
  #pragma unroll
  for (int p = 0; p < 16; ++p) zacc[p] = 0.f;
  for (int c = 0; c < CIN; ++c){
    float w = wquz[(size_t)(256+o)*CIN + c];
    #pragma unroll
    for (int p = 0; p < 16; ++p) zacc[p] += w*xs[c][p];
  }
  #pragma unroll
  for (int p = 0; p < 16; ++p) pz[o][p] = pacc[p]*zacc[p];
  __syncthreads();
  int oo = t & 63; int ph = t >> 6;
  float oacc[8];
  #pragma unroll
  for (int p = 0; p < 8; ++p) oacc[p] = 0.f;
  for (int c = 0; c < HD; ++c){
    float w = projow[(size_t)oo*HD + c];
    #pragma unroll
    for (int p = 0; p < 8; ++p) oacc[p] += w*pz[c][ph*8 + p];
  }
  #pragma unroll
  for (int p = 0; p < 8; ++p)
    dout[((size_t)(bsel*64+oo)*IMG + y)*IMG + x0 + ph*8 + p] = oacc[p];
}

// ---------------- launch ----------------
extern "C" void kernel_launch(void* const* d_in, const int* in_sizes, int n_in,
                              void* d_out, int out_size, void* d_ws, size_t ws_size,
                              hipStream_t stream)
{
  const float* x     = (const float*)d_in[0];
  const float* wquz  = (const float*)d_in[1];
  const float* wkv   = (const float*)d_in[2];
  const float* temp  = (const float*)d_in[3];
  const float* rtalk = (const float*)d_in[4];
  const float* gtalk = (const float*)d_in[5];
  const float* btw   = (const float*)d_in[6];
  const float* ltw   = (const float*)d_in[7];
  const float* dww   = (const float*)d_in[8];
  const float* projw = (const float*)d_in[9];
  const float* projow= (const float*)d_in[10];
  const float* scaw  = (const float*)d_in[11];
  const float* scab  = (const float*)d_in[12];
  float* dout = (float*)d_out;

  // per-batch workspace (~134 MB total)
  float* ws = (float*)d_ws;
  float* qw     = ws;                 // NWINEL
  float* kw     = qw + NWINEL;        // NWINEL
  float* vw     = kw + NWINEL;        // NWINEL
  float* u      = vw + NWINEL;        // NSP
  float* outa   = u + NSP;            // NSP
  float* attnB  = outa + NSP;         // NATTNB
  float* attnL  = attnB + NATTNB;     // NATTNL
  float* attnGbuf = attnL + NATTNL;   // NATTNG
  float* attnGp = attnGbuf + NATTNG;  // NATTNG
  float* attnR  = attnGp + NATTNG;    // NATTNR
  float* attnRp = attnR + NATTNR;     // NATTNR
  float* meanb  = attnRp + NATTNR;    // 128
  float* svec   = meanb + 128;        // 128

  for (int b = 0; b < BB; ++b){
    k1_proj<<<IMG*3, 256, 0, stream>>>(x, wquz, wkv, qw, kw, vw, u, b);

    k2a<<<(2*NH*NWIN*KK + 255)/256, 256, 0, stream>>>(qw, kw);
    k2b<<<(2*NH*NWIN*CB + 255)/256, 256, 0, stream>>>(qw, kw);
    k2c<<<(2*NH*KK*16 + 255)/256, 256, 0, stream>>>(qw, kw);

    k3_attnb<<<NH*NWIN, 64, 0, stream>>>(qw, kw, temp, attnB);
    k4_bconv<<<NWIN*KK, 256, 0, stream>>>(attnB, btw, vw, outa);

    k5a<<<NH*NWIN, 64, 0, stream>>>(qw, kw, temp, attnL);
    k5b<<<NWIN, 256, 0, stream>>>(attnL, ltw, vw, outa);

    k6a<<<NH*KK, 64, 0, stream>>>(qw, kw, temp, attnGbuf);
    k6b<<<NH*KK, 64, 0, stream>>>(attnGbuf, gtalk, attnGp);
    k6c<<<NH*NWIN, 256, 0, stream>>>(attnGp, vw, outa);

    k7a<<<NH*CB, 256, 0, stream>>>(qw, kw, temp, attnR);
    k7b<<<NH*CB, 256, 0, stream>>>(attnR, rtalk, attnRp);
    k7c<<<NH*NWIN, 256, 0, stream>>>(attnRp, vw, outa);

    k8_mean<<<HD, 256, 0, stream>>>(outa, meanb);
    k8b<<<1, 128, 0, stream>>>(meanb, scaw, scab, svec);

    k9_final<<<IMG*12, 128, 0, stream>>>(outa, svec, projw, projow, wquz, x, u, dww, dout, b);
  }
}

// Round 3
// 3309.880 us; speedup vs baseline: 1.2490x; 1.2490x over previous
//
#include <hip/hip_runtime.h>
#include <cstdint>
#include <cstddef>

// ---------------- problem constants ----------------
#define BB   4      // batch
#define CIN  64     // input channels
#define HD   128    // h_dim
#define NH   4      // heads
#define CHW  32     // channels per head
#define CB   8      // channels per branch
#define IMG  192    // H = W
#define SSH  4      // shift
#define NWS  24     // windows per side
#define NWIN 576    // windows total
#define KK   64     // window elements (8x8)
#define HWP  (IMG*IMG)

// per-batch buffer sizes (floats)
static const size_t NWINEL = (size_t)NH*NWIN*KK*CHW;  // 4,718,592 windowed q/k/v
static const size_t NSP    = (size_t)HD*HWP;          // 4,718,592 spatial 128ch
static const size_t NATTNB = (size_t)NH*NWIN*KK*KK;   // 9,437,184
static const size_t NATTNL = (size_t)NH*NWIN*64;      // 147,456
static const size_t NATTNG = (size_t)NH*KK*64;        // 16,384
static const size_t NATTNR = (size_t)NH*CB*KK*KK;     // 131,072

// ---------------- helpers ----------------
__device__ inline float wave_max(float v){
  #pragma unroll
  for (int s=1;s<64;s<<=1) v = fmaxf(v, __shfl_xor(v, s));
  return v;
}
__device__ inline float wave_sum(float v){
  #pragma unroll
  for (int s=1;s<64;s<<=1) v += __shfl_xor(v, s);
  return v;
}
__device__ inline float g8_max(float v){
  v = fmaxf(v, __shfl_xor(v,1)); v = fmaxf(v, __shfl_xor(v,2)); v = fmaxf(v, __shfl_xor(v,4));
  return v;
}
__device__ inline float g8_sum(float v){
  v += __shfl_xor(v,1); v += __shfl_xor(v,2); v += __shfl_xor(v,4);
  return v;
}
// Swin region id for an image coordinate (0..191): [0,184)=0, [184,188)=1, [188,192)=2
__device__ inline int regionc(int y){ return (y < IMG-8) ? 0 : ((y < IMG-4) ? 1 : 2); }

// per-batch windowed index: [h][n][i][c]  (c in 0..31)
__device__ inline size_t widx(int h,int n,int i,int c){
  return (((size_t)h*NWIN + n)*KK + i)*CHW + c;
}

// ---------------- K1: pointwise projections -> q/k/v (windowed, shifted) + u,z (spatial) ----------------
// grid: IMG blocks (one image row each), 256 threads
__global__ __launch_bounds__(256) void k1_proj(
    const float* __restrict__ x, const float* __restrict__ wquz, const float* __restrict__ wkv,
    float* __restrict__ qw, float* __restrict__ kw, float* __restrict__ vw,
    float* __restrict__ u, float* __restrict__ zbuf, int bsel)
{
  __shared__ float xs[64][196];     // [c][px], padded
  __shared__ int pn[192], pi[192];
  int y = blockIdx.x;
  int t = threadIdx.x;
  // stage the full row of x: 64 ch x 192 px
  for (int idx = t; idx < 64*48; idx += 256){
    int c = idx / 48, px4 = (idx % 48)*4;
    float4 v = *(const float4*)&x[((size_t)(bsel*CIN + c)*IMG + y)*IMG + px4];
    xs[c][px4] = v.x; xs[c][px4+1] = v.y; xs[c][px4+2] = v.z; xs[c][px4+3] = v.w;
  }
  if (t < 192){
    int py  = (y + IMG - SSH) % IMG;   // window coordinate after roll(-4)
    int pxx = (t + IMG - SSH) % IMG;
    int hw = py >> 3, kh = py & 7, ww = pxx >> 3, kwd = pxx & 7;
    pn[t] = hw*NWS + ww;
    pi[t] = kh*8 + kwd;
  }
  __syncthreads();

  // oi=0: o=t (q 0..127, u 128..255); oi=1: o=t+384 (k,v); oi=2 (t<128): o=t+256 (z)
  for (int oi = 0; oi < 3; ++oi){
    if (oi == 2 && t >= 128) break;
    int o = (oi == 0) ? t : (oi == 1 ? t + 384 : t + 256);
    const float* wr = (o < 384) ? (wquz + (size_t)o*CIN) : (wkv + (size_t)(o-384)*CIN);
    for (int g = 0; g < 12; ++g){
      float acc[16];
      #pragma unroll
      for (int p = 0; p < 16; ++p) acc[p] = 0.f;
      for (int cc = 0; cc < 64; cc += 4){
        float4 w4 = *(const float4*)(wr + cc);
        #pragma unroll
        for (int p = 0; p < 16; ++p){
          acc[p] += w4.x * xs[cc][g*16 + p];
          acc[p] += w4.y * xs[cc+1][g*16 + p];
          acc[p] += w4.z * xs[cc+2][g*16 + p];
          acc[p] += w4.w * xs[cc+3][g*16 + p];
        }
      }
      #pragma unroll
      for (int p = 0; p < 16; ++p){
        int px = g*16 + p;
        float val = acc[p];
        if (o < 128){                       // q
          int h = o >> 5, c = o & 31;
          qw[widx(h,pn[px],pi[px],c)] = val;
        } else if (o < 256){                // u (spatial)
          u[((size_t)(o-128)*IMG + y)*IMG + px] = val;
        } else if (o < 384){                // z (spatial)
          zbuf[((size_t)(o-256)*IMG + y)*IMG + px] = val;
        } else if (o < 512){                // k
          int oc = o - 384; int h = oc >> 5, c = oc & 31;
          kw[widx(h,pn[px],pi[px],c)] = val;
        } else {                            // v
          int oc = o - 512; int h = oc >> 5, c = oc & 31;
          vw[widx(h,pn[px],pi[px],c)] = val;
        }
      }
    }
  }
}

// ---------------- K2: L2-normalizations in place on qw,kw (per batch) ----------------
__global__ __launch_bounds__(256) void k2a(float* qw, float* kw){
  const int total = NH*NWIN*KK;
  int tid = blockIdx.x*256 + threadIdx.x;
  if (tid >= 2*total) return;
  float* p = ((tid < total) ? qw : kw) + (size_t)(tid % total)*CHW;
  float s = 0.f;
  #pragma unroll
  for (int c = 0; c < CB; ++c){ float v = p[c]; s += v*v; }
  float inv = 1.f / fmaxf(sqrtf(s), 1e-12f);
  #pragma unroll
  for (int c = 0; c < CB; ++c) p[c] *= inv;
}
__global__ __launch_bounds__(256) void k2b(float* qw, float* kw){
  const int total = NH*NWIN*CB;
  int tid = blockIdx.x*256 + threadIdx.x;
  if (tid >= 2*total) return;
  int r = tid % total;
  int c = r % CB; int hn = r / CB;
  float* p = ((tid < total) ? qw : kw) + (size_t)hn*KK*CHW + 8 + c;
  float s = 0.f;
  for (int i = 0; i < KK; ++i){ float v = p[(size_t)i*CHW]; s += v*v; }
  float inv = 1.f / fmaxf(sqrtf(s), 1e-12f);
  for (int i = 0; i < KK; ++i) p[(size_t)i*CHW] *= inv;
}
__global__ __launch_bounds__(256) void k2c(float* qw, float* kw){
  const int total = NH*KK*16;
  int tid = blockIdx.x*256 + threadIdx.x;
  if (tid >= 2*total) return;
  int r = tid % total;
  int c = r % 16; int rem = r / 16; int i = rem % KK; int h = rem / KK;
  float* p = ((tid < total) ? qw : kw) + ((size_t)h*NWIN*KK + i)*CHW + 16 + c;
  float s = 0.f;
  for (int n = 0; n < NWIN; ++n){ float v = p[(size_t)n*KK*CHW]; s += v*v; }
  float inv = 1.f / fmaxf(sqrtf(s), 1e-12f);
  for (int n = 0; n < NWIN; ++n) p[(size_t)n*KK*CHW] *= inv;
}

// ---------------- K3: attn_b = qb@kb^T * temp ----------------
__global__ __launch_bounds__(64) void k3_attnb(
    const float* __restrict__ qw, const float* __restrict__ kw,
    const float* __restrict__ temp, float* __restrict__ attnB)
{
  int n = blockIdx.x % NWIN; int h = blockIdx.x / NWIN;
  __shared__ float qs[KK][CB], ks2[KK][CB];
  int j = threadIdx.x;
  size_t base = widx(h,n,j,0);
  #pragma unroll
  for (int c = 0; c < CB; ++c){ qs[j][c] = qw[base + c]; ks2[j][c] = kw[base + c]; }
  __syncthreads();
  float kr[CB];
  #pragma unroll
  for (int c = 0; c < CB; ++c) kr[c] = ks2[j][c];
  float tmp = temp[0*NH + h];
  float* orow = attnB + ((size_t)(h*NWIN + n)*KK)*KK;
  for (int i = 0; i < KK; ++i){
    float a = 0.f;
    #pragma unroll
    for (int c = 0; c < CB; ++c) a += qs[i][c]*kr[c];
    orow[(size_t)i*KK + j] = a * tmp;
  }
}

// ---------------- K4: b-branch talk-conv + mask + softmax + PV, fused ----------------
// grid KK*NWIN with i SLOW (consecutive blocks sweep n => L2-resident 9-neighborhood)
__global__ __launch_bounds__(256) void k4_bconv(
    const float* __restrict__ attnB, const float* __restrict__ wtalk,
    const float* __restrict__ vw, float* __restrict__ outa)
{
  int i = blockIdx.x / NWIN, n = blockIdx.x % NWIN;
  int hw = n / NWS, ww = n % NWS;
  __shared__ float rows[NH][9][KK];
  __shared__ float wt[NH*NH*9];
  int t = threadIdx.x;
  if (t < NH*NH*9) wt[t] = wtalk[t];
  for (int l = t; l < NH*9*KK; l += 256){
    int h = l / (9*KK); int nb = (l / KK) % 9; int j = l & 63;
    int dy = nb/3 - 1, dx = nb%3 - 1;
    int hw2 = hw + dy, ww2 = ww + dx;
    float v = 0.f;
    if (hw2 >= 0 && hw2 < NWS && ww2 >= 0 && ww2 < NWS)
      v = attnB[((size_t)(h*NWIN + hw2*NWS + ww2)*KK + i)*KK + j];
    rows[h][nb][j] = v;
  }
  __syncthreads();
  int wv = t >> 6;   // output head after talking
  int j  = t & 63;
  float a = 0.f;
  #pragma unroll
  for (int h = 0; h < NH; ++h)
    #pragma unroll
    for (int nb = 0; nb < 9; ++nb)
      a += wt[(wv*NH + h)*9 + nb] * rows[h][nb][j];
  int kh = i >> 3, kwd = i & 7;
  int cntI = regionc(hw*8 + kh)*3 + regionc(ww*8 + kwd);
  int cntJ = regionc(hw*8 + (j>>3))*3 + regionc(ww*8 + (j&7));
  if (cntI != cntJ) a -= 100.f;
  float m = wave_max(a);
  float e = __expf(a - m);
  float p = e / wave_sum(e);
  size_t vbase = widx(wv, n, j, 0);
  float pv[CB];
  #pragma unroll
  for (int c = 0; c < CB; ++c) pv[c] = p * vw[vbase + c];
  #pragma unroll
  for (int c = 0; c < CB; ++c) pv[c] = wave_sum(pv[c]);
  if (j == 0){
    int Y = (hw*8 + kh + SSH) % IMG;
    int X = (ww*8 + kwd + SSH) % IMG;
    #pragma unroll
    for (int c = 0; c < CB; ++c)
      outa[((size_t)(wv*CB + c)*IMG + Y)*IMG + X] = pv[c];
  }
}

// ---------------- K5a: attn_l = ql^T@kl * temp ----------------
__global__ __launch_bounds__(64) void k5a(
    const float* __restrict__ qw, const float* __restrict__ kw,
    const float* __restrict__ temp, float* __restrict__ attnL)
{
  int n = blockIdx.x % NWIN; int h = blockIdx.x / NWIN;
  __shared__ float qs[KK][CB], ks2[KK][CB];
  int t = threadIdx.x;
  size_t base = ((size_t)h*NWIN + n)*KK*CHW + (size_t)t*CHW + 8;
  #pragma unroll
  for (int c = 0; c < CB; ++c){ qs[t][c] = qw[base + c]; ks2[t][c] = kw[base + c]; }
  __syncthreads();
  int c = t >> 3, d = t & 7;
  float a = 0.f;
  for (int i = 0; i < KK; ++i) a += qs[i][c]*ks2[i][d];
  attnL[(size_t)h*NWIN*64 + (size_t)n*64 + t] = a * temp[NH + h];
}

// ---------------- K5b: l-branch talk-conv + softmax(d) + PV, fused ----------------
__global__ __launch_bounds__(256) void k5b(
    const float* __restrict__ attnL, const float* __restrict__ wtalk,
    const float* __restrict__ vw, float* __restrict__ outa)
{
  int n = blockIdx.x;
  int hw = n/NWS, ww = n%NWS;
  __shared__ float rows[NH][9][64];
  __shared__ float wt[NH*NH*9];
  __shared__ float P[NH][CB][CB];
  int t = threadIdx.x;
  if (t < NH*NH*9) wt[t] = wtalk[t];
  for (int l = t; l < NH*9*64; l += 256){
    int h = l/(9*64); int nb = (l/64)%9; int cd = l & 63;
    int dy = nb/3-1, dx = nb%3-1; int hw2 = hw+dy, ww2 = ww+dx;
    float v = 0.f;
    if (hw2>=0 && hw2<NWS && ww2>=0 && ww2<NWS)
      v = attnL[((size_t)h*NWIN + hw2*NWS + ww2)*64 + cd];
    rows[h][nb][cd] = v;
  }
  __syncthreads();
  int tt = t >> 6; int cd = t & 63; int c = cd >> 3, d = cd & 7;
  float a = 0.f;
  #pragma unroll
  for (int h = 0; h < NH; ++h)
    #pragma unroll
    for (int nb = 0; nb < 9; ++nb)
      a += wt[(tt*NH + h)*9 + nb] * rows[h][nb][cd];
  float m = g8_max(a);
  float e = __expf(a - m);
  P[tt][c][d] = e / g8_sum(e);
  __syncthreads();
  int i = t & 63;
  size_t vbase = widx(tt, n, i, 8);
  float vl[CB];
  #pragma unroll
  for (int d2 = 0; d2 < CB; ++d2) vl[d2] = vw[vbase + d2];
  int kh = i>>3, kwd = i&7;
  int Y = (hw*8+kh+SSH)%IMG, X = (ww*8+kwd+SSH)%IMG;
  #pragma unroll
  for (int c2 = 0; c2 < CB; ++c2){
    float o = 0.f;
    #pragma unroll
    for (int d2 = 0; d2 < CB; ++d2) o += P[tt][c2][d2]*vl[d2];
    outa[((size_t)(32 + tt*CB + c2)*IMG + Y)*IMG + X] = o;
  }
}

// ---------------- K6a: attn_g[h,i,c,d] = sum_n qg*kg * temp ----------------
__global__ __launch_bounds__(64) void k6a(
    const float* __restrict__ qw, const float* __restrict__ kw,
    const float* __restrict__ temp, float* __restrict__ attnG)
{
  int i = blockIdx.x % KK; int h = blockIdx.x / KK;
  __shared__ float qs[64][CB], ks2[64][CB];
  int t = threadIdx.x; int c = t >> 3, d = t & 7;
  float a = 0.f;
  for (int n0 = 0; n0 < NWIN; n0 += 64){
    __syncthreads();
    size_t base = ((size_t)h*NWIN + n0 + t)*KK*CHW + (size_t)i*CHW + 16;
    #pragma unroll
    for (int cc = 0; cc < CB; ++cc){ qs[t][cc] = qw[base+cc]; ks2[t][cc] = kw[base+cc]; }
    __syncthreads();
    for (int l = 0; l < 64; ++l) a += qs[l][c]*ks2[l][d];
  }
  attnG[(size_t)h*KK*64 + (size_t)i*64 + t] = a * temp[2*NH + h];
}

// ---------------- K6b: g talking + softmax(d) ----------------
__global__ __launch_bounds__(64) void k6b(
    const float* __restrict__ attnG, const float* __restrict__ gtalk, float* __restrict__ attnGp)
{
  int l = blockIdx.x % KK; int t2 = blockIdx.x / KK;
  int cd = threadIdx.x;
  float a = 0.f;
  for (int h = 0; h < NH; ++h)
    for (int k = 0; k < KK; ++k)
      a += gtalk[((size_t)(h*KK + k)*KK + l)*NH + t2] * attnG[((size_t)h*KK + k)*64 + cd];
  float m = g8_max(a);
  float e = __expf(a - m);
  attnGp[((size_t)t2*KK + l)*64 + cd] = e / g8_sum(e);
}

// ---------------- K6c: out_g PV ----------------
__global__ __launch_bounds__(256) void k6c(
    const float* __restrict__ attnGp, const float* __restrict__ vw, float* __restrict__ outa)
{
  int n = blockIdx.x % NWIN; int t2 = blockIdx.x / NWIN;
  __shared__ float P[KK*64];
  int t = threadIdx.x;
  for (int l = t; l < KK*64; l += 256) P[l] = attnGp[(size_t)t2*KK*64 + l];
  __syncthreads();
  int i = t >> 2; int c0 = (t & 3)*2;
  size_t vbase = widx(t2, n, i, 16);
  float vg[8];
  #pragma unroll
  for (int d = 0; d < 8; ++d) vg[d] = vw[vbase + d];
  int hw = n/NWS, ww = n%NWS; int kh = i>>3, kwd = i&7;
  int Y = (hw*8+kh+SSH)%IMG, X = (ww*8+kwd+SSH)%IMG;
  for (int c = c0; c < c0+2; ++c){
    float o = 0.f;
    #pragma unroll
    for (int d = 0; d < 8; ++d) o += P[(i*8 + c)*8 + d]*vg[d];
    outa[((size_t)(64 + t2*CB + c)*IMG + Y)*IMG + X] = o;
  }
}

// ---------------- K7a: attn_r[h,c,i,j] = sum_n qr*kr * temp ----------------
__global__ __launch_bounds__(256) void k7a(
    const float* __restrict__ qw, const float* __restrict__ kw,
    const float* __restrict__ temp, float* __restrict__ attnR)
{
  int c = blockIdx.x % CB; int h = blockIdx.x / CB;
  __shared__ float qs[64][64];
  __shared__ float ks2[64][64];
  int t = threadIdx.x;
  int j = t & 63; int ig = t >> 6;
  float acc[16];
  #pragma unroll
  for (int p = 0; p < 16; ++p) acc[p] = 0.f;
  for (int n0 = 0; n0 < NWIN; n0 += 64){
    __syncthreads();
    for (int l = t; l < 4096; l += 256){
      int nn = l >> 6, ii = l & 63;
      size_t base = ((size_t)h*NWIN + n0 + nn)*KK*CHW + (size_t)ii*CHW + 24 + c;
      qs[nn][ii] = qw[base]; ks2[nn][ii] = kw[base];
    }
    __syncthreads();
    for (int nn = 0; nn < 64; ++nn){
      float kv = ks2[nn][j];
      #pragma unroll
      for (int p = 0; p < 16; ++p) acc[p] += qs[nn][ig*16+p]*kv;
    }
  }
  float tmp = temp[3*NH + h];
  #pragma unroll
  for (int p = 0; p < 16; ++p){
    int i = ig*16 + p;
    attnR[(((size_t)h*CB + c)*KK + i)*KK + j] = acc[p]*tmp;
  }
}

// ---------------- K7b: r talking + softmax(j) ----------------
__global__ __launch_bounds__(256) void k7b(
    const float* __restrict__ attnR, const float* __restrict__ rtalk, float* __restrict__ attnRp)
{
  int d = blockIdx.x % CB; int t2 = blockIdx.x / CB;
  __shared__ float S[64][64];
  __shared__ float wr2[32];
  int t = threadIdx.x;
  if (t < 32){ int h = t >> 3, c = t & 7; wr2[t] = rtalk[((size_t)(h*CB + c)*CB + d)*NH + t2]; }
  __syncthreads();
  int j = t & 63; int ig = t >> 6;
  float acc[16];
  #pragma unroll
  for (int p = 0; p < 16; ++p) acc[p] = 0.f;
  for (int hc = 0; hc < 32; ++hc){
    int h = hc >> 3, c = hc & 7;
    float w = wr2[hc];
    const float* Ar = attnR + ((size_t)h*CB + c)*KK*KK;
    #pragma unroll
    for (int p = 0; p < 16; ++p) acc[p] += w * Ar[(size_t)(ig*16+p)*KK + j];
  }
  #pragma unroll
  for (int p = 0; p < 16; ++p) S[ig*16+p][j] = acc[p];
  __syncthreads();
  for (int r = ig; r < 64; r += 4){
    float a = S[r][j];
    float m = wave_max(a);
    float e = __expf(a - m);
    attnRp[(((size_t)t2*CB + d)*KK + r)*KK + j] = e / wave_sum(e);
  }
}

// ---------------- K7c: out_r PV ----------------
__global__ __launch_bounds__(256) void k7c(
    const float* __restrict__ attnRp, const float* __restrict__ vw, float* __restrict__ outa)
{
  int n = blockIdx.x % NWIN; int t2 = blockIdx.x / NWIN;
  __shared__ float vr[KK][CB];
  int t = threadIdx.x;
  for (int l = t; l < KK*CB; l += 256){
    int j = l >> 3, c = l & 7;
    vr[j][c] = vw[widx(t2, n, j, 24 + c)];
  }
  __syncthreads();
  int i = t & 63; int cg = t >> 6;
  int hw = n/NWS, ww = n%NWS; int kh = i>>3, kwd = i&7;
  int Y = (hw*8+kh+SSH)%IMG, X = (ww*8+kwd+SSH)%IMG;
  for (int c = cg*2; c < cg*2+2; ++c){
    const float* Pr = attnRp + (((size_t)t2*CB + c)*KK + i)*KK;
    float o = 0.f;
    for (int j = 0; j < KK; ++j) o += Pr[j]*vr[j][c];
    outa[((size_t)(96 + t2*CB + c)*IMG + Y)*IMG + X] = o;
  }
}

// ---------------- K_dw: depthwise 3x3 over u -> dwu ----------------
// grid 128*48 blocks (one channel, 4 rows each), 256 threads
__global__ __launch_bounds__(256) void k_dw(
    const float* __restrict__ u, const float* __restrict__ dww, float* __restrict__ dwu)
{
  int ch = blockIdx.x / 48; int y0 = (blockIdx.x % 48) * 4;
  __shared__ float rows[6][192];
  int t = threadIdx.x;
  for (int idx = t; idx < 6*48; idx += 256){
    int r = idx / 48, px4 = (idx % 48)*4;
    int yy = y0 - 1 + r;
    float4 v = {0.f,0.f,0.f,0.f};
    if (yy >= 0 && yy < IMG) v = *(const float4*)&u[(size_t)ch*HWP + (size_t)yy*IMG + px4];
    rows[r][px4] = v.x; rows[r][px4+1] = v.y; rows[r][px4+2] = v.z; rows[r][px4+3] = v.w;
  }
  float kw9[9];
  #pragma unroll
  for (int q = 0; q < 9; ++q) kw9[q] = dww[ch*9 + q];
  __syncthreads();
  int r = t >> 6, lane = t & 63;
  for (int kx = 0; kx < 3; ++kx){
    int px = lane + kx*64;
    float s = 0.f;
    #pragma unroll
    for (int dy = 0; dy < 3; ++dy){
      #pragma unroll
      for (int dx = -1; dx <= 1; ++dx){
        int xx = px + dx;
        if (xx >= 0 && xx < IMG) s += kw9[dy*3 + dx + 1] * rows[r+dy][xx];
      }
    }
    dwu[(size_t)ch*HWP + (size_t)(y0+r)*IMG + px] = s;
  }
}

// ---------------- K8: channel means + sca ----------------
__global__ __launch_bounds__(256) void k8_mean(const float* __restrict__ outa, float* __restrict__ meanb){
  int ch = blockIdx.x;
  const float* p = outa + (size_t)ch*HWP;
  float s = 0.f;
  for (int l = threadIdx.x; l < HWP; l += 256) s += p[l];
  __shared__ float red[256];
  red[threadIdx.x] = s; __syncthreads();
  for (int k = 128; k > 0; k >>= 1){
    if (threadIdx.x < k) red[threadIdx.x] += red[threadIdx.x + k];
    __syncthreads();
  }
  if (threadIdx.x == 0) meanb[ch] = red[0] / (float)HWP;
}
__global__ __launch_bounds__(128) void k8b(const float* __restrict__ meanb, const float* __restrict__ scaw,
                                           const float* __restrict__ scab, float* __restrict__ svec){
  int o = threadIdx.x;
  float s = scab[o];
  for (int c = 0; c < HD; ++c) s += scaw[(size_t)o*HD + c]*meanb[c];
  svec[o] = s;
}

// ---------------- K9a: out2z = (projw @ (outa*svec) + dwu) * zbuf ----------------
// grid 288 blocks x 2 tiles of 64px, 256 threads; weights transposed in LDS
#define PADX 68
__global__ __launch_bounds__(256) void k9a(
    const float* __restrict__ outa, const float* __restrict__ svec,
    const float* __restrict__ projw, const float* __restrict__ dwu,
    const float* __restrict__ zbuf, float* __restrict__ out2z)
{
  __shared__ float WT[128][128];    // WT[c][o] = projw[o][c]
  __shared__ float xsv[128][PADX];
  __shared__ float sv[128];
  int t = threadIdx.x;
  if (t < 128) sv[t] = svec[t];
  for (int idx = t; idx < 4096; idx += 256){
    int o = idx & 127; int c4 = (idx >> 7) * 4;
    float4 w = *(const float4*)&projw[(size_t)o*HD + c4];
    WT[c4][o] = w.x; WT[c4+1][o] = w.y; WT[c4+2][o] = w.z; WT[c4+3][o] = w.w;
  }
  int px4 = (t & 15) * 4; int og8 = (t >> 4) * 8;
  for (int tile = 0; tile < 2; ++tile){
    int tid = blockIdx.x * 2 + tile;
    int y = tid / 3, x0 = (tid % 3) * 64;
    size_t sb = (size_t)y*IMG + x0;
    __syncthreads();
    for (int idx = t; idx < 2048; idx += 256){
      int c = idx >> 4; int p4 = (idx & 15) * 4;
      float4 v = *(const float4*)&outa[(size_t)c*HWP + sb + p4];
      float s = sv[c];
      xsv[c][p4] = v.x*s; xsv[c][p4+1] = v.y*s; xsv[c][p4+2] = v.z*s; xsv[c][p4+3] = v.w*s;
    }
    __syncthreads();
    float acc[8][4];
    #pragma unroll
    for (int a = 0; a < 8; ++a){ acc[a][0]=0.f; acc[a][1]=0.f; acc[a][2]=0.f; acc[a][3]=0.f; }
    for (int c = 0; c < 128; ++c){
      float4 xv = *(const float4*)&xsv[c][px4];
      float4 wA = *(const float4*)&WT[c][og8];
      float4 wB = *(const float4*)&WT[c][og8+4];
      float w8[8] = {wA.x,wA.y,wA.z,wA.w,wB.x,wB.y,wB.z,wB.w};
      #pragma unroll
      for (int a = 0; a < 8; ++a){
        acc[a][0] += w8[a]*xv.x; acc[a][1] += w8[a]*xv.y;
        acc[a][2] += w8[a]*xv.z; acc[a][3] += w8[a]*xv.w;
      }
    }
    #pragma unroll
    for (int oo = 0; oo < 8; ++oo){
      int o = og8 + oo;
      size_t off = (size_t)o*HWP + sb + px4;
      float4 d = *(const float4*)&dwu[off];
      float4 z = *(const float4*)&zbuf[off];
      float4 r;
      r.x = (acc[oo][0]+d.x)*z.x; r.y = (acc[oo][1]+d.y)*z.y;
      r.z = (acc[oo][2]+d.z)*z.z; r.w = (acc[oo][3]+d.w)*z.w;
      *(float4*)&out2z[off] = r;
    }
  }
}

// ---------------- K9b: dout = projow @ out2z ----------------
// grid 288 blocks x 2 tiles of 64px, 256 threads
__global__ __launch_bounds__(256) void k9b(
    const float* __restrict__ out2z, const float* __restrict__ projow,
    float* __restrict__ dout, int bsel)
{
  __shared__ float WT2[128][64];    // WT2[c][o] = projow[o][c]
  __shared__ float xsv[128][PADX];
  int t = threadIdx.x;
  for (int idx = t; idx < 2048; idx += 256){
    int o = idx & 63; int c4 = (idx >> 6) * 4;
    float4 w = *(const float4*)&projow[(size_t)o*HD + c4];
    WT2[c4][o] = w.x; WT2[c4+1][o] = w.y; WT2[c4+2][o] = w.z; WT2[c4+3][o] = w.w;
  }
  int px4 = (t & 15) * 4; int og4 = (t >> 4) * 4;
  for (int tile = 0; tile < 2; ++tile){
    int tid = blockIdx.x * 2 + tile;
    int y = tid / 3, x0 = (tid % 3) * 64;
    size_t sb = (size_t)y*IMG + x0;
    __syncthreads();
    for (int idx = t; idx < 2048; idx += 256){
      int c = idx >> 4; int p4 = (idx & 15) * 4;
      float4 v = *(const float4*)&out2z[(size_t)c*HWP + sb + p4];
      xsv[c][p4] = v.x; xsv[c][p4+1] = v.y; xsv[c][p4+2] = v.z; xsv[c][p4+3] = v.w;
    }
    __syncthreads();
    float acc[4][4];
    #pragma unroll
    for (int a = 0; a < 4; ++a){ acc[a][0]=0.f; acc[a][1]=0.f; acc[a][2]=0.f; acc[a][3]=0.f; }
    for (int c = 0; c < 128; ++c){
      float4 xv = *(const float4*)&xsv[c][px4];
      float4 w4 = *(const float4*)&WT2[c][og4];
      float w4a[4] = {w4.x,w4.y,w4.z,w4.w};
      #pragma unroll
      for (int a = 0; a < 4; ++a){
        acc[a][0] += w4a[a]*xv.x; acc[a][1] += w4a[a]*xv.y;
        acc[a][2] += w4a[a]*xv.z; acc[a][3] += w4a[a]*xv.w;
      }
    }
    #pragma unroll
    for (int oo = 0; oo < 4; ++oo){
      int o = og4 + oo;
      float4 r; r.x = acc[oo][0]; r.y = acc[oo][1]; r.z = acc[oo][2]; r.w = acc[oo][3];
      *(float4*)&dout[(size_t)(bsel*CIN + o)*HWP + sb + px4] = r;
    }
  }
}

// ---------------- launch ----------------
extern "C" void kernel_launch(void* const* d_in, const int* in_sizes, int n_in,
                              void* d_out, int out_size, void* d_ws, size_t ws_size,
                              hipStream_t stream)
{
  const float* x     = (const float*)d_in[0];
  const float* wquz  = (const float*)d_in[1];
  const float* wkv   = (const float*)d_in[2];
  const float* temp  = (const float*)d_in[3];
  const float* rtalk = (const float*)d_in[4];
  const float* gtalk = (const float*)d_in[5];
  const float* btw   = (const float*)d_in[6];
  const float* ltw   = (const float*)d_in[7];
  const float* dww   = (const float*)d_in[8];
  const float* projw = (const float*)d_in[9];
  const float* projow= (const float*)d_in[10];
  const float* scaw  = (const float*)d_in[11];
  const float* scab  = (const float*)d_in[12];
  float* dout = (float*)d_out;

  // per-batch workspace (~153 MB total)
  float* ws = (float*)d_ws;
  float* qw     = ws;                 // NWINEL
  float* kw     = qw + NWINEL;        // NWINEL
  float* vw     = kw + NWINEL;        // NWINEL
  float* u      = vw + NWINEL;        // NSP
  float* outa   = u + NSP;            // NSP
  float* zbuf   = outa + NSP;         // NSP
  float* attnB  = zbuf + NSP;         // NATTNB (reused: dwu + out2z after k4)
  float* dwu    = attnB;              // NSP (alias)
  float* out2z  = attnB + NSP;        // NSP (alias)
  float* attnL  = attnB + NATTNB;     // NATTNL
  float* attnGbuf = attnL + NATTNL;   // NATTNG
  float* attnGp = attnGbuf + NATTNG;  // NATTNG
  float* attnR  = attnGp + NATTNG;    // NATTNR
  float* attnRp = attnR + NATTNR;     // NATTNR
  float* meanb  = attnRp + NATTNR;    // 128
  float* svec   = meanb + 128;        // 128

  for (int b = 0; b < BB; ++b){
    k1_proj<<<IMG, 256, 0, stream>>>(x, wquz, wkv, qw, kw, vw, u, zbuf, b);

    k2a<<<(2*NH*NWIN*KK + 255)/256, 256, 0, stream>>>(qw, kw);
    k2b<<<(2*NH*NWIN*CB + 255)/256, 256, 0, stream>>>(qw, kw);
    k2c<<<(2*NH*KK*16 + 255)/256, 256, 0, stream>>>(qw, kw);

    k3_attnb<<<NH*NWIN, 64, 0, stream>>>(qw, kw, temp, attnB);
    k4_bconv<<<NWIN*KK, 256, 0, stream>>>(attnB, btw, vw, outa);

    k5a<<<NH*NWIN, 64, 0, stream>>>(qw, kw, temp, attnL);
    k5b<<<NWIN, 256, 0, stream>>>(attnL, ltw, vw, outa);

    k6a<<<NH*KK, 64, 0, stream>>>(qw, kw, temp, attnGbuf);
    k6b<<<NH*KK, 64, 0, stream>>>(attnGbuf, gtalk, attnGp);
    k6c<<<NH*NWIN, 256, 0, stream>>>(attnGp, vw, outa);

    k7a<<<NH*CB, 256, 0, stream>>>(qw, kw, temp, attnR);
    k7b<<<NH*CB, 256, 0, stream>>>(attnR, rtalk, attnRp);
    k7c<<<NH*NWIN, 256, 0, stream>>>(attnRp, vw, outa);

    // attnB region is free now -> dwu/out2z
    k_dw<<<HD*48, 256, 0, stream>>>(u, dww, dwu);

    k8_mean<<<HD, 256, 0, stream>>>(outa, meanb);
    k8b<<<1, 128, 0, stream>>>(meanb, scaw, scab, svec);

    k9a<<<288, 256, 0, stream>>>(outa, svec, projw, dwu, zbuf, out2z);
    k9b<<<288, 256, 0, stream>>>(out2z, projow, dout, b);
  }
}

// Round 4
// 2330.098 us; speedup vs baseline: 1.7742x; 1.4205x over previous
//
#include <hip/hip_runtime.h>
#include <cstdint>
#include <cstddef>

// ---------------- problem constants ----------------
#define BB   4      // batch
#define CIN  64     // input channels
#define HD   128    // h_dim
#define NH   4      // heads
#define CHW  32     // channels per head
#define CB   8      // channels per branch
#define IMG  192    // H = W
#define SSH  4      // shift
#define NWS  24     // windows per side
#define NWIN 576    // windows total
#define KK   64     // window elements (8x8)
#define HWP  (IMG*IMG)

// per-batch buffer sizes (floats)
static const size_t NQK16  = (size_t)NH*NWIN*KK*16;   // 2,359,296 (q/k b+l channels)
static const size_t NV32   = (size_t)NH*NWIN*KK*CHW;  // 4,718,592 (v all channels)
static const size_t NGR    = (size_t)NH*KK*NWIN*CB;   // 1,179,648 (qg/kg/qr/kr)
static const size_t NSP    = (size_t)HD*HWP;          // 4,718,592 spatial 128ch
static const size_t NATTNB = (size_t)NH*NWIN*KK*KK;   // 9,437,184
static const size_t NATTNL = (size_t)NH*NWIN*64;      // 147,456
static const size_t NATTNG = (size_t)NH*KK*64;        // 16,384
static const size_t NATTNR = (size_t)NH*CB*KK*KK;     // 131,072
static const size_t NPART  = (size_t)8*NATTNR;        // 1,048,576

// ---------------- helpers ----------------
__device__ inline float wave_max(float v){
  #pragma unroll
  for (int s=1;s<64;s<<=1) v = fmaxf(v, __shfl_xor(v, s));
  return v;
}
__device__ inline float wave_sum(float v){
  #pragma unroll
  for (int s=1;s<64;s<<=1) v += __shfl_xor(v, s);
  return v;
}
__device__ inline float g8_max(float v){
  v = fmaxf(v, __shfl_xor(v,1)); v = fmaxf(v, __shfl_xor(v,2)); v = fmaxf(v, __shfl_xor(v,4));
  return v;
}
__device__ inline float g8_sum(float v){
  v += __shfl_xor(v,1); v += __shfl_xor(v,2); v += __shfl_xor(v,4);
  return v;
}
// Swin region id for an image coordinate (0..191): [0,184)=0, [184,188)=1, [188,192)=2
__device__ inline int regionc(int y){ return (y < IMG-8) ? 0 : ((y < IMG-4) ? 1 : 2); }

// v layout [h][n][i][c32]
__device__ inline size_t widx(int h,int n,int i,int c){
  return (((size_t)h*NWIN + n)*KK + i)*CHW + c;
}
// q/k b+l layout [h][n][i][c16]
__device__ inline size_t widx16(int h,int n,int i,int c){
  return (((size_t)h*NWIN + n)*KK + i)*16 + c;
}
// g layout [h][i][n][c8]
__device__ inline size_t gidx(int h,int i,int n,int c){
  return (((size_t)(h*KK + i))*NWIN + n)*CB + c;
}
// r layout [h][c][n][i]
__device__ inline size_t ridx(int h,int c,int n,int i){
  return (((size_t)(h*CB + c))*NWIN + n)*KK + i;
}

// ---------------- K1: projections -> q/k/v (split layouts) + u,z (spatial) ----------------
// grid IMG*3 (64-px tiles), 256 threads
__global__ __launch_bounds__(256) void k1_proj(
    const float* __restrict__ x, const float* __restrict__ wquz, const float* __restrict__ wkv,
    float* __restrict__ qw, float* __restrict__ kw, float* __restrict__ vw,
    float* __restrict__ qg, float* __restrict__ kg,
    float* __restrict__ qr, float* __restrict__ kr,
    float* __restrict__ u, float* __restrict__ zbuf, int bsel)
{
  __shared__ float xs[64][64];
  __shared__ int pn[64], pi[64];
  int blk = blockIdx.x;
  int xc = blk % 3, y = blk / 3;
  int x0 = xc*64;
  int t = threadIdx.x;
  for (int idx = t; idx < 64*16; idx += 256){
    int c = idx >> 4, p4 = (idx & 15)*4;
    float4 v = *(const float4*)&x[((size_t)(bsel*CIN+c)*IMG + y)*IMG + x0 + p4];
    *(float4*)&xs[c][p4] = v;
  }
  if (t < 64){
    int py  = (y + IMG - SSH) % IMG;
    int pxx = (x0 + t + IMG - SSH) % IMG;
    pn[t] = (py>>3)*NWS + (pxx>>3);
    pi[t] = (py&7)*8 + (pxx&7);
  }
  __syncthreads();

  for (int oi = 0; oi < 3; ++oi){
    if (oi == 2 && t >= 128) break;
    int o = (oi == 0) ? t : (oi == 1 ? t + 384 : t + 256);
    const float* wr = (o < 384) ? (wquz + (size_t)o*CIN) : (wkv + (size_t)(o-384)*CIN);
    for (int g = 0; g < 4; ++g){
      float acc[16];
      #pragma unroll
      for (int p = 0; p < 16; ++p) acc[p] = 0.f;
      for (int cc = 0; cc < 64; cc += 4){
        float4 w4 = *(const float4*)(wr + cc);
        #pragma unroll
        for (int p = 0; p < 16; ++p){
          acc[p] += w4.x * xs[cc  ][g*16 + p];
          acc[p] += w4.y * xs[cc+1][g*16 + p];
          acc[p] += w4.z * xs[cc+2][g*16 + p];
          acc[p] += w4.w * xs[cc+3][g*16 + p];
        }
      }
      #pragma unroll
      for (int p = 0; p < 16; ++p){
        int px = g*16 + p;
        float val = acc[p];
        if (o < 128){                       // q
          int h = o >> 5, c = o & 31;
          if (c < 16)      qw[widx16(h,pn[px],pi[px],c)] = val;
          else if (c < 24) qg[gidx(h,pi[px],pn[px],c-16)] = val;
          else             qr[ridx(h,c-24,pn[px],pi[px])] = val;
        } else if (o < 256){                // u
          u[((size_t)(o-128)*IMG + y)*IMG + x0 + px] = val;
        } else if (o < 384){                // z
          zbuf[((size_t)(o-256)*IMG + y)*IMG + x0 + px] = val;
        } else if (o < 512){                // k
          int oc = o - 384; int h = oc >> 5, c = oc & 31;
          if (c < 16)      kw[widx16(h,pn[px],pi[px],c)] = val;
          else if (c < 24) kg[gidx(h,pi[px],pn[px],c-16)] = val;
          else             kr[ridx(h,c-24,pn[px],pi[px])] = val;
        } else {                            // v
          int oc = o - 512; int h = oc >> 5, c = oc & 31;
          vw[widx(h,pn[px],pi[px],c)] = val;
        }
      }
    }
  }
}

// ---------------- kNg: inverse L2 norms over n for g-branch ----------------
// grid NH*KK (h,i), 64 threads
__global__ __launch_bounds__(64) void kNg(
    const float* __restrict__ qg, const float* __restrict__ kg,
    float* __restrict__ invqg, float* __restrict__ invkg)
{
  int i = blockIdx.x & 63, h = blockIdx.x >> 6;
  size_t base = ((size_t)(h*KK+i))*NWIN*CB;
  int t = threadIdx.x, c = t & 7, ng = t >> 3;
  float sq = 0.f, sk2 = 0.f;
  for (int n = ng; n < NWIN; n += 8){
    float a = qg[base + (size_t)n*CB + c]; sq  += a*a;
    float b = kg[base + (size_t)n*CB + c]; sk2 += b*b;
  }
  #pragma unroll
  for (int m = 8; m < 64; m <<= 1){ sq += __shfl_xor(sq,m); sk2 += __shfl_xor(sk2,m); }
  if (t < 8){
    invqg[(h*KK+i)*CB + c] = 1.f/fmaxf(sqrtf(sq), 1e-12f);
    invkg[(h*KK+i)*CB + c] = 1.f/fmaxf(sqrtf(sk2),1e-12f);
  }
}

// ---------------- kNr: inverse L2 norms over n for r-branch ----------------
// grid NH*CB (h,c), 256 threads
__global__ __launch_bounds__(256) void kNr(
    const float* __restrict__ qr, const float* __restrict__ kr,
    float* __restrict__ invqr, float* __restrict__ invkr)
{
  int hc = blockIdx.x;
  size_t base = (size_t)hc*NWIN*KK;
  int t = threadIdx.x, i = t & 63, ng = t >> 6;
  float sq = 0.f, sk2 = 0.f;
  for (int n = ng; n < NWIN; n += 4){
    float a = qr[base + (size_t)n*KK + i]; sq  += a*a;
    float b = kr[base + (size_t)n*KK + i]; sk2 += b*b;
  }
  __shared__ float rq[4][64], rk[4][64];
  rq[ng][i] = sq; rk[ng][i] = sk2;
  __syncthreads();
  if (t < 64){
    float s = rq[0][t]+rq[1][t]+rq[2][t]+rq[3][t];
    invqr[hc*KK + t] = 1.f/fmaxf(sqrtf(s),1e-12f);
  } else if (t < 128){
    int i2 = t - 64;
    float s = rk[0][i2]+rk[1][i2]+rk[2][i2]+rk[3][i2];
    invkr[hc*KK + i2] = 1.f/fmaxf(sqrtf(s),1e-12f);
  }
}

// ---------------- K3: attn_b = norm(qb)@norm(kb)^T * temp (norm fused) ----------------
// grid NH*NWIN, 64 threads (j)
__global__ __launch_bounds__(64) void k3_attnb(
    const float* __restrict__ qw, const float* __restrict__ kw,
    const float* __restrict__ temp, float* __restrict__ attnB)
{
  int n = blockIdx.x % NWIN, h = blockIdx.x / NWIN;
  __shared__ float qs[KK][CB];
  int j = threadIdx.x;
  size_t base = widx16(h,n,j,0);
  float q8[CB], k8[CB];
  float sq = 0.f, sk2 = 0.f;
  #pragma unroll
  for (int c = 0; c < CB; ++c){
    q8[c] = qw[base+c]; sq += q8[c]*q8[c];
    k8[c] = kw[base+c]; sk2 += k8[c]*k8[c];
  }
  float invq = 1.f/fmaxf(sqrtf(sq),1e-12f), invk = 1.f/fmaxf(sqrtf(sk2),1e-12f);
  #pragma unroll
  for (int c = 0; c < CB; ++c){ qs[j][c] = q8[c]*invq; k8[c] *= invk; }
  __syncthreads();
  float tmp = temp[h];
  float* orow = attnB + (size_t)(h*NWIN + n)*KK*KK;
  for (int i = 0; i < KK; ++i){
    float a = 0.f;
    #pragma unroll
    for (int c = 0; c < CB; ++c) a += qs[i][c]*k8[c];
    orow[(size_t)i*KK + j] = a * tmp;
  }
}

// ---------------- K4: b-branch talk-conv + mask + softmax + PV, fused ----------------
// grid KK*NWIN with i SLOW
__global__ __launch_bounds__(256) void k4_bconv(
    const float* __restrict__ attnB, const float* __restrict__ wtalk,
    const float* __restrict__ vw, float* __restrict__ outa)
{
  int i = blockIdx.x / NWIN, n = blockIdx.x % NWIN;
  int hw = n / NWS, ww = n % NWS;
  __shared__ float rows[NH][9][KK];
  __shared__ float wt[NH*NH*9];
  int t = threadIdx.x;
  if (t < NH*NH*9) wt[t] = wtalk[t];
  for (int l = t; l < NH*9*KK; l += 256){
    int h = l / (9*KK); int nb = (l / KK) % 9; int j = l & 63;
    int dy = nb/3 - 1, dx = nb%3 - 1;
    int hw2 = hw + dy, ww2 = ww + dx;
    float v = 0.f;
    if (hw2 >= 0 && hw2 < NWS && ww2 >= 0 && ww2 < NWS)
      v = attnB[((size_t)(h*NWIN + hw2*NWS + ww2)*KK + i)*KK + j];
    rows[h][nb][j] = v;
  }
  __syncthreads();
  int wv = t >> 6;
  int j  = t & 63;
  float a = 0.f;
  #pragma unroll
  for (int h = 0; h < NH; ++h)
    #pragma unroll
    for (int nb = 0; nb < 9; ++nb)
      a += wt[(wv*NH + h)*9 + nb] * rows[h][nb][j];
  int kh = i >> 3, kwd = i & 7;
  int cntI = regionc(hw*8 + kh)*3 + regionc(ww*8 + kwd);
  int cntJ = regionc(hw*8 + (j>>3))*3 + regionc(ww*8 + (j&7));
  if (cntI != cntJ) a -= 100.f;
  float m = wave_max(a);
  float e = __expf(a - m);
  float p = e / wave_sum(e);
  size_t vbase = widx(wv, n, j, 0);
  float pv[CB];
  #pragma unroll
  for (int c = 0; c < CB; ++c) pv[c] = p * vw[vbase + c];
  #pragma unroll
  for (int c = 0; c < CB; ++c) pv[c] = wave_sum(pv[c]);
  if (j == 0){
    int Y = (hw*8 + kh + SSH) % IMG;
    int X = (ww*8 + kwd + SSH) % IMG;
    #pragma unroll
    for (int c = 0; c < CB; ++c)
      outa[((size_t)(wv*CB + c)*IMG + Y)*IMG + X] = pv[c];
  }
}

// ---------------- K5a: attn_l (norm factored out) ----------------
// grid NH*NWIN, 64 threads
__global__ __launch_bounds__(64) void k5a(
    const float* __restrict__ qw, const float* __restrict__ kw,
    const float* __restrict__ temp, float* __restrict__ attnL)
{
  int n = blockIdx.x % NWIN, h = blockIdx.x / NWIN;
  __shared__ float qs[KK][CB], ks[KK][CB];
  __shared__ float invqA[CB], invkA[CB];
  int t = threadIdx.x;
  size_t base = widx16(h,n,t,8);
  #pragma unroll
  for (int c = 0; c < CB; ++c){ qs[t][c] = qw[base+c]; ks[t][c] = kw[base+c]; }
  __syncthreads();
  int c8 = t & 7, ig = t >> 3;
  float sq = 0.f, sk2 = 0.f;
  for (int i = ig; i < KK; i += 8){
    float a = qs[i][c8]; sq += a*a;
    float b = ks[i][c8]; sk2 += b*b;
  }
  #pragma unroll
  for (int m = 8; m < 64; m <<= 1){ sq += __shfl_xor(sq,m); sk2 += __shfl_xor(sk2,m); }
  if (t < 8){ invqA[t] = 1.f/fmaxf(sqrtf(sq),1e-12f); invkA[t] = 1.f/fmaxf(sqrtf(sk2),1e-12f); }
  __syncthreads();
  int c = t >> 3, d = t & 7;
  float a = 0.f;
  for (int i = 0; i < KK; ++i) a += qs[i][c]*ks[i][d];
  attnL[(size_t)h*NWIN*64 + (size_t)n*64 + t] = a * invqA[c] * invkA[d] * temp[NH + h];
}

// ---------------- K5b: l-branch talk-conv + softmax(d) + PV ----------------
__global__ __launch_bounds__(256) void k5b(
    const float* __restrict__ attnL, const float* __restrict__ wtalk,
    const float* __restrict__ vw, float* __restrict__ outa)
{
  int n = blockIdx.x;
  int hw = n/NWS, ww = n%NWS;
  __shared__ float rows[NH][9][64];
  __shared__ float wt[NH*NH*9];
  __shared__ float P[NH][CB][CB];
  int t = threadIdx.x;
  if (t < NH*NH*9) wt[t] = wtalk[t];
  for (int l = t; l < NH*9*64; l += 256){
    int h = l/(9*64); int nb = (l/64)%9; int cd = l & 63;
    int dy = nb/3-1, dx = nb%3-1; int hw2 = hw+dy, ww2 = ww+dx;
    float v = 0.f;
    if (hw2>=0 && hw2<NWS && ww2>=0 && ww2<NWS)
      v = attnL[((size_t)h*NWIN + hw2*NWS + ww2)*64 + cd];
    rows[h][nb][cd] = v;
  }
  __syncthreads();
  int tt = t >> 6; int cd = t & 63; int c = cd >> 3, d = cd & 7;
  float a = 0.f;
  #pragma unroll
  for (int h = 0; h < NH; ++h)
    #pragma unroll
    for (int nb = 0; nb < 9; ++nb)
      a += wt[(tt*NH + h)*9 + nb] * rows[h][nb][cd];
  float m = g8_max(a);
  float e = __expf(a - m);
  P[tt][c][d] = e / g8_sum(e);
  __syncthreads();
  int i = t & 63;
  size_t vbase = widx(tt, n, i, 8);
  float vl[CB];
  #pragma unroll
  for (int d2 = 0; d2 < CB; ++d2) vl[d2] = vw[vbase + d2];
  int kh = i>>3, kwd = i&7;
  int Y = (hw*8+kh+SSH)%IMG, X = (ww*8+kwd+SSH)%IMG;
  #pragma unroll
  for (int c2 = 0; c2 < CB; ++c2){
    float o = 0.f;
    #pragma unroll
    for (int d2 = 0; d2 < CB; ++d2) o += P[tt][c2][d2]*vl[d2];
    outa[((size_t)(32 + tt*CB + c2)*IMG + Y)*IMG + X] = o;
  }
}

// ---------------- K6a: attn_g[h,i,c,d] = sum_n qg*kg (coalesced layout) ----------------
// grid NH*KK, 256 threads
__global__ __launch_bounds__(256) void k6a(
    const float* __restrict__ qg, const float* __restrict__ kg,
    const float* __restrict__ invqg, const float* __restrict__ invkg,
    const float* __restrict__ temp, float* __restrict__ attnG)
{
  int i = blockIdx.x & 63, h = blockIdx.x >> 6;
  __shared__ float sq[64*8], sk[64*8];
  __shared__ float red[4][64];
  int t = threadIdx.x;
  size_t base = ((size_t)(h*KK+i))*NWIN*CB;
  int np = t >> 6, cd = t & 63, c = cd >> 3, d = cd & 7;
  float a = 0.f;
  for (int n0 = 0; n0 < NWIN; n0 += 64){
    __syncthreads();
    for (int idx = t; idx < 512; idx += 256){
      sq[idx] = qg[base + (size_t)n0*CB + idx];
      sk[idx] = kg[base + (size_t)n0*CB + idx];
    }
    __syncthreads();
    for (int nn = np; nn < 64; nn += 4) a += sq[nn*8+c]*sk[nn*8+d];
  }
  __syncthreads();
  red[np][cd] = a;
  __syncthreads();
  if (t < 64){
    float tot = red[0][t]+red[1][t]+red[2][t]+red[3][t];
    tot *= invqg[(h*KK+i)*CB + (t>>3)] * invkg[(h*KK+i)*CB + (t&7)] * temp[2*NH + h];
    attnG[(size_t)(h*KK+i)*64 + t] = tot;
  }
}

// ---------------- K6b: g talking + softmax(d) ----------------
__global__ __launch_bounds__(64) void k6b(
    const float* __restrict__ attnG, const float* __restrict__ gtalk, float* __restrict__ attnGp)
{
  int l = blockIdx.x % KK; int t2 = blockIdx.x / KK;
  int cd = threadIdx.x;
  float a = 0.f;
  for (int h = 0; h < NH; ++h)
    for (int k = 0; k < KK; ++k)
      a += gtalk[((size_t)(h*KK + k)*KK + l)*NH + t2] * attnG[((size_t)h*KK + k)*64 + cd];
  float m = g8_max(a);
  float e = __expf(a - m);
  attnGp[((size_t)t2*KK + l)*64 + cd] = e / g8_sum(e);
}

// ---------------- K6c: out_g PV ----------------
__global__ __launch_bounds__(256) void k6c(
    const float* __restrict__ attnGp, const float* __restrict__ vw, float* __restrict__ outa)
{
  int n = blockIdx.x % NWIN; int t2 = blockIdx.x / NWIN;
  __shared__ float P[KK*64];
  int t = threadIdx.x;
  for (int l = t; l < KK*64; l += 256) P[l] = attnGp[(size_t)t2*KK*64 + l];
  __syncthreads();
  int i = t >> 2; int c0 = (t & 3)*2;
  size_t vbase = widx(t2, n, i, 16);
  float vg[8];
  #pragma unroll
  for (int d = 0; d < 8; ++d) vg[d] = vw[vbase + d];
  int hw = n/NWS, ww = n%NWS; int kh = i>>3, kwd = i&7;
  int Y = (hw*8+kh+SSH)%IMG, X = (ww*8+kwd+SSH)%IMG;
  for (int c = c0; c < c0+2; ++c){
    float o = 0.f;
    #pragma unroll
    for (int d = 0; d < 8; ++d) o += P[(i*8 + c)*8 + d]*vg[d];
    outa[((size_t)(64 + t2*CB + c)*IMG + Y)*IMG + X] = o;
  }
}

// ---------------- K7a: r-branch Gram partials over n-chunks ----------------
// grid 8 chunks x NH*CB, 256 threads
__global__ __launch_bounds__(256) void k7a(
    const float* __restrict__ qr, const float* __restrict__ kr, float* __restrict__ part)
{
  int chunk = blockIdx.x >> 5, hc = blockIdx.x & 31;
  int n0 = chunk*72;
  __shared__ float sq[72*64], sk[72*64];
  int t = threadIdx.x;
  size_t base = (size_t)hc*NWIN*KK + (size_t)n0*KK;
  for (int idx = t; idx < 72*64/4; idx += 256){
    *(float4*)&sq[idx*4] = *(const float4*)&qr[base + (size_t)idx*4];
    *(float4*)&sk[idx*4] = *(const float4*)&kr[base + (size_t)idx*4];
  }
  __syncthreads();
  int j = t & 63, ig = t >> 6;
  float acc[16];
  #pragma unroll
  for (int p = 0; p < 16; ++p) acc[p] = 0.f;
  for (int nn = 0; nn < 72; ++nn){
    float kv = sk[nn*64+j];
    #pragma unroll
    for (int p = 0; p < 16; ++p) acc[p] += sq[nn*64 + ig*16 + p]*kv;
  }
  float* ob = part + (size_t)blockIdx.x*4096;
  #pragma unroll
  for (int p = 0; p < 16; ++p) ob[(size_t)(ig*16+p)*64 + j] = acc[p];
}

// ---------------- kRed: sum partials * norms * temp -> attnR ----------------
// grid 512, 256 threads
__global__ __launch_bounds__(256) void kRed(
    const float* __restrict__ part, const float* __restrict__ invqr,
    const float* __restrict__ invkr, const float* __restrict__ temp,
    float* __restrict__ attnR)
{
  int e = blockIdx.x*256 + threadIdx.x;
  float s = 0.f;
  #pragma unroll
  for (int ch = 0; ch < 8; ++ch) s += part[(size_t)ch*NATTNR + e];
  int hc = e >> 12, ij = e & 4095, i = ij >> 6, j = ij & 63;
  attnR[e] = s * invqr[hc*64+i] * invkr[hc*64+j] * temp[3*NH + (hc>>3)];
}

// ---------------- K7b: r talking + softmax(j) ----------------
__global__ __launch_bounds__(256) void k7b(
    const float* __restrict__ attnR, const float* __restrict__ rtalk, float* __restrict__ attnRp)
{
  int d = blockIdx.x % CB; int t2 = blockIdx.x / CB;
  __shared__ float S[64][64];
  __shared__ float wr2[32];
  int t = threadIdx.x;
  if (t < 32){ int h = t >> 3, c = t & 7; wr2[t] = rtalk[((size_t)(h*CB + c)*CB + d)*NH + t2]; }
  __syncthreads();
  int j = t & 63; int ig = t >> 6;
  float acc[16];
  #pragma unroll
  for (int p = 0; p < 16; ++p) acc[p] = 0.f;
  for (int hc = 0; hc < 32; ++hc){
    float w = wr2[hc];
    const float* Ar = attnR + (size_t)hc*KK*KK;
    #pragma unroll
    for (int p = 0; p < 16; ++p) acc[p] += w * Ar[(size_t)(ig*16+p)*KK + j];
  }
  #pragma unroll
  for (int p = 0; p < 16; ++p) S[ig*16+p][j] = acc[p];
  __syncthreads();
  for (int r = ig; r < 64; r += 4){
    float a = S[r][j];
    float m = wave_max(a);
    float e = __expf(a - m);
    attnRp[(((size_t)t2*CB + d)*KK + r)*KK + j] = e / wave_sum(e);
  }
}

// ---------------- K7c: out_r PV ----------------
__global__ __launch_bounds__(256) void k7c(
    const float* __restrict__ attnRp, const float* __restrict__ vw, float* __restrict__ outa)
{
  int n = blockIdx.x % NWIN; int t2 = blockIdx.x / NWIN;
  __shared__ float vr[KK][CB];
  int t = threadIdx.x;
  for (int l = t; l < KK*CB; l += 256){
    int j = l >> 3, c = l & 7;
    vr[j][c] = vw[widx(t2, n, j, 24 + c)];
  }
  __syncthreads();
  int i = t & 63; int cg = t >> 6;
  int hw = n/NWS, ww = n%NWS; int kh = i>>3, kwd = i&7;
  int Y = (hw*8+kh+SSH)%IMG, X = (ww*8+kwd+SSH)%IMG;
  for (int c = cg*2; c < cg*2+2; ++c){
    const float* Pr = attnRp + (((size_t)t2*CB + c)*KK + i)*KK;
    float o = 0.f;
    for (int j = 0; j < KK; ++j) o += Pr[j]*vr[j][c];
    outa[((size_t)(96 + t2*CB + c)*IMG + Y)*IMG + X] = o;
  }
}

// ---------------- K_dw: depthwise 3x3 over u -> dwu ----------------
__global__ __launch_bounds__(256) void k_dw(
    const float* __restrict__ u, const float* __restrict__ dww, float* __restrict__ dwu)
{
  int ch = blockIdx.x / 48; int y0 = (blockIdx.x % 48) * 4;
  __shared__ float rows[6][192];
  int t = threadIdx.x;
  for (int idx = t; idx < 6*48; idx += 256){
    int r = idx / 48, px4 = (idx % 48)*4;
    int yy = y0 - 1 + r;
    float4 v = {0.f,0.f,0.f,0.f};
    if (yy >= 0 && yy < IMG) v = *(const float4*)&u[(size_t)ch*HWP + (size_t)yy*IMG + px4];
    rows[r][px4] = v.x; rows[r][px4+1] = v.y; rows[r][px4+2] = v.z; rows[r][px4+3] = v.w;
  }
  float kw9[9];
  #pragma unroll
  for (int q = 0; q < 9; ++q) kw9[q] = dww[ch*9 + q];
  __syncthreads();
  int r = t >> 6, lane = t & 63;
  for (int kx = 0; kx < 3; ++kx){
    int px = lane + kx*64;
    float s = 0.f;
    #pragma unroll
    for (int dy = 0; dy < 3; ++dy){
      #pragma unroll
      for (int dx = -1; dx <= 1; ++dx){
        int xx = px + dx;
        if (xx >= 0 && xx < IMG) s += kw9[dy*3 + dx + 1] * rows[r+dy][xx];
      }
    }
    dwu[(size_t)ch*HWP + (size_t)(y0+r)*IMG + px] = s;
  }
}

// ---------------- K8: channel means + sca ----------------
__global__ __launch_bounds__(256) void k8_mean(const float* __restrict__ outa, float* __restrict__ meanb){
  int ch = blockIdx.x;
  const float4* p = (const float4*)(outa + (size_t)ch*HWP);
  float s = 0.f;
  for (int l = threadIdx.x; l < HWP/4; l += 256){
    float4 v = p[l]; s += v.x+v.y+v.z+v.w;
  }
  __shared__ float red[256];
  red[threadIdx.x] = s; __syncthreads();
  for (int k = 128; k > 0; k >>= 1){
    if (threadIdx.x < k) red[threadIdx.x] += red[threadIdx.x + k];
    __syncthreads();
  }
  if (threadIdx.x == 0) meanb[ch] = red[0] / (float)HWP;
}
__global__ __launch_bounds__(128) void k8b(const float* __restrict__ meanb, const float* __restrict__ scaw,
                                           const float* __restrict__ scab, float* __restrict__ svec){
  int o = threadIdx.x;
  float s = scab[o];
  for (int c = 0; c < HD; ++c) s += scaw[(size_t)o*HD + c]*meanb[c];
  svec[o] = s;
}

// ---------------- K9a: out2z = (projw @ (outa*svec) + dwu) * zbuf ----------------
#define PADX 68
__global__ __launch_bounds__(256) void k9a(
    const float* __restrict__ outa, const float* __restrict__ svec,
    const float* __restrict__ projw, const float* __restrict__ dwu,
    const float* __restrict__ zbuf, float* __restrict__ out2z)
{
  __shared__ float WT[128][128];
  __shared__ float xsv[128][PADX];
  __shared__ float sv[128];
  int t = threadIdx.x;
  if (t < 128) sv[t] = svec[t];
  for (int idx = t; idx < 4096; idx += 256){
    int o = idx & 127; int c4 = (idx >> 7) * 4;
    float4 w = *(const float4*)&projw[(size_t)o*HD + c4];
    WT[c4][o] = w.x; WT[c4+1][o] = w.y; WT[c4+2][o] = w.z; WT[c4+3][o] = w.w;
  }
  int px4 = (t & 15) * 4; int og8 = (t >> 4) * 8;
  for (int tile = 0; tile < 2; ++tile){
    int tid = blockIdx.x * 2 + tile;
    int y = tid / 3, x0 = (tid % 3) * 64;
    size_t sb = (size_t)y*IMG + x0;
    __syncthreads();
    for (int idx = t; idx < 2048; idx += 256){
      int c = idx >> 4; int p4 = (idx & 15) * 4;
      float4 v = *(const float4*)&outa[(size_t)c*HWP + sb + p4];
      float s = sv[c];
      xsv[c][p4] = v.x*s; xsv[c][p4+1] = v.y*s; xsv[c][p4+2] = v.z*s; xsv[c][p4+3] = v.w*s;
    }
    __syncthreads();
    float acc[8][4];
    #pragma unroll
    for (int a = 0; a < 8; ++a){ acc[a][0]=0.f; acc[a][1]=0.f; acc[a][2]=0.f; acc[a][3]=0.f; }
    for (int c = 0; c < 128; ++c){
      float4 xv = *(const float4*)&xsv[c][px4];
      float4 wA = *(const float4*)&WT[c][og8];
      float4 wB = *(const float4*)&WT[c][og8+4];
      float w8[8] = {wA.x,wA.y,wA.z,wA.w,wB.x,wB.y,wB.z,wB.w};
      #pragma unroll
      for (int a = 0; a < 8; ++a){
        acc[a][0] += w8[a]*xv.x; acc[a][1] += w8[a]*xv.y;
        acc[a][2] += w8[a]*xv.z; acc[a][3] += w8[a]*xv.w;
      }
    }
    #pragma unroll
    for (int oo = 0; oo < 8; ++oo){
      int o = og8 + oo;
      size_t off = (size_t)o*HWP + sb + px4;
      float4 d = *(const float4*)&dwu[off];
      float4 z = *(const float4*)&zbuf[off];
      float4 r;
      r.x = (acc[oo][0]+d.x)*z.x; r.y = (acc[oo][1]+d.y)*z.y;
      r.z = (acc[oo][2]+d.z)*z.z; r.w = (acc[oo][3]+d.w)*z.w;
      *(float4*)&out2z[off] = r;
    }
  }
}

// ---------------- K9b: dout = projow @ out2z ----------------
__global__ __launch_bounds__(256) void k9b(
    const float* __restrict__ out2z, const float* __restrict__ projow,
    float* __restrict__ dout, int bsel)
{
  __shared__ float WT2[128][64];
  __shared__ float xsv[128][PADX];
  int t = threadIdx.x;
  for (int idx = t; idx < 2048; idx += 256){
    int o = idx & 63; int c4 = (idx >> 6) * 4;
    float4 w = *(const float4*)&projow[(size_t)o*HD + c4];
    WT2[c4][o] = w.x; WT2[c4+1][o] = w.y; WT2[c4+2][o] = w.z; WT2[c4+3][o] = w.w;
  }
  int px4 = (t & 15) * 4; int og4 = (t >> 4) * 4;
  for (int tile = 0; tile < 2; ++tile){
    int tid = blockIdx.x * 2 + tile;
    int y = tid / 3, x0 = (tid % 3) * 64;
    size_t sb = (size_t)y*IMG + x0;
    __syncthreads();
    for (int idx = t; idx < 2048; idx += 256){
      int c = idx >> 4; int p4 = (idx & 15) * 4;
      float4 v = *(const float4*)&out2z[(size_t)c*HWP + sb + p4];
      xsv[c][p4] = v.x; xsv[c][p4+1] = v.y; xsv[c][p4+2] = v.z; xsv[c][p4+3] = v.w;
    }
    __syncthreads();
    float acc[4][4];
    #pragma unroll
    for (int a = 0; a < 4; ++a){ acc[a][0]=0.f; acc[a][1]=0.f; acc[a][2]=0.f; acc[a][3]=0.f; }
    for (int c = 0; c < 128; ++c){
      float4 xv = *(const float4*)&xsv[c][px4];
      float4 w4 = *(const float4*)&WT2[c][og4];
      float w4a[4] = {w4.x,w4.y,w4.z,w4.w};
      #pragma unroll
      for (int a = 0; a < 4; ++a){
        acc[a][0] += w4a[a]*xv.x; acc[a][1] += w4a[a]*xv.y;
        acc[a][2] += w4a[a]*xv.z; acc[a][3] += w4a[a]*xv.w;
      }
    }
    #pragma unroll
    for (int oo = 0; oo < 4; ++oo){
      int o = og4 + oo;
      float4 r; r.x = acc[oo][0]; r.y = acc[oo][1]; r.z = acc[oo][2]; r.w = acc[oo][3];
      *(float4*)&dout[(size_t)(bsel*CIN + o)*HWP + sb + px4] = r;
    }
  }
}

// ---------------- launch ----------------
extern "C" void kernel_launch(void* const* d_in, const int* in_sizes, int n_in,
                              void* d_out, int out_size, void* d_ws, size_t ws_size,
                              hipStream_t stream)
{
  const float* x     = (const float*)d_in[0];
  const float* wquz  = (const float*)d_in[1];
  const float* wkv   = (const float*)d_in[2];
  const float* temp  = (const float*)d_in[3];
  const float* rtalk = (const float*)d_in[4];
  const float* gtalk = (const float*)d_in[5];
  const float* btw   = (const float*)d_in[6];
  const float* ltw   = (const float*)d_in[7];
  const float* dww   = (const float*)d_in[8];
  const float* projw = (const float*)d_in[9];
  const float* projow= (const float*)d_in[10];
  const float* scaw  = (const float*)d_in[11];
  const float* scab  = (const float*)d_in[12];
  float* dout = (float*)d_out;

  float* ws = (float*)d_ws;
  float* qw    = ws;                  // NQK16
  float* kw    = qw + NQK16;          // NQK16
  float* vw    = kw + NQK16;          // NV32
  float* qg    = vw + NV32;           // NGR
  float* kg    = qg + NGR;            // NGR
  float* qr    = kg + NGR;            // NGR
  float* kr    = qr + NGR;            // NGR
  float* u     = kr + NGR;            // NSP
  float* zbuf  = u + NSP;             // NSP
  float* outa  = zbuf + NSP;          // NSP
  float* attnB = outa + NSP;          // NATTNB (aliased by dwu/out2z after k4)
  float* dwu   = attnB;               // NSP alias
  float* out2z = attnB + NSP;         // NSP alias
  float* attnL = attnB + NATTNB;      // NATTNL
  float* attnG = attnL + NATTNL;      // NATTNG
  float* attnGp= attnG + NATTNG;      // NATTNG
  float* part  = attnGp + NATTNG;     // NPART
  float* attnR = part + NPART;        // NATTNR
  float* attnRp= attnR + NATTNR;      // NATTNR
  float* invqg = attnRp + NATTNR;     // 2048
  float* invkg = invqg + 2048;        // 2048
  float* invqr = invkg + 2048;        // 2048
  float* invkr = invqr + 2048;        // 2048
  float* meanb = invkr + 2048;        // 128
  float* svec  = meanb + 128;         // 128

  for (int b = 0; b < BB; ++b){
    k1_proj<<<IMG*3, 256, 0, stream>>>(x, wquz, wkv, qw, kw, vw, qg, kg, qr, kr, u, zbuf, b);

    kNg<<<NH*KK, 64, 0, stream>>>(qg, kg, invqg, invkg);
    kNr<<<NH*CB, 256, 0, stream>>>(qr, kr, invqr, invkr);

    k3_attnb<<<NH*NWIN, 64, 0, stream>>>(qw, kw, temp, attnB);
    k4_bconv<<<NWIN*KK, 256, 0, stream>>>(attnB, btw, vw, outa);

    k5a<<<NH*NWIN, 64, 0, stream>>>(qw, kw, temp, attnL);
    k5b<<<NWIN, 256, 0, stream>>>(attnL, ltw, vw, outa);

    k6a<<<NH*KK, 256, 0, stream>>>(qg, kg, invqg, invkg, temp, attnG);
    k6b<<<NH*KK, 64, 0, stream>>>(attnG, gtalk, attnGp);
    k6c<<<NH*NWIN, 256, 0, stream>>>(attnGp, vw, outa);

    k7a<<<8*NH*CB, 256, 0, stream>>>(qr, kr, part);
    kRed<<<512, 256, 0, stream>>>(part, invqr, invkr, temp, attnR);
    k7b<<<NH*CB, 256, 0, stream>>>(attnR, rtalk, attnRp);
    k7c<<<NH*NWIN, 256, 0, stream>>>(attnRp, vw, outa);

    k_dw<<<HD*48, 256, 0, stream>>>(u, dww, dwu);

    k8_mean<<<HD, 256, 0, stream>>>(outa, meanb);
    k8b<<<1, 128, 0, stream>>>(meanb, scaw, scab, svec);

    k9a<<<288, 256, 0, stream>>>(outa, svec, projw, dwu, zbuf, out2z);
    k9b<<<288, 256, 0, stream>>>(out2z, projow, dout, b);
  }
}

// Round 5
// 2235.117 us; speedup vs baseline: 1.8496x; 1.0425x over previous
//
#include <hip/hip_runtime.h>
#include <cstdint>
#include <cstddef>

// ---------------- problem constants ----------------
#define BB   4      // batch
#define CIN  64     // input channels
#define HD   128    // h_dim
#define NH   4      // heads
#define CHW  32     // channels per head
#define CB   8      // channels per branch
#define IMG  192    // H = W
#define SSH  4      // shift
#define NWS  24     // windows per side
#define NWIN 576    // windows total
#define KK   64     // window elements (8x8)
#define HWP  (IMG*IMG)

// per-batch buffer sizes (floats)
static const size_t NQK16  = (size_t)NH*NWIN*KK*16;   // 2,359,296 (q/k b+l channels)
static const size_t NV32   = (size_t)NH*NWIN*KK*CHW;  // 4,718,592 (v all channels)
static const size_t NGR    = (size_t)NH*KK*NWIN*CB;   // 1,179,648 (qg/kg/qr/kr)
static const size_t NSP    = (size_t)HD*HWP;          // 4,718,592 spatial 128ch
static const size_t NATTNB = (size_t)NH*NWIN*KK*KK;   // 9,437,184
static const size_t NATTNL = (size_t)NH*NWIN*64;      // 147,456
static const size_t NATTNG = (size_t)NH*KK*64;        // 16,384
static const size_t NATTNR = (size_t)NH*CB*KK*KK;     // 131,072
static const size_t NPART  = (size_t)8*NATTNR;        // 1,048,576

// ---------------- helpers ----------------
__device__ inline float wave_max(float v){
  #pragma unroll
  for (int s=1;s<64;s<<=1) v = fmaxf(v, __shfl_xor(v, s));
  return v;
}
__device__ inline float wave_sum(float v){
  #pragma unroll
  for (int s=1;s<64;s<<=1) v += __shfl_xor(v, s);
  return v;
}
__device__ inline float g8_max(float v){
  v = fmaxf(v, __shfl_xor(v,1)); v = fmaxf(v, __shfl_xor(v,2)); v = fmaxf(v, __shfl_xor(v,4));
  return v;
}
__device__ inline float g8_sum(float v){
  v += __shfl_xor(v,1); v += __shfl_xor(v,2); v += __shfl_xor(v,4);
  return v;
}
// Swin region id for an image coordinate (0..191): [0,184)=0, [184,188)=1, [188,192)=2
__device__ inline int regionc(int y){ return (y < IMG-8) ? 0 : ((y < IMG-4) ? 1 : 2); }

// v layout [h][n][i][c32]
__device__ inline size_t widx(int h,int n,int i,int c){
  return (((size_t)h*NWIN + n)*KK + i)*CHW + c;
}
// q/k b+l layout [h][n][i][c16]
__device__ inline size_t widx16(int h,int n,int i,int c){
  return (((size_t)h*NWIN + n)*KK + i)*16 + c;
}
// g layout [h][i][n][c8]
__device__ inline size_t gidx(int h,int i,int n,int c){
  return (((size_t)(h*KK + i))*NWIN + n)*CB + c;
}
// r layout [h][c][n][i]
__device__ inline size_t ridx(int h,int c,int n,int i){
  return (((size_t)(h*CB + c))*NWIN + n)*KK + i;
}

// ---------------- K1: projections -> q/k/v (split layouts) + u,z (spatial) ----------------
// grid IMG*12 (16-px tiles), 256 threads
__global__ __launch_bounds__(256) void k1_proj(
    const float* __restrict__ x, const float* __restrict__ wquz, const float* __restrict__ wkv,
    float* __restrict__ qw, float* __restrict__ kw, float* __restrict__ vw,
    float* __restrict__ qg, float* __restrict__ kg,
    float* __restrict__ qr, float* __restrict__ kr,
    float* __restrict__ u, float* __restrict__ zbuf, int bsel)
{
  __shared__ float xs[64][20];   // padded: avoids 8-way ds_write bank conflict
  __shared__ int pn[16], pi[16];
  int blk = blockIdx.x;
  int xc = blk % 12, y = blk / 12;
  int x0 = xc*16;
  int t = threadIdx.x;
  {
    int c = t >> 2, p4 = (t & 3)*4;
    float4 v = *(const float4*)&x[((size_t)(bsel*CIN+c)*IMG + y)*IMG + x0 + p4];
    *(float4*)&xs[c][p4] = v;
  }
  if (t < 16){
    int py  = (y + IMG - SSH) % IMG;
    int pxx = (x0 + t + IMG - SSH) % IMG;
    pn[t] = (py>>3)*NWS + (pxx>>3);
    pi[t] = (py&7)*8 + (pxx&7);
  }
  __syncthreads();

  for (int oi = 0; oi < 3; ++oi){
    if (oi == 2 && t >= 128) break;
    int o = (oi == 0) ? t : (oi == 1 ? t + 384 : t + 256);
    const float* wr = (o < 384) ? (wquz + (size_t)o*CIN) : (wkv + (size_t)(o-384)*CIN);
    float acc[16];
    #pragma unroll
    for (int p = 0; p < 16; ++p) acc[p] = 0.f;
    for (int cc = 0; cc < 64; cc += 4){
      float4 w4 = *(const float4*)(wr + cc);
      #pragma unroll
      for (int p = 0; p < 16; ++p){
        acc[p] += w4.x * xs[cc  ][p];
        acc[p] += w4.y * xs[cc+1][p];
        acc[p] += w4.z * xs[cc+2][p];
        acc[p] += w4.w * xs[cc+3][p];
      }
    }
    #pragma unroll
    for (int p = 0; p < 16; ++p){
      float val = acc[p];
      if (o < 128){                       // q
        int h = o >> 5, c = o & 31;
        if (c < 16)      qw[widx16(h,pn[p],pi[p],c)] = val;
        else if (c < 24) qg[gidx(h,pi[p],pn[p],c-16)] = val;
        else             qr[ridx(h,c-24,pn[p],pi[p])] = val;
      } else if (o < 256){                // u
        u[((size_t)(o-128)*IMG + y)*IMG + x0 + p] = val;
      } else if (o < 384){                // z
        zbuf[((size_t)(o-256)*IMG + y)*IMG + x0 + p] = val;
      } else if (o < 512){                // k
        int oc = o - 384; int h = oc >> 5, c = oc & 31;
        if (c < 16)      kw[widx16(h,pn[p],pi[p],c)] = val;
        else if (c < 24) kg[gidx(h,pi[p],pn[p],c-16)] = val;
        else             kr[ridx(h,c-24,pn[p],pi[p])] = val;
      } else {                            // v
        int oc = o - 512; int h = oc >> 5, c = oc & 31;
        vw[widx(h,pn[p],pi[p],c)] = val;
      }
    }
  }
}

// ---------------- kNg: inverse L2 norms over n for g-branch ----------------
// grid NH*KK (h,i), 64 threads
__global__ __launch_bounds__(64) void kNg(
    const float* __restrict__ qg, const float* __restrict__ kg,
    float* __restrict__ invqg, float* __restrict__ invkg)
{
  int i = blockIdx.x & 63, h = blockIdx.x >> 6;
  size_t base = ((size_t)(h*KK+i))*NWIN*CB;
  int t = threadIdx.x, c = t & 7, ng = t >> 3;
  float sq = 0.f, sk2 = 0.f;
  for (int n = ng; n < NWIN; n += 8){
    float a = qg[base + (size_t)n*CB + c]; sq  += a*a;
    float b = kg[base + (size_t)n*CB + c]; sk2 += b*b;
  }
  #pragma unroll
  for (int m = 8; m < 64; m <<= 1){ sq += __shfl_xor(sq,m); sk2 += __shfl_xor(sk2,m); }
  if (t < 8){
    invqg[(h*KK+i)*CB + c] = 1.f/fmaxf(sqrtf(sq), 1e-12f);
    invkg[(h*KK+i)*CB + c] = 1.f/fmaxf(sqrtf(sk2),1e-12f);
  }
}

// ---------------- kNr: inverse L2 norms over n for r-branch ----------------
// grid NH*CB (h,c), 256 threads
__global__ __launch_bounds__(256) void kNr(
    const float* __restrict__ qr, const float* __restrict__ kr,
    float* __restrict__ invqr, float* __restrict__ invkr)
{
  int hc = blockIdx.x;
  size_t base = (size_t)hc*NWIN*KK;
  int t = threadIdx.x, i = t & 63, ng = t >> 6;
  float sq = 0.f, sk2 = 0.f;
  for (int n = ng; n < NWIN; n += 4){
    float a = qr[base + (size_t)n*KK + i]; sq  += a*a;
    float b = kr[base + (size_t)n*KK + i]; sk2 += b*b;
  }
  __shared__ float rq[4][64], rk[4][64];
  rq[ng][i] = sq; rk[ng][i] = sk2;
  __syncthreads();
  if (t < 64){
    float s = rq[0][t]+rq[1][t]+rq[2][t]+rq[3][t];
    invqr[hc*KK + t] = 1.f/fmaxf(sqrtf(s),1e-12f);
  } else if (t < 128){
    int i2 = t - 64;
    float s = rk[0][i2]+rk[1][i2]+rk[2][i2]+rk[3][i2];
    invkr[hc*KK + i2] = 1.f/fmaxf(sqrtf(s),1e-12f);
  }
}

// ---------------- K3: attn_b = norm(qb)@norm(kb)^T * temp (norm fused) ----------------
// grid NH*NWIN/4 = 576, 256 threads (one window per wave)
__global__ __launch_bounds__(256) void k3_attnb(
    const float* __restrict__ qw, const float* __restrict__ kw,
    const float* __restrict__ temp, float* __restrict__ attnB)
{
  __shared__ float qs[4][KK][CB];
  int t = threadIdx.x;
  int wv = t >> 6, j = t & 63;
  int gid = blockIdx.x*4 + wv;      // == h*NWIN + n
  int n = gid % NWIN, h = gid / NWIN;
  size_t base = widx16(h,n,j,0);
  float q8[CB], k8[CB];
  float sq = 0.f, sk2 = 0.f;
  #pragma unroll
  for (int c = 0; c < CB; ++c){
    q8[c] = qw[base+c]; sq += q8[c]*q8[c];
    k8[c] = kw[base+c]; sk2 += k8[c]*k8[c];
  }
  float invq = 1.f/fmaxf(sqrtf(sq),1e-12f), invk = 1.f/fmaxf(sqrtf(sk2),1e-12f);
  #pragma unroll
  for (int c = 0; c < CB; ++c){ qs[wv][j][c] = q8[c]*invq; k8[c] *= invk; }
  __syncthreads();
  float tmp = temp[h];
  float* orow = attnB + (size_t)gid*KK*KK;
  for (int i = 0; i < KK; ++i){
    float a = 0.f;
    #pragma unroll
    for (int c = 0; c < CB; ++c) a += qs[wv][i][c]*k8[c];
    orow[(size_t)i*KK + j] = a * tmp;
  }
}

// ---------------- K4: b-branch talk-conv + mask + softmax + PV, fused ----------------
// grid KK*NWIN with i SLOW
__global__ __launch_bounds__(256) void k4_bconv(
    const float* __restrict__ attnB, const float* __restrict__ wtalk,
    const float* __restrict__ vw, float* __restrict__ outa)
{
  int i = blockIdx.x / NWIN, n = blockIdx.x % NWIN;
  int hw = n / NWS, ww = n % NWS;
  __shared__ float rows[NH][9][KK];
  __shared__ float wt[NH*NH*9];
  int t = threadIdx.x;
  if (t < NH*NH*9) wt[t] = wtalk[t];
  for (int l = t; l < NH*9*KK; l += 256){
    int h = l / (9*KK); int nb = (l / KK) % 9; int j = l & 63;
    int dy = nb/3 - 1, dx = nb%3 - 1;
    int hw2 = hw + dy, ww2 = ww + dx;
    float v = 0.f;
    if (hw2 >= 0 && hw2 < NWS && ww2 >= 0 && ww2 < NWS)
      v = attnB[((size_t)(h*NWIN + hw2*NWS + ww2)*KK + i)*KK + j];
    rows[h][nb][j] = v;
  }
  __syncthreads();
  int wv = t >> 6;
  int j  = t & 63;
  float a = 0.f;
  #pragma unroll
  for (int h = 0; h < NH; ++h)
    #pragma unroll
    for (int nb = 0; nb < 9; ++nb)
      a += wt[(wv*NH + h)*9 + nb] * rows[h][nb][j];
  int kh = i >> 3, kwd = i & 7;
  int cntI = regionc(hw*8 + kh)*3 + regionc(ww*8 + kwd);
  int cntJ = regionc(hw*8 + (j>>3))*3 + regionc(ww*8 + (j&7));
  if (cntI != cntJ) a -= 100.f;
  float m = wave_max(a);
  float e = __expf(a - m);
  float p = e / wave_sum(e);
  size_t vbase = widx(wv, n, j, 0);
  float pv[CB];
  #pragma unroll
  for (int c = 0; c < CB; ++c) pv[c] = p * vw[vbase + c];
  #pragma unroll
  for (int c = 0; c < CB; ++c) pv[c] = wave_sum(pv[c]);
  if (j == 0){
    int Y = (hw*8 + kh + SSH) % IMG;
    int X = (ww*8 + kwd + SSH) % IMG;
    #pragma unroll
    for (int c = 0; c < CB; ++c)
      outa[((size_t)(wv*CB + c)*IMG + Y)*IMG + X] = pv[c];
  }
}

// ---------------- K5a: attn_l (norm factored out) ----------------
// grid 576, 256 threads (one window per wave)
__global__ __launch_bounds__(256) void k5a(
    const float* __restrict__ qw, const float* __restrict__ kw,
    const float* __restrict__ temp, float* __restrict__ attnL)
{
  __shared__ float qs[4][KK][CB], ks[4][KK][CB];
  __shared__ float invqA[4][CB], invkA[4][CB];
  int t = threadIdx.x;
  int wv = t >> 6, tl = t & 63;
  int gid = blockIdx.x*4 + wv;      // == h*NWIN + n
  int n = gid % NWIN, h = gid / NWIN;
  size_t base = widx16(h,n,tl,8);
  #pragma unroll
  for (int c = 0; c < CB; ++c){ qs[wv][tl][c] = qw[base+c]; ks[wv][tl][c] = kw[base+c]; }
  __syncthreads();
  int c8 = tl & 7, ig = tl >> 3;
  float sq = 0.f, sk2 = 0.f;
  for (int i = ig; i < KK; i += 8){
    float a = qs[wv][i][c8]; sq += a*a;
    float b = ks[wv][i][c8]; sk2 += b*b;
  }
  #pragma unroll
  for (int m = 8; m < 64; m <<= 1){ sq += __shfl_xor(sq,m); sk2 += __shfl_xor(sk2,m); }
  if (tl < 8){ invqA[wv][tl] = 1.f/fmaxf(sqrtf(sq),1e-12f); invkA[wv][tl] = 1.f/fmaxf(sqrtf(sk2),1e-12f); }
  __syncthreads();
  int c = tl >> 3, d = tl & 7;
  float a = 0.f;
  for (int i = 0; i < KK; ++i) a += qs[wv][i][c]*ks[wv][i][d];
  attnL[(size_t)gid*64 + tl] = a * invqA[wv][c] * invkA[wv][d] * temp[NH + h];
}

// ---------------- K5b: l-branch talk-conv + softmax(d) + PV ----------------
__global__ __launch_bounds__(256) void k5b(
    const float* __restrict__ attnL, const float* __restrict__ wtalk,
    const float* __restrict__ vw, float* __restrict__ outa)
{
  int n = blockIdx.x;
  int hw = n/NWS, ww = n%NWS;
  __shared__ float rows[NH][9][64];
  __shared__ float wt[NH*NH*9];
  __shared__ float P[NH][CB][CB];
  int t = threadIdx.x;
  if (t < NH*NH*9) wt[t] = wtalk[t];
  for (int l = t; l < NH*9*64; l += 256){
    int h = l/(9*64); int nb = (l/64)%9; int cd = l & 63;
    int dy = nb/3-1, dx = nb%3-1; int hw2 = hw+dy, ww2 = ww+dx;
    float v = 0.f;
    if (hw2>=0 && hw2<NWS && ww2>=0 && ww2<NWS)
      v = attnL[((size_t)h*NWIN + hw2*NWS + ww2)*64 + cd];
    rows[h][nb][cd] = v;
  }
  __syncthreads();
  int tt = t >> 6; int cd = t & 63; int c = cd >> 3, d = cd & 7;
  float a = 0.f;
  #pragma unroll
  for (int h = 0; h < NH; ++h)
    #pragma unroll
    for (int nb = 0; nb < 9; ++nb)
      a += wt[(tt*NH + h)*9 + nb] * rows[h][nb][cd];
  float m = g8_max(a);
  float e = __expf(a - m);
  P[tt][c][d] = e / g8_sum(e);
  __syncthreads();
  int i = t & 63;
  size_t vbase = widx(tt, n, i, 8);
  float vl[CB];
  #pragma unroll
  for (int d2 = 0; d2 < CB; ++d2) vl[d2] = vw[vbase + d2];
  int kh = i>>3, kwd = i&7;
  int Y = (hw*8+kh+SSH)%IMG, X = (ww*8+kwd+SSH)%IMG;
  #pragma unroll
  for (int c2 = 0; c2 < CB; ++c2){
    float o = 0.f;
    #pragma unroll
    for (int d2 = 0; d2 < CB; ++d2) o += P[tt][c2][d2]*vl[d2];
    outa[((size_t)(32 + tt*CB + c2)*IMG + Y)*IMG + X] = o;
  }
}

// ---------------- K6a: attn_g[h,i,c,d] = sum_n qg*kg (coalesced layout) ----------------
// grid NH*KK, 256 threads
__global__ __launch_bounds__(256) void k6a(
    const float* __restrict__ qg, const float* __restrict__ kg,
    const float* __restrict__ invqg, const float* __restrict__ invkg,
    const float* __restrict__ temp, float* __restrict__ attnG)
{
  int i = blockIdx.x & 63, h = blockIdx.x >> 6;
  __shared__ float sq[64*8], sk[64*8];
  __shared__ float red[4][64];
  int t = threadIdx.x;
  size_t base = ((size_t)(h*KK+i))*NWIN*CB;
  int np = t >> 6, cd = t & 63, c = cd >> 3, d = cd & 7;
  float a = 0.f;
  for (int n0 = 0; n0 < NWIN; n0 += 64){
    __syncthreads();
    for (int idx = t; idx < 512; idx += 256){
      sq[idx] = qg[base + (size_t)n0*CB + idx];
      sk[idx] = kg[base + (size_t)n0*CB + idx];
    }
    __syncthreads();
    for (int nn = np; nn < 64; nn += 4) a += sq[nn*8+c]*sk[nn*8+d];
  }
  __syncthreads();
  red[np][cd] = a;
  __syncthreads();
  if (t < 64){
    float tot = red[0][t]+red[1][t]+red[2][t]+red[3][t];
    tot *= invqg[(h*KK+i)*CB + (t>>3)] * invkg[(h*KK+i)*CB + (t&7)] * temp[2*NH + h];
    attnG[(size_t)(h*KK+i)*64 + t] = tot;
  }
}

// ---------------- K6b: g talking + softmax(d) ----------------
__global__ __launch_bounds__(64) void k6b(
    const float* __restrict__ attnG, const float* __restrict__ gtalk, float* __restrict__ attnGp)
{
  int l = blockIdx.x % KK; int t2 = blockIdx.x / KK;
  int cd = threadIdx.x;
  float a = 0.f;
  for (int h = 0; h < NH; ++h)
    for (int k = 0; k < KK; ++k)
      a += gtalk[((size_t)(h*KK + k)*KK + l)*NH + t2] * attnG[((size_t)h*KK + k)*64 + cd];
  float m = g8_max(a);
  float e = __expf(a - m);
  attnGp[((size_t)t2*KK + l)*64 + cd] = e / g8_sum(e);
}

// ---------------- K6c: out_g PV ----------------
__global__ __launch_bounds__(256) void k6c(
    const float* __restrict__ attnGp, const float* __restrict__ vw, float* __restrict__ outa)
{
  int n = blockIdx.x % NWIN; int t2 = blockIdx.x / NWIN;
  __shared__ float P[KK*64];
  int t = threadIdx.x;
  for (int l = t; l < KK*64; l += 256) P[l] = attnGp[(size_t)t2*KK*64 + l];
  __syncthreads();
  int i = t >> 2; int c0 = (t & 3)*2;
  size_t vbase = widx(t2, n, i, 16);
  float vg[8];
  #pragma unroll
  for (int d = 0; d < 8; ++d) vg[d] = vw[vbase + d];
  int hw = n/NWS, ww = n%NWS; int kh = i>>3, kwd = i&7;
  int Y = (hw*8+kh+SSH)%IMG, X = (ww*8+kwd+SSH)%IMG;
  for (int c = c0; c < c0+2; ++c){
    float o = 0.f;
    #pragma unroll
    for (int d = 0; d < 8; ++d) o += P[(i*8 + c)*8 + d]*vg[d];
    outa[((size_t)(64 + t2*CB + c)*IMG + Y)*IMG + X] = o;
  }
}

// ---------------- K7a: r-branch Gram partials over n-chunks ----------------
// grid 8 chunks x NH*CB, 256 threads
__global__ __launch_bounds__(256) void k7a(
    const float* __restrict__ qr, const float* __restrict__ kr, float* __restrict__ part)
{
  int chunk = blockIdx.x >> 5, hc = blockIdx.x & 31;
  int n0 = chunk*72;
  __shared__ float sq[72*64], sk[72*64];
  int t = threadIdx.x;
  size_t base = (size_t)hc*NWIN*KK + (size_t)n0*KK;
  for (int idx = t; idx < 72*64/4; idx += 256){
    *(float4*)&sq[idx*4] = *(const float4*)&qr[base + (size_t)idx*4];
    *(float4*)&sk[idx*4] = *(const float4*)&kr[base + (size_t)idx*4];
  }
  __syncthreads();
  int j = t & 63, ig = t >> 6;
  float acc[16];
  #pragma unroll
  for (int p = 0; p < 16; ++p) acc[p] = 0.f;
  for (int nn = 0; nn < 72; ++nn){
    float kv = sk[nn*64+j];
    #pragma unroll
    for (int p = 0; p < 16; ++p) acc[p] += sq[nn*64 + ig*16 + p]*kv;
  }
  float* ob = part + (size_t)blockIdx.x*4096;
  #pragma unroll
  for (int p = 0; p < 16; ++p) ob[(size_t)(ig*16+p)*64 + j] = acc[p];
}

// ---------------- kRed: sum partials * norms * temp -> attnR ----------------
// grid 512, 256 threads
__global__ __launch_bounds__(256) void kRed(
    const float* __restrict__ part, const float* __restrict__ invqr,
    const float* __restrict__ invkr, const float* __restrict__ temp,
    float* __restrict__ attnR)
{
  int e = blockIdx.x*256 + threadIdx.x;
  float s = 0.f;
  #pragma unroll
  for (int ch = 0; ch < 8; ++ch) s += part[(size_t)ch*NATTNR + e];
  int hc = e >> 12, ij = e & 4095, i = ij >> 6, j = ij & 63;
  attnR[e] = s * invqr[hc*64+i] * invkr[hc*64+j] * temp[3*NH + (hc>>3)];
}

// ---------------- K7b: r talking + softmax(j) ----------------
__global__ __launch_bounds__(256) void k7b(
    const float* __restrict__ attnR, const float* __restrict__ rtalk, float* __restrict__ attnRp)
{
  int d = blockIdx.x % CB; int t2 = blockIdx.x / CB;
  __shared__ float S[64][64];
  __shared__ float wr2[32];
  int t = threadIdx.x;
  if (t < 32){ int h = t >> 3, c = t & 7; wr2[t] = rtalk[((size_t)(h*CB + c)*CB + d)*NH + t2]; }
  __syncthreads();
  int j = t & 63; int ig = t >> 6;
  float acc[16];
  #pragma unroll
  for (int p = 0; p < 16; ++p) acc[p] = 0.f;
  for (int hc = 0; hc < 32; ++hc){
    float w = wr2[hc];
    const float* Ar = attnR + (size_t)hc*KK*KK;
    #pragma unroll
    for (int p = 0; p < 16; ++p) acc[p] += w * Ar[(size_t)(ig*16+p)*KK + j];
  }
  #pragma unroll
  for (int p = 0; p < 16; ++p) S[ig*16+p][j] = acc[p];
  __syncthreads();
  for (int r = ig; r < 64; r += 4){
    float a = S[r][j];
    float m = wave_max(a);
    float e = __expf(a - m);
    attnRp[(((size_t)t2*CB + d)*KK + r)*KK + j] = e / wave_sum(e);
  }
}

// ---------------- K7c: out_r PV ----------------
__global__ __launch_bounds__(256) void k7c(
    const float* __restrict__ attnRp, const float* __restrict__ vw, float* __restrict__ outa)
{
  int n = blockIdx.x % NWIN; int t2 = blockIdx.x / NWIN;
  __shared__ float vr[KK][CB];
  int t = threadIdx.x;
  for (int l = t; l < KK*CB; l += 256){
    int j = l >> 3, c = l & 7;
    vr[j][c] = vw[widx(t2, n, j, 24 + c)];
  }
  __syncthreads();
  int i = t & 63; int cg = t >> 6;
  int hw = n/NWS, ww = n%NWS; int kh = i>>3, kwd = i&7;
  int Y = (hw*8+kh+SSH)%IMG, X = (ww*8+kwd+SSH)%IMG;
  for (int c = cg*2; c < cg*2+2; ++c){
    const float* Pr = attnRp + (((size_t)t2*CB + c)*KK + i)*KK;
    float o = 0.f;
    for (int j = 0; j < KK; ++j) o += Pr[j]*vr[j][c];
    outa[((size_t)(96 + t2*CB + c)*IMG + Y)*IMG + X] = o;
  }
}

// ---------------- K_dw: depthwise 3x3 over u -> dwu ----------------
__global__ __launch_bounds__(256) void k_dw(
    const float* __restrict__ u, const float* __restrict__ dww, float* __restrict__ dwu)
{
  int ch = blockIdx.x / 48; int y0 = (blockIdx.x % 48) * 4;
  __shared__ float rows[6][192];
  int t = threadIdx.x;
  for (int idx = t; idx < 6*48; idx += 256){
    int r = idx / 48, px4 = (idx % 48)*4;
    int yy = y0 - 1 + r;
    float4 v = {0.f,0.f,0.f,0.f};
    if (yy >= 0 && yy < IMG) v = *(const float4*)&u[(size_t)ch*HWP + (size_t)yy*IMG + px4];
    rows[r][px4] = v.x; rows[r][px4+1] = v.y; rows[r][px4+2] = v.z; rows[r][px4+3] = v.w;
  }
  float kw9[9];
  #pragma unroll
  for (int q = 0; q < 9; ++q) kw9[q] = dww[ch*9 + q];
  __syncthreads();
  int r = t >> 6, lane = t & 63;
  for (int kx = 0; kx < 3; ++kx){
    int px = lane + kx*64;
    float s = 0.f;
    #pragma unroll
    for (int dy = 0; dy < 3; ++dy){
      #pragma unroll
      for (int dx = -1; dx <= 1; ++dx){
        int xx = px + dx;
        if (xx >= 0 && xx < IMG) s += kw9[dy*3 + dx + 1] * rows[r+dy][xx];
      }
    }
    dwu[(size_t)ch*HWP + (size_t)(y0+r)*IMG + px] = s;
  }
}

// ---------------- K8: channel means ----------------
__global__ __launch_bounds__(256) void k8_mean(const float* __restrict__ outa, float* __restrict__ meanb){
  int ch = blockIdx.x;
  const float4* p = (const float4*)(outa + (size_t)ch*HWP);
  float s = 0.f;
  for (int l = threadIdx.x; l < HWP/4; l += 256){
    float4 v = p[l]; s += v.x+v.y+v.z+v.w;
  }
  __shared__ float red[256];
  red[threadIdx.x] = s; __syncthreads();
  for (int k = 128; k > 0; k >>= 1){
    if (threadIdx.x < k) red[threadIdx.x] += red[threadIdx.x + k];
    __syncthreads();
  }
  if (threadIdx.x == 0) meanb[ch] = red[0] / (float)HWP;
}

// ---------------- K9a: out2z = (projw @ (outa*svec) + dwu) * zbuf (svec computed in-block) ----------------
#define PADX 68
__global__ __launch_bounds__(256) void k9a(
    const float* __restrict__ outa, const float* __restrict__ meanb,
    const float* __restrict__ scaw, const float* __restrict__ scab,
    const float* __restrict__ projw, const float* __restrict__ dwu,
    const float* __restrict__ zbuf, float* __restrict__ out2z)
{
  __shared__ float WT[128][128];
  __shared__ float xsv[128][PADX];
  __shared__ float sv[128];
  int t = threadIdx.x;
  // svec = scab + scaw @ meanb (redundant per block; 16K FMA)
  if (t < 128){
    float s = scab[t];
    const float* srow = scaw + (size_t)t*HD;
    for (int c = 0; c < HD; c += 4){
      float4 w = *(const float4*)&srow[c];
      float4 mm = *(const float4*)&meanb[c];
      s += w.x*mm.x + w.y*mm.y + w.z*mm.z + w.w*mm.w;
    }
    sv[t] = s;
  }
  for (int idx = t; idx < 4096; idx += 256){
    int o = idx & 127; int c4 = (idx >> 7) * 4;
    float4 w = *(const float4*)&projw[(size_t)o*HD + c4];
    WT[c4][o] = w.x; WT[c4+1][o] = w.y; WT[c4+2][o] = w.z; WT[c4+3][o] = w.w;
  }
  int px4 = (t & 15) * 4; int og8 = (t >> 4) * 8;
  for (int tile = 0; tile < 2; ++tile){
    int tid = blockIdx.x * 2 + tile;
    int y = tid / 3, x0 = (tid % 3) * 64;
    size_t sb = (size_t)y*IMG + x0;
    __syncthreads();
    for (int idx = t; idx < 2048; idx += 256){
      int c = idx >> 4; int p4 = (idx & 15) * 4;
      float4 v = *(const float4*)&outa[(size_t)c*HWP + sb + p4];
      float s = sv[c];
      xsv[c][p4] = v.x*s; xsv[c][p4+1] = v.y*s; xsv[c][p4+2] = v.z*s; xsv[c][p4+3] = v.w*s;
    }
    __syncthreads();
    float acc[8][4];
    #pragma unroll
    for (int a = 0; a < 8; ++a){ acc[a][0]=0.f; acc[a][1]=0.f; acc[a][2]=0.f; acc[a][3]=0.f; }
    for (int c = 0; c < 128; ++c){
      float4 xv = *(const float4*)&xsv[c][px4];
      float4 wA = *(const float4*)&WT[c][og8];
      float4 wB = *(const float4*)&WT[c][og8+4];
      float w8[8] = {wA.x,wA.y,wA.z,wA.w,wB.x,wB.y,wB.z,wB.w};
      #pragma unroll
      for (int a = 0; a < 8; ++a){
        acc[a][0] += w8[a]*xv.x; acc[a][1] += w8[a]*xv.y;
        acc[a][2] += w8[a]*xv.z; acc[a][3] += w8[a]*xv.w;
      }
    }
    #pragma unroll
    for (int oo = 0; oo < 8; ++oo){
      int o = og8 + oo;
      size_t off = (size_t)o*HWP + sb + px4;
      float4 d = *(const float4*)&dwu[off];
      float4 z = *(const float4*)&zbuf[off];
      float4 r;
      r.x = (acc[oo][0]+d.x)*z.x; r.y = (acc[oo][1]+d.y)*z.y;
      r.z = (acc[oo][2]+d.z)*z.z; r.w = (acc[oo][3]+d.w)*z.w;
      *(float4*)&out2z[off] = r;
    }
  }
}

// ---------------- K9b: dout = projow @ out2z ----------------
__global__ __launch_bounds__(256) void k9b(
    const float* __restrict__ out2z, const float* __restrict__ projow,
    float* __restrict__ dout, int bsel)
{
  __shared__ float WT2[128][64];
  __shared__ float xsv[128][PADX];
  int t = threadIdx.x;
  for (int idx = t; idx < 2048; idx += 256){
    int o = idx & 63; int c4 = (idx >> 6) * 4;
    float4 w = *(const float4*)&projow[(size_t)o*HD + c4];
    WT2[c4][o] = w.x; WT2[c4+1][o] = w.y; WT2[c4+2][o] = w.z; WT2[c4+3][o] = w.w;
  }
  int px4 = (t & 15) * 4; int og4 = (t >> 4) * 4;
  for (int tile = 0; tile < 2; ++tile){
    int tid = blockIdx.x * 2 + tile;
    int y = tid / 3, x0 = (tid % 3) * 64;
    size_t sb = (size_t)y*IMG + x0;
    __syncthreads();
    for (int idx = t; idx < 2048; idx += 256){
      int c = idx >> 4; int p4 = (idx & 15) * 4;
      float4 v = *(const float4*)&out2z[(size_t)c*HWP + sb + p4];
      xsv[c][p4] = v.x; xsv[c][p4+1] = v.y; xsv[c][p4+2] = v.z; xsv[c][p4+3] = v.w;
    }
    __syncthreads();
    float acc[4][4];
    #pragma unroll
    for (int a = 0; a < 4; ++a){ acc[a][0]=0.f; acc[a][1]=0.f; acc[a][2]=0.f; acc[a][3]=0.f; }
    for (int c = 0; c < 128; ++c){
      float4 xv = *(const float4*)&xsv[c][px4];
      float4 w4 = *(const float4*)&WT2[c][og4];
      float w4a[4] = {w4.x,w4.y,w4.z,w4.w};
      #pragma unroll
      for (int a = 0; a < 4; ++a){
        acc[a][0] += w4a[a]*xv.x; acc[a][1] += w4a[a]*xv.y;
        acc[a][2] += w4a[a]*xv.z; acc[a][3] += w4a[a]*xv.w;
      }
    }
    #pragma unroll
    for (int oo = 0; oo < 4; ++oo){
      int o = og4 + oo;
      float4 r; r.x = acc[oo][0]; r.y = acc[oo][1]; r.z = acc[oo][2]; r.w = acc[oo][3];
      *(float4*)&dout[(size_t)(bsel*CIN + o)*HWP + sb + px4] = r;
    }
  }
}

// ---------------- launch ----------------
extern "C" void kernel_launch(void* const* d_in, const int* in_sizes, int n_in,
                              void* d_out, int out_size, void* d_ws, size_t ws_size,
                              hipStream_t stream)
{
  const float* x     = (const float*)d_in[0];
  const float* wquz  = (const float*)d_in[1];
  const float* wkv   = (const float*)d_in[2];
  const float* temp  = (const float*)d_in[3];
  const float* rtalk = (const float*)d_in[4];
  const float* gtalk = (const float*)d_in[5];
  const float* btw   = (const float*)d_in[6];
  const float* ltw   = (const float*)d_in[7];
  const float* dww   = (const float*)d_in[8];
  const float* projw = (const float*)d_in[9];
  const float* projow= (const float*)d_in[10];
  const float* scaw  = (const float*)d_in[11];
  const float* scab  = (const float*)d_in[12];
  float* dout = (float*)d_out;

  float* ws = (float*)d_ws;
  float* qw    = ws;                  // NQK16
  float* kw    = qw + NQK16;          // NQK16
  float* vw    = kw + NQK16;          // NV32
  float* qg    = vw + NV32;           // NGR
  float* kg    = qg + NGR;            // NGR
  float* qr    = kg + NGR;            // NGR
  float* kr    = qr + NGR;            // NGR
  float* u     = kr + NGR;            // NSP
  float* zbuf  = u + NSP;             // NSP
  float* outa  = zbuf + NSP;          // NSP
  float* attnB = outa + NSP;          // NATTNB (aliased by dwu/out2z after k4)
  float* dwu   = attnB;               // NSP alias
  float* out2z = attnB + NSP;         // NSP alias
  float* attnL = attnB + NATTNB;      // NATTNL
  float* attnG = attnL + NATTNL;      // NATTNG
  float* attnGp= attnG + NATTNG;      // NATTNG
  float* part  = attnGp + NATTNG;     // NPART
  float* attnR = part + NPART;        // NATTNR
  float* attnRp= attnR + NATTNR;      // NATTNR
  float* invqg = attnRp + NATTNR;     // 2048
  float* invkg = invqg + 2048;        // 2048
  float* invqr = invkg + 2048;        // 2048
  float* invkr = invqr + 2048;        // 2048
  float* meanb = invkr + 2048;        // 128

  for (int b = 0; b < BB; ++b){
    k1_proj<<<IMG*12, 256, 0, stream>>>(x, wquz, wkv, qw, kw, vw, qg, kg, qr, kr, u, zbuf, b);

    kNg<<<NH*KK, 64, 0, stream>>>(qg, kg, invqg, invkg);
    kNr<<<NH*CB, 256, 0, stream>>>(qr, kr, invqr, invkr);

    k3_attnb<<<NH*NWIN/4, 256, 0, stream>>>(qw, kw, temp, attnB);
    k4_bconv<<<NWIN*KK, 256, 0, stream>>>(attnB, btw, vw, outa);

    k5a<<<NH*NWIN/4, 256, 0, stream>>>(qw, kw, temp, attnL);
    k5b<<<NWIN, 256, 0, stream>>>(attnL, ltw, vw, outa);

    k6a<<<NH*KK, 256, 0, stream>>>(qg, kg, invqg, invkg, temp, attnG);
    k6b<<<NH*KK, 64, 0, stream>>>(attnG, gtalk, attnGp);
    k6c<<<NH*NWIN, 256, 0, stream>>>(attnGp, vw, outa);

    k7a<<<8*NH*CB, 256, 0, stream>>>(qr, kr, part);
    kRed<<<512, 256, 0, stream>>>(part, invqr, invkr, temp, attnR);
    k7b<<<NH*CB, 256, 0, stream>>>(attnR, rtalk, attnRp);
    k7c<<<NH*NWIN, 256, 0, stream>>>(attnRp, vw, outa);

    k_dw<<<HD*48, 256, 0, stream>>>(u, dww, dwu);

    k8_mean<<<HD, 256, 0, stream>>>(outa, meanb);

    k9a<<<288, 256, 0, stream>>>(outa, meanb, scaw, scab, projw, dwu, zbuf, out2z);
    k9b<<<288, 256, 0, stream>>>(out2z, projow, dout, b);
  }
}

// Round 6
// 1963.779 us; speedup vs baseline: 2.1052x; 1.1382x over previous
//
#include <hip/hip_runtime.h>
#include <cstdint>
#include <cstddef>

// ---------------- problem constants ----------------
#define BB   4      // batch
#define CIN  64     // input channels
#define HD   128    // h_dim
#define NH   4      // heads
#define CHW  32     // channels per head
#define CB   8      // channels per branch
#define IMG  192    // H = W
#define SSH  4      // shift
#define NWS  24     // windows per side
#define NWIN 576    // windows total
#define KK   64     // window elements (8x8)
#define HWP  (IMG*IMG)

// per-batch buffer sizes (floats)
static const size_t NQK16  = (size_t)NH*NWIN*KK*16;   // 2,359,296 (q/k b+l channels)
static const size_t NV32   = (size_t)NH*NWIN*KK*CHW;  // 4,718,592 (v all channels)
static const size_t NGR    = (size_t)NH*KK*NWIN*CB;   // 1,179,648 (qg/kg/qr/kr)
static const size_t NSP    = (size_t)HD*HWP;          // 4,718,592 spatial 128ch
static const size_t NATTNB = (size_t)NH*NWIN*KK*KK;   // 9,437,184
static const size_t NATTNL = (size_t)NH*NWIN*64;      // 147,456
static const size_t NATTNG = (size_t)NH*KK*64;        // 16,384
static const size_t NATTNR = (size_t)NH*CB*KK*KK;     // 131,072
static const size_t NPART  = (size_t)8*NATTNR;        // 1,048,576

// ---------------- helpers ----------------
__device__ inline float wave_max(float v){
  #pragma unroll
  for (int s=1;s<64;s<<=1) v = fmaxf(v, __shfl_xor(v, s));
  return v;
}
__device__ inline float wave_sum(float v){
  #pragma unroll
  for (int s=1;s<64;s<<=1) v += __shfl_xor(v, s);
  return v;
}
__device__ inline float g8_max(float v){
  v = fmaxf(v, __shfl_xor(v,1)); v = fmaxf(v, __shfl_xor(v,2)); v = fmaxf(v, __shfl_xor(v,4));
  return v;
}
__device__ inline float g8_sum(float v){
  v += __shfl_xor(v,1); v += __shfl_xor(v,2); v += __shfl_xor(v,4);
  return v;
}
// Swin region id for an image coordinate (0..191): [0,184)=0, [184,188)=1, [188,192)=2
__device__ inline int regionc(int y){ return (y < IMG-8) ? 0 : ((y < IMG-4) ? 1 : 2); }

// v layout [h][n][i][c32]
__device__ inline size_t widx(int h,int n,int i,int c){
  return (((size_t)h*NWIN + n)*KK + i)*CHW + c;
}
// q/k b+l layout [h][n][i][c16]
__device__ inline size_t widx16(int h,int n,int i,int c){
  return (((size_t)h*NWIN + n)*KK + i)*16 + c;
}
// g layout [h][i][n][c8]
__device__ inline size_t gidx(int h,int i,int n,int c){
  return (((size_t)(h*KK + i))*NWIN + n)*CB + c;
}
// r layout [h][c][n][i]
__device__ inline size_t ridx(int h,int c,int n,int i){
  return (((size_t)(h*CB + c))*NWIN + n)*KK + i;
}

// ---------------- K1: projections -> q/k/v (split layouts) + u,z (spatial) ----------------
// grid IMG*12 (16-px tiles), 256 threads
__global__ __launch_bounds__(256) void k1_proj(
    const float* __restrict__ x, const float* __restrict__ wquz, const float* __restrict__ wkv,
    float* __restrict__ qw, float* __restrict__ kw, float* __restrict__ vw,
    float* __restrict__ qg, float* __restrict__ kg,
    float* __restrict__ qr, float* __restrict__ kr,
    float* __restrict__ u, float* __restrict__ zbuf, int bsel)
{
  __shared__ float xs[64][20];   // padded: avoids 8-way ds_write bank conflict
  __shared__ int pn[16], pi[16];
  int blk = blockIdx.x;
  int xc = blk % 12, y = blk / 12;
  int x0 = xc*16;
  int t = threadIdx.x;
  {
    int c = t >> 2, p4 = (t & 3)*4;
    float4 v = *(const float4*)&x[((size_t)(bsel*CIN+c)*IMG + y)*IMG + x0 + p4];
    *(float4*)&xs[c][p4] = v;
  }
  if (t < 16){
    int py  = (y + IMG - SSH) % IMG;
    int pxx = (x0 + t + IMG - SSH) % IMG;
    pn[t] = (py>>3)*NWS + (pxx>>3);
    pi[t] = (py&7)*8 + (pxx&7);
  }
  __syncthreads();

  for (int oi = 0; oi < 3; ++oi){
    if (oi == 2 && t >= 128) break;
    int o = (oi == 0) ? t : (oi == 1 ? t + 384 : t + 256);
    const float* wr = (o < 384) ? (wquz + (size_t)o*CIN) : (wkv + (size_t)(o-384)*CIN);
    float acc[16];
    #pragma unroll
    for (int p = 0; p < 16; ++p) acc[p] = 0.f;
    for (int cc = 0; cc < 64; cc += 4){
      float4 w4 = *(const float4*)(wr + cc);
      #pragma unroll
      for (int p = 0; p < 16; ++p){
        acc[p] += w4.x * xs[cc  ][p];
        acc[p] += w4.y * xs[cc+1][p];
        acc[p] += w4.z * xs[cc+2][p];
        acc[p] += w4.w * xs[cc+3][p];
      }
    }
    #pragma unroll
    for (int p = 0; p < 16; ++p){
      float val = acc[p];
      if (o < 128){                       // q
        int h = o >> 5, c = o & 31;
        if (c < 16)      qw[widx16(h,pn[p],pi[p],c)] = val;
        else if (c < 24) qg[gidx(h,pi[p],pn[p],c-16)] = val;
        else             qr[ridx(h,c-24,pn[p],pi[p])] = val;
      } else if (o < 256){                // u
        u[((size_t)(o-128)*IMG + y)*IMG + x0 + p] = val;
      } else if (o < 384){                // z
        zbuf[((size_t)(o-256)*IMG + y)*IMG + x0 + p] = val;
      } else if (o < 512){                // k
        int oc = o - 384; int h = oc >> 5, c = oc & 31;
        if (c < 16)      kw[widx16(h,pn[p],pi[p],c)] = val;
        else if (c < 24) kg[gidx(h,pi[p],pn[p],c-16)] = val;
        else             kr[ridx(h,c-24,pn[p],pi[p])] = val;
      } else {                            // v
        int oc = o - 512; int h = oc >> 5, c = oc & 31;
        vw[widx(h,pn[p],pi[p],c)] = val;
      }
    }
  }
}

// ---------------- kNg: inverse L2 norms over n for g-branch ----------------
// grid NH*KK (h,i), 64 threads
__global__ __launch_bounds__(64) void kNg(
    const float* __restrict__ qg, const float* __restrict__ kg,
    float* __restrict__ invqg, float* __restrict__ invkg)
{
  int i = blockIdx.x & 63, h = blockIdx.x >> 6;
  size_t base = ((size_t)(h*KK+i))*NWIN*CB;
  int t = threadIdx.x, c = t & 7, ng = t >> 3;
  float sq = 0.f, sk2 = 0.f;
  for (int n = ng; n < NWIN; n += 8){
    float a = qg[base + (size_t)n*CB + c]; sq  += a*a;
    float b = kg[base + (size_t)n*CB + c]; sk2 += b*b;
  }
  #pragma unroll
  for (int m = 8; m < 64; m <<= 1){ sq += __shfl_xor(sq,m); sk2 += __shfl_xor(sk2,m); }
  if (t < 8){
    invqg[(h*KK+i)*CB + c] = 1.f/fmaxf(sqrtf(sq), 1e-12f);
    invkg[(h*KK+i)*CB + c] = 1.f/fmaxf(sqrtf(sk2),1e-12f);
  }
}

// ---------------- kNr: inverse L2 norms over n for r-branch ----------------
// grid NH*CB (h,c), 256 threads
__global__ __launch_bounds__(256) void kNr(
    const float* __restrict__ qr, const float* __restrict__ kr,
    float* __restrict__ invqr, float* __restrict__ invkr)
{
  int hc = blockIdx.x;
  size_t base = (size_t)hc*NWIN*KK;
  int t = threadIdx.x, i = t & 63, ng = t >> 6;
  float sq = 0.f, sk2 = 0.f;
  for (int n = ng; n < NWIN; n += 4){
    float a = qr[base + (size_t)n*KK + i]; sq  += a*a;
    float b = kr[base + (size_t)n*KK + i]; sk2 += b*b;
  }
  __shared__ float rq[4][64], rk[4][64];
  rq[ng][i] = sq; rk[ng][i] = sk2;
  __syncthreads();
  if (t < 64){
    float s = rq[0][t]+rq[1][t]+rq[2][t]+rq[3][t];
    invqr[hc*KK + t] = 1.f/fmaxf(sqrtf(s),1e-12f);
  } else if (t < 128){
    int i2 = t - 64;
    float s = rk[0][i2]+rk[1][i2]+rk[2][i2]+rk[3][i2];
    invkr[hc*KK + i2] = 1.f/fmaxf(sqrtf(s),1e-12f);
  }
}

// ---------------- K3: attn_b = norm(qb)@norm(kb)^T * temp (norm fused) ----------------
// grid NH*NWIN/4 = 576, 256 threads (one window per wave)
__global__ __launch_bounds__(256) void k3_attnb(
    const float* __restrict__ qw, const float* __restrict__ kw,
    const float* __restrict__ temp, float* __restrict__ attnB)
{
  __shared__ float qs[4][KK][CB];
  int t = threadIdx.x;
  int wv = t >> 6, j = t & 63;
  int gid = blockIdx.x*4 + wv;      // == h*NWIN + n
  int n = gid % NWIN, h = gid / NWIN;
  size_t base = widx16(h,n,j,0);
  float q8[CB], k8[CB];
  float sq = 0.f, sk2 = 0.f;
  #pragma unroll
  for (int c = 0; c < CB; ++c){
    q8[c] = qw[base+c]; sq += q8[c]*q8[c];
    k8[c] = kw[base+c]; sk2 += k8[c]*k8[c];
  }
  float invq = 1.f/fmaxf(sqrtf(sq),1e-12f), invk = 1.f/fmaxf(sqrtf(sk2),1e-12f);
  #pragma unroll
  for (int c = 0; c < CB; ++c){ qs[wv][j][c] = q8[c]*invq; k8[c] *= invk; }
  __syncthreads();
  float tmp = temp[h];
  float* orow = attnB + (size_t)gid*KK*KK;
  for (int i = 0; i < KK; ++i){
    float a = 0.f;
    #pragma unroll
    for (int c = 0; c < CB; ++c) a += qs[wv][i][c]*k8[c];
    orow[(size_t)i*KK + j] = a * tmp;
  }
}

// ---------------- K4: b-branch talk-conv + mask + softmax + PV, fused ----------------
// grid 16*NWIN (i-group SLOW, n fast for L2 locality), 256 threads
__global__ __launch_bounds__(256) void k4_bconv(
    const float* __restrict__ attnB, const float* __restrict__ wtalk,
    const float* __restrict__ vw, float* __restrict__ outa)
{
  int ig = blockIdx.x / NWIN, n = blockIdx.x % NWIN;
  int i0 = ig*4;
  int hw = n / NWS, ww = n % NWS;
  __shared__ float rows[4][9][4][64];   // [h][nb][i_local][j]
  __shared__ float pbuf[4][4][66];      // [wv][i_local][j] padded
  __shared__ float vv[4][8][66];        // [wv][c][j] padded
  int t = threadIdx.x;
  int w = t >> 6, l = t & 63;

  // Phase 1a: load 9-neighbor rows (wave = input head h = w)
  {
    int li = l >> 4, j4 = (l & 15)*4;
    #pragma unroll
    for (int nb = 0; nb < 9; ++nb){
      const int dy = nb/3 - 1, dx = nb%3 - 1;
      int hw2 = hw + dy, ww2 = ww + dx;
      float4 v = {0.f,0.f,0.f,0.f};
      if (hw2 >= 0 && hw2 < NWS && ww2 >= 0 && ww2 < NWS){
        int n2 = hw2*NWS + ww2;
        v = *(const float4*)&attnB[((size_t)(w*NWIN + n2)*KK + i0 + li)*KK + j4];
      }
      *(float4*)&rows[w][nb][li][j4] = v;
    }
  }
  // Phase 1b: stage V (wave = head)
  {
    size_t vb = widx(w, n, l, 0);
    float4 va = *(const float4*)&vw[vb];
    float4 vb4 = *(const float4*)&vw[vb + 4];
    vv[w][0][l] = va.x;  vv[w][1][l] = va.y;  vv[w][2][l] = va.z;  vv[w][3][l] = va.w;
    vv[w][4][l] = vb4.x; vv[w][5][l] = vb4.y; vv[w][6][l] = vb4.z; vv[w][7][l] = vb4.w;
  }
  __syncthreads();

  // Phase 2: conv (wave = local i); thread computes all 4 output heads
  int i = i0 + w;
  float a0 = 0.f, a1 = 0.f, a2 = 0.f, a3 = 0.f;
  #pragma unroll
  for (int h = 0; h < 4; ++h){
    #pragma unroll
    for (int nb = 0; nb < 9; ++nb){
      float r = rows[h][nb][w][l];
      a0 += wtalk[(0*4 + h)*9 + nb] * r;   // uniform -> scalar loads
      a1 += wtalk[(1*4 + h)*9 + nb] * r;
      a2 += wtalk[(2*4 + h)*9 + nb] * r;
      a3 += wtalk[(3*4 + h)*9 + nb] * r;
    }
  }
  // Phase 3: analytic shifted-window mask + per-head wave softmax
  int kh = i >> 3, kwd = i & 7;
  int cntI = regionc(hw*8 + kh)*3 + regionc(ww*8 + kwd);
  int cntJ = regionc(hw*8 + (l>>3))*3 + regionc(ww*8 + (l&7));
  float mval = (cntI != cntJ) ? -100.f : 0.f;
  a0 += mval; a1 += mval; a2 += mval; a3 += mval;
  {
    float m0 = wave_max(a0); float e0 = __expf(a0 - m0); pbuf[0][w][l] = e0 / wave_sum(e0);
    float m1 = wave_max(a1); float e1 = __expf(a1 - m1); pbuf[1][w][l] = e1 / wave_sum(e1);
    float m2 = wave_max(a2); float e2 = __expf(a2 - m2); pbuf[2][w][l] = e2 / wave_sum(e2);
    float m3 = wave_max(a3); float e3 = __expf(a3 - m3); pbuf[3][w][l] = e3 / wave_sum(e3);
  }
  __syncthreads();

  // Phase 4: PV as tiny GEMM; thread = (wv=w, i2, c, jq)
  {
    int i2 = l >> 4, c = (l >> 1) & 7, jq = l & 1;
    const float* pr = &pbuf[w][i2][jq*32];
    const float* vr = &vv[w][c][jq*32];
    float s = 0.f;
    #pragma unroll
    for (int q = 0; q < 32; ++q) s += pr[q] * vr[q];
    s += __shfl_xor(s, 1);
    if (jq == 0){
      int ii = i0 + i2;
      int khh = ii >> 3, kww = ii & 7;
      int Y = (hw*8 + khh + SSH) % IMG;
      int X = (ww*8 + kww + SSH) % IMG;
      outa[((size_t)(w*CB + c)*HWP) + (size_t)Y*IMG + X] = s;
    }
  }
}

// ---------------- K5a: attn_l (norm factored out) ----------------
// grid 576, 256 threads (one window per wave)
__global__ __launch_bounds__(256) void k5a(
    const float* __restrict__ qw, const float* __restrict__ kw,
    const float* __restrict__ temp, float* __restrict__ attnL)
{
  __shared__ float qs[4][KK][CB], ks[4][KK][CB];
  __shared__ float invqA[4][CB], invkA[4][CB];
  int t = threadIdx.x;
  int wv = t >> 6, tl = t & 63;
  int gid = blockIdx.x*4 + wv;      // == h*NWIN + n
  int n = gid % NWIN, h = gid / NWIN;
  size_t base = widx16(h,n,tl,8);
  #pragma unroll
  for (int c = 0; c < CB; ++c){ qs[wv][tl][c] = qw[base+c]; ks[wv][tl][c] = kw[base+c]; }
  __syncthreads();
  int c8 = tl & 7, ig = tl >> 3;
  float sq = 0.f, sk2 = 0.f;
  for (int i = ig; i < KK; i += 8){
    float a = qs[wv][i][c8]; sq += a*a;
    float b = ks[wv][i][c8]; sk2 += b*b;
  }
  #pragma unroll
  for (int m = 8; m < 64; m <<= 1){ sq += __shfl_xor(sq,m); sk2 += __shfl_xor(sk2,m); }
  if (tl < 8){ invqA[wv][tl] = 1.f/fmaxf(sqrtf(sq),1e-12f); invkA[wv][tl] = 1.f/fmaxf(sqrtf(sk2),1e-12f); }
  __syncthreads();
  int c = tl >> 3, d = tl & 7;
  float a = 0.f;
  for (int i = 0; i < KK; ++i) a += qs[wv][i][c]*ks[wv][i][d];
  attnL[(size_t)gid*64 + tl] = a * invqA[wv][c] * invkA[wv][d] * temp[NH + h];
}

// ---------------- K5b: l-branch talk-conv + softmax(d) + PV ----------------
__global__ __launch_bounds__(256) void k5b(
    const float* __restrict__ attnL, const float* __restrict__ wtalk,
    const float* __restrict__ vw, float* __restrict__ outa)
{
  int n = blockIdx.x;
  int hw = n/NWS, ww = n%NWS;
  __shared__ float rows[NH][9][64];
  __shared__ float wt[NH*NH*9];
  __shared__ float P[NH][CB][CB];
  int t = threadIdx.x;
  if (t < NH*NH*9) wt[t] = wtalk[t];
  for (int l = t; l < NH*9*64; l += 256){
    int h = l/(9*64); int nb = (l/64)%9; int cd = l & 63;
    int dy = nb/3-1, dx = nb%3-1; int hw2 = hw+dy, ww2 = ww+dx;
    float v = 0.f;
    if (hw2>=0 && hw2<NWS && ww2>=0 && ww2<NWS)
      v = attnL[((size_t)h*NWIN + hw2*NWS + ww2)*64 + cd];
    rows[h][nb][cd] = v;
  }
  __syncthreads();
  int tt = t >> 6; int cd = t & 63; int c = cd >> 3, d = cd & 7;
  float a = 0.f;
  #pragma unroll
  for (int h = 0; h < NH; ++h)
    #pragma unroll
    for (int nb = 0; nb < 9; ++nb)
      a += wt[(tt*NH + h)*9 + nb] * rows[h][nb][cd];
  float m = g8_max(a);
  float e = __expf(a - m);
  P[tt][c][d] = e / g8_sum(e);
  __syncthreads();
  int i = t & 63;
  size_t vbase = widx(tt, n, i, 8);
  float vl[CB];
  #pragma unroll
  for (int d2 = 0; d2 < CB; ++d2) vl[d2] = vw[vbase + d2];
  int kh = i>>3, kwd = i&7;
  int Y = (hw*8+kh+SSH)%IMG, X = (ww*8+kwd+SSH)%IMG;
  #pragma unroll
  for (int c2 = 0; c2 < CB; ++c2){
    float o = 0.f;
    #pragma unroll
    for (int d2 = 0; d2 < CB; ++d2) o += P[tt][c2][d2]*vl[d2];
    outa[((size_t)(32 + tt*CB + c2)*IMG + Y)*IMG + X] = o;
  }
}

// ---------------- K6a: attn_g[h,i,c,d] = sum_n qg*kg (coalesced layout) ----------------
// grid NH*KK, 256 threads
__global__ __launch_bounds__(256) void k6a(
    const float* __restrict__ qg, const float* __restrict__ kg,
    const float* __restrict__ invqg, const float* __restrict__ invkg,
    const float* __restrict__ temp, float* __restrict__ attnG)
{
  int i = blockIdx.x & 63, h = blockIdx.x >> 6;
  __shared__ float sq[64*8], sk[64*8];
  __shared__ float red[4][64];
  int t = threadIdx.x;
  size_t base = ((size_t)(h*KK+i))*NWIN*CB;
  int np = t >> 6, cd = t & 63, c = cd >> 3, d = cd & 7;
  float a = 0.f;
  for (int n0 = 0; n0 < NWIN; n0 += 64){
    __syncthreads();
    for (int idx = t; idx < 512; idx += 256){
      sq[idx] = qg[base + (size_t)n0*CB + idx];
      sk[idx] = kg[base + (size_t)n0*CB + idx];
    }
    __syncthreads();
    for (int nn = np; nn < 64; nn += 4) a += sq[nn*8+c]*sk[nn*8+d];
  }
  __syncthreads();
  red[np][cd] = a;
  __syncthreads();
  if (t < 64){
    float tot = red[0][t]+red[1][t]+red[2][t]+red[3][t];
    tot *= invqg[(h*KK+i)*CB + (t>>3)] * invkg[(h*KK+i)*CB + (t&7)] * temp[2*NH + h];
    attnG[(size_t)(h*KK+i)*64 + t] = tot;
  }
}

// ---------------- K6b: g talking + softmax(d) ----------------
__global__ __launch_bounds__(64) void k6b(
    const float* __restrict__ attnG, const float* __restrict__ gtalk, float* __restrict__ attnGp)
{
  int l = blockIdx.x % KK; int t2 = blockIdx.x / KK;
  int cd = threadIdx.x;
  float a = 0.f;
  for (int h = 0; h < NH; ++h)
    for (int k = 0; k < KK; ++k)
      a += gtalk[((size_t)(h*KK + k)*KK + l)*NH + t2] * attnG[((size_t)h*KK + k)*64 + cd];
  float m = g8_max(a);
  float e = __expf(a - m);
  attnGp[((size_t)t2*KK + l)*64 + cd] = e / g8_sum(e);
}

// ---------------- K6c: out_g PV ----------------
__global__ __launch_bounds__(256) void k6c(
    const float* __restrict__ attnGp, const float* __restrict__ vw, float* __restrict__ outa)
{
  int n = blockIdx.x % NWIN; int t2 = blockIdx.x / NWIN;
  __shared__ float P[KK*64];
  int t = threadIdx.x;
  for (int l = t; l < KK*64; l += 256) P[l] = attnGp[(size_t)t2*KK*64 + l];
  __syncthreads();
  int i = t >> 2; int c0 = (t & 3)*2;
  size_t vbase = widx(t2, n, i, 16);
  float vg[8];
  #pragma unroll
  for (int d = 0; d < 8; ++d) vg[d] = vw[vbase + d];
  int hw = n/NWS, ww = n%NWS; int kh = i>>3, kwd = i&7;
  int Y = (hw*8+kh+SSH)%IMG, X = (ww*8+kwd+SSH)%IMG;
  for (int c = c0; c < c0+2; ++c){
    float o = 0.f;
    #pragma unroll
    for (int d = 0; d < 8; ++d) o += P[(i*8 + c)*8 + d]*vg[d];
    outa[((size_t)(64 + t2*CB + c)*IMG + Y)*IMG + X] = o;
  }
}

// ---------------- K7a: r-branch Gram partials over n-chunks ----------------
// grid 8 chunks x NH*CB, 256 threads
__global__ __launch_bounds__(256) void k7a(
    const float* __restrict__ qr, const float* __restrict__ kr, float* __restrict__ part)
{
  int chunk = blockIdx.x >> 5, hc = blockIdx.x & 31;
  int n0 = chunk*72;
  __shared__ float sq[72*64], sk[72*64];
  int t = threadIdx.x;
  size_t base = (size_t)hc*NWIN*KK + (size_t)n0*KK;
  for (int idx = t; idx < 72*64/4; idx += 256){
    *(float4*)&sq[idx*4] = *(const float4*)&qr[base + (size_t)idx*4];
    *(float4*)&sk[idx*4] = *(const float4*)&kr[base + (size_t)idx*4];
  }
  __syncthreads();
  int j = t & 63, ig = t >> 6;
  float acc[16];
  #pragma unroll
  for (int p = 0; p < 16; ++p) acc[p] = 0.f;
  for (int nn = 0; nn < 72; ++nn){
    float kv = sk[nn*64+j];
    #pragma unroll
    for (int p = 0; p < 16; ++p) acc[p] += sq[nn*64 + ig*16 + p]*kv;
  }
  float* ob = part + (size_t)blockIdx.x*4096;
  #pragma unroll
  for (int p = 0; p < 16; ++p) ob[(size_t)(ig*16+p)*64 + j] = acc[p];
}

// ---------------- kRed: sum partials * norms * temp -> attnR ----------------
// grid 512, 256 threads
__global__ __launch_bounds__(256) void kRed(
    const float* __restrict__ part, const float* __restrict__ invqr,
    const float* __restrict__ invkr, const float* __restrict__ temp,
    float* __restrict__ attnR)
{
  int e = blockIdx.x*256 + threadIdx.x;
  float s = 0.f;
  #pragma unroll
  for (int ch = 0; ch < 8; ++ch) s += part[(size_t)ch*NATTNR + e];
  int hc = e >> 12, ij = e & 4095, i = ij >> 6, j = ij & 63;
  attnR[e] = s * invqr[hc*64+i] * invkr[hc*64+j] * temp[3*NH + (hc>>3)];
}

// ---------------- K7b: r talking + softmax(j) ----------------
__global__ __launch_bounds__(256) void k7b(
    const float* __restrict__ attnR, const float* __restrict__ rtalk, float* __restrict__ attnRp)
{
  int d = blockIdx.x % CB; int t2 = blockIdx.x / CB;
  __shared__ float S[64][64];
  __shared__ float wr2[32];
  int t = threadIdx.x;
  if (t < 32){ int h = t >> 3, c = t & 7; wr2[t] = rtalk[((size_t)(h*CB + c)*CB + d)*NH + t2]; }
  __syncthreads();
  int j = t & 63; int ig = t >> 6;
  float acc[16];
  #pragma unroll
  for (int p = 0; p < 16; ++p) acc[p] = 0.f;
  for (int hc = 0; hc < 32; ++hc){
    float w = wr2[hc];
    const float* Ar = attnR + (size_t)hc*KK*KK;
    #pragma unroll
    for (int p = 0; p < 16; ++p) acc[p] += w * Ar[(size_t)(ig*16+p)*KK + j];
  }
  #pragma unroll
  for (int p = 0; p < 16; ++p) S[ig*16+p][j] = acc[p];
  __syncthreads();
  for (int r = ig; r < 64; r += 4){
    float a = S[r][j];
    float m = wave_max(a);
    float e = __expf(a - m);
    attnRp[(((size_t)t2*CB + d)*KK + r)*KK + j] = e / wave_sum(e);
  }
}

// ---------------- K7c: out_r PV ----------------
__global__ __launch_bounds__(256) void k7c(
    const float* __restrict__ attnRp, const float* __restrict__ vw, float* __restrict__ outa)
{
  int n = blockIdx.x % NWIN; int t2 = blockIdx.x / NWIN;
  __shared__ float vr[KK][CB];
  int t = threadIdx.x;
  for (int l = t; l < KK*CB; l += 256){
    int j = l >> 3, c = l & 7;
    vr[j][c] = vw[widx(t2, n, j, 24 + c)];
  }
  __syncthreads();
  int i = t & 63; int cg = t >> 6;
  int hw = n/NWS, ww = n%NWS; int kh = i>>3, kwd = i&7;
  int Y = (hw*8+kh+SSH)%IMG, X = (ww*8+kwd+SSH)%IMG;
  for (int c = cg*2; c < cg*2+2; ++c){
    const float* Pr = attnRp + (((size_t)t2*CB + c)*KK + i)*KK;
    float o = 0.f;
    for (int j = 0; j < KK; ++j) o += Pr[j]*vr[j][c];
    outa[((size_t)(96 + t2*CB + c)*IMG + Y)*IMG + X] = o;
  }
}

// ---------------- K_dw: depthwise 3x3 over u -> dwu ----------------
__global__ __launch_bounds__(256) void k_dw(
    const float* __restrict__ u, const float* __restrict__ dww, float* __restrict__ dwu)
{
  int ch = blockIdx.x / 48; int y0 = (blockIdx.x % 48) * 4;
  __shared__ float rows[6][192];
  int t = threadIdx.x;
  for (int idx = t; idx < 6*48; idx += 256){
    int r = idx / 48, px4 = (idx % 48)*4;
    int yy = y0 - 1 + r;
    float4 v = {0.f,0.f,0.f,0.f};
    if (yy >= 0 && yy < IMG) v = *(const float4*)&u[(size_t)ch*HWP + (size_t)yy*IMG + px4];
    rows[r][px4] = v.x; rows[r][px4+1] = v.y; rows[r][px4+2] = v.z; rows[r][px4+3] = v.w;
  }
  float kw9[9];
  #pragma unroll
  for (int q = 0; q < 9; ++q) kw9[q] = dww[ch*9 + q];
  __syncthreads();
  int r = t >> 6, lane = t & 63;
  for (int kx = 0; kx < 3; ++kx){
    int px = lane + kx*64;
    float s = 0.f;
    #pragma unroll
    for (int dy = 0; dy < 3; ++dy){
      #pragma unroll
      for (int dx = -1; dx <= 1; ++dx){
        int xx = px + dx;
        if (xx >= 0 && xx < IMG) s += kw9[dy*3 + dx + 1] * rows[r+dy][xx];
      }
    }
    dwu[(size_t)ch*HWP + (size_t)(y0+r)*IMG + px] = s;
  }
}

// ---------------- K8: channel means ----------------
__global__ __launch_bounds__(256) void k8_mean(const float* __restrict__ outa, float* __restrict__ meanb){
  int ch = blockIdx.x;
  const float4* p = (const float4*)(outa + (size_t)ch*HWP);
  float s = 0.f;
  for (int l = threadIdx.x; l < HWP/4; l += 256){
    float4 v = p[l]; s += v.x+v.y+v.z+v.w;
  }
  __shared__ float red[256];
  red[threadIdx.x] = s; __syncthreads();
  for (int k = 128; k > 0; k >>= 1){
    if (threadIdx.x < k) red[threadIdx.x] += red[threadIdx.x + k];
    __syncthreads();
  }
  if (threadIdx.x == 0) meanb[ch] = red[0] / (float)HWP;
}

// ---------------- K9a: out2z = (projw @ (outa*svec) + dwu) * zbuf (svec computed in-block) ----------------
#define PADX 68
__global__ __launch_bounds__(256) void k9a(
    const float* __restrict__ outa, const float* __restrict__ meanb,
    const float* __restrict__ scaw, const float* __restrict__ scab,
    const float* __restrict__ projw, const float* __restrict__ dwu,
    const float* __restrict__ zbuf, float* __restrict__ out2z)
{
  __shared__ float WT[128][128];
  __shared__ float xsv[128][PADX];
  __shared__ float sv[128];
  int t = threadIdx.x;
  // svec = scab + scaw @ meanb (redundant per block; 16K FMA)
  if (t < 128){
    float s = scab[t];
    const float* srow = scaw + (size_t)t*HD;
    for (int c = 0; c < HD; c += 4){
      float4 w = *(const float4*)&srow[c];
      float4 mm = *(const float4*)&meanb[c];
      s += w.x*mm.x + w.y*mm.y + w.z*mm.z + w.w*mm.w;
    }
    sv[t] = s;
  }
  for (int idx = t; idx < 4096; idx += 256){
    int o = idx & 127; int c4 = (idx >> 7) * 4;
    float4 w = *(const float4*)&projw[(size_t)o*HD + c4];
    WT[c4][o] = w.x; WT[c4+1][o] = w.y; WT[c4+2][o] = w.z; WT[c4+3][o] = w.w;
  }
  int px4 = (t & 15) * 4; int og8 = (t >> 4) * 8;
  for (int tile = 0; tile < 2; ++tile){
    int tid = blockIdx.x * 2 + tile;
    int y = tid / 3, x0 = (tid % 3) * 64;
    size_t sb = (size_t)y*IMG + x0;
    __syncthreads();
    for (int idx = t; idx < 2048; idx += 256){
      int c = idx >> 4; int p4 = (idx & 15) * 4;
      float4 v = *(const float4*)&outa[(size_t)c*HWP + sb + p4];
      float s = sv[c];
      xsv[c][p4] = v.x*s; xsv[c][p4+1] = v.y*s; xsv[c][p4+2] = v.z*s; xsv[c][p4+3] = v.w*s;
    }
    __syncthreads();
    float acc[8][4];
    #pragma unroll
    for (int a = 0; a < 8; ++a){ acc[a][0]=0.f; acc[a][1]=0.f; acc[a][2]=0.f; acc[a][3]=0.f; }
    for (int c = 0; c < 128; ++c){
      float4 xv = *(const float4*)&xsv[c][px4];
      float4 wA = *(const float4*)&WT[c][og8];
      float4 wB = *(const float4*)&WT[c][og8+4];
      float w8[8] = {wA.x,wA.y,wA.z,wA.w,wB.x,wB.y,wB.z,wB.w};
      #pragma unroll
      for (int a = 0; a < 8; ++a){
        acc[a][0] += w8[a]*xv.x; acc[a][1] += w8[a]*xv.y;
        acc[a][2] += w8[a]*xv.z; acc[a][3] += w8[a]*xv.w;
      }
    }
    #pragma unroll
    for (int oo = 0; oo < 8; ++oo){
      int o = og8 + oo;
      size_t off = (size_t)o*HWP + sb + px4;
      float4 d = *(const float4*)&dwu[off];
      float4 z = *(const float4*)&zbuf[off];
      float4 r;
      r.x = (acc[oo][0]+d.x)*z.x; r.y = (acc[oo][1]+d.y)*z.y;
      r.z = (acc[oo][2]+d.z)*z.z; r.w = (acc[oo][3]+d.w)*z.w;
      *(float4*)&out2z[off] = r;
    }
  }
}

// ---------------- K9b: dout = projow @ out2z ----------------
__global__ __launch_bounds__(256) void k9b(
    const float* __restrict__ out2z, const float* __restrict__ projow,
    float* __restrict__ dout, int bsel)
{
  __shared__ float WT2[128][64];
  __shared__ float xsv[128][PADX];
  int t = threadIdx.x;
  for (int idx = t; idx < 2048; idx += 256){
    int o = idx & 63; int c4 = (idx >> 6) * 4;
    float4 w = *(const float4*)&projow[(size_t)o*HD + c4];
    WT2[c4][o] = w.x; WT2[c4+1][o] = w.y; WT2[c4+2][o] = w.z; WT2[c4+3][o] = w.w;
  }
  int px4 = (t & 15) * 4; int og4 = (t >> 4) * 4;
  for (int tile = 0; tile < 2; ++tile){
    int tid = blockIdx.x * 2 + tile;
    int y = tid / 3, x0 = (tid % 3) * 64;
    size_t sb = (size_t)y*IMG + x0;
    __syncthreads();
    for (int idx = t; idx < 2048; idx += 256){
      int c = idx >> 4; int p4 = (idx & 15) * 4;
      float4 v = *(const float4*)&out2z[(size_t)c*HWP + sb + p4];
      xsv[c][p4] = v.x; xsv[c][p4+1] = v.y; xsv[c][p4+2] = v.z; xsv[c][p4+3] = v.w;
    }
    __syncthreads();
    float acc[4][4];
    #pragma unroll
    for (int a = 0; a < 4; ++a){ acc[a][0]=0.f; acc[a][1]=0.f; acc[a][2]=0.f; acc[a][3]=0.f; }
    for (int c = 0; c < 128; ++c){
      float4 xv = *(const float4*)&xsv[c][px4];
      float4 w4 = *(const float4*)&WT2[c][og4];
      float w4a[4] = {w4.x,w4.y,w4.z,w4.w};
      #pragma unroll
      for (int a = 0; a < 4; ++a){
        acc[a][0] += w4a[a]*xv.x; acc[a][1] += w4a[a]*xv.y;
        acc[a][2] += w4a[a]*xv.z; acc[a][3] += w4a[a]*xv.w;
      }
    }
    #pragma unroll
    for (int oo = 0; oo < 4; ++oo){
      int o = og4 + oo;
      float4 r; r.x = acc[oo][0]; r.y = acc[oo][1]; r.z = acc[oo][2]; r.w = acc[oo][3];
      *(float4*)&dout[(size_t)(bsel*CIN + o)*HWP + sb + px4] = r;
    }
  }
}

// ---------------- launch ----------------
extern "C" void kernel_launch(void* const* d_in, const int* in_sizes, int n_in,
                              void* d_out, int out_size, void* d_ws, size_t ws_size,
                              hipStream_t stream)
{
  const float* x     = (const float*)d_in[0];
  const float* wquz  = (const float*)d_in[1];
  const float* wkv   = (const float*)d_in[2];
  const float* temp  = (const float*)d_in[3];
  const float* rtalk = (const float*)d_in[4];
  const float* gtalk = (const float*)d_in[5];
  const float* btw   = (const float*)d_in[6];
  const float* ltw   = (const float*)d_in[7];
  const float* dww   = (const float*)d_in[8];
  const float* projw = (const float*)d_in[9];
  const float* projow= (const float*)d_in[10];
  const float* scaw  = (const float*)d_in[11];
  const float* scab  = (const float*)d_in[12];
  float* dout = (float*)d_out;

  float* ws = (float*)d_ws;
  float* qw    = ws;                  // NQK16
  float* kw    = qw + NQK16;          // NQK16
  float* vw    = kw + NQK16;          // NV32
  float* qg    = vw + NV32;           // NGR
  float* kg    = qg + NGR;            // NGR
  float* qr    = kg + NGR;            // NGR
  float* kr    = qr + NGR;            // NGR
  float* u     = kr + NGR;            // NSP
  float* zbuf  = u + NSP;             // NSP
  float* outa  = zbuf + NSP;          // NSP
  float* attnB = outa + NSP;          // NATTNB (aliased by dwu/out2z after k4)
  float* dwu   = attnB;               // NSP alias
  float* out2z = attnB + NSP;         // NSP alias
  float* attnL = attnB + NATTNB;      // NATTNL
  float* attnG = attnL + NATTNL;      // NATTNG
  float* attnGp= attnG + NATTNG;      // NATTNG
  float* part  = attnGp + NATTNG;     // NPART
  float* attnR = part + NPART;        // NATTNR
  float* attnRp= attnR + NATTNR;      // NATTNR
  float* invqg = attnRp + NATTNR;     // 2048
  float* invkg = invqg + 2048;        // 2048
  float* invqr = invkg + 2048;        // 2048
  float* invkr = invqr + 2048;        // 2048
  float* meanb = invkr + 2048;        // 128

  for (int b = 0; b < BB; ++b){
    k1_proj<<<IMG*12, 256, 0, stream>>>(x, wquz, wkv, qw, kw, vw, qg, kg, qr, kr, u, zbuf, b);

    kNg<<<NH*KK, 64, 0, stream>>>(qg, kg, invqg, invkg);
    kNr<<<NH*CB, 256, 0, stream>>>(qr, kr, invqr, invkr);

    k3_attnb<<<NH*NWIN/4, 256, 0, stream>>>(qw, kw, temp, attnB);
    k4_bconv<<<16*NWIN, 256, 0, stream>>>(attnB, btw, vw, outa);

    k5a<<<NH*NWIN/4, 256, 0, stream>>>(qw, kw, temp, attnL);
    k5b<<<NWIN, 256, 0, stream>>>(attnL, ltw, vw, outa);

    k6a<<<NH*KK, 256, 0, stream>>>(qg, kg, invqg, invkg, temp, attnG);
    k6b<<<NH*KK, 64, 0, stream>>>(attnG, gtalk, attnGp);
    k6c<<<NH*NWIN, 256, 0, stream>>>(attnGp, vw, outa);

    k7a<<<8*NH*CB, 256, 0, stream>>>(qr, kr, part);
    kRed<<<512, 256, 0, stream>>>(part, invqr, invkr, temp, attnR);
    k7b<<<NH*CB, 256, 0, stream>>>(attnR, rtalk, attnRp);
    k7c<<<NH*NWIN, 256, 0, stream>>>(attnRp, vw, outa);

    k_dw<<<HD*48, 256, 0, stream>>>(u, dww, dwu);

    k8_mean<<<HD, 256, 0, stream>>>(outa, meanb);

    k9a<<<288, 256, 0, stream>>>(outa, meanb, scaw, scab, projw, dwu, zbuf, out2z);
    k9b<<<288, 256, 0, stream>>>(out2z, projow, dout, b);
  }
}

// Round 7
// 1738.253 us; speedup vs baseline: 2.3783x; 1.1297x over previous
//
#include <hip/hip_runtime.h>
#include <cstdint>
#include <cstddef>

// ---------------- problem constants ----------------
#define BB   4      // batch
#define CIN  64     // input channels
#define HD   128    // h_dim
#define NH   4      // heads
#define CHW  32     // channels per head
#define CB   8      // channels per branch
#define IMG  192    // H = W
#define SSH  4      // shift
#define NWS  24     // windows per side
#define NWIN 576    // windows total
#define KK   64     // window elements (8x8)
#define HWP  (IMG*IMG)

// per-batch buffer sizes (floats)
static const size_t NQK16  = (size_t)NH*NWIN*KK*16;   // 2,359,296 (q/k b+l channels)
static const size_t NV32   = (size_t)NH*NWIN*KK*CHW;  // 4,718,592 (v all channels)
static const size_t NGR    = (size_t)NH*KK*NWIN*CB;   // 1,179,648 (qg/kg/qr/kr)
static const size_t NSP    = (size_t)HD*HWP;          // 4,718,592 spatial 128ch
static const size_t NATTNB = (size_t)NH*NWIN*KK*KK;   // 9,437,184
static const size_t NATTNL = (size_t)NH*NWIN*64;      // 147,456
static const size_t NATTNG = (size_t)NH*KK*64;        // 16,384
static const size_t NATTNR = (size_t)NH*CB*KK*KK;     // 131,072
static const size_t NPART  = (size_t)8*NATTNR;        // 1,048,576

// ---------------- helpers ----------------
__device__ inline float wave_max(float v){
  #pragma unroll
  for (int s=1;s<64;s<<=1) v = fmaxf(v, __shfl_xor(v, s));
  return v;
}
__device__ inline float wave_sum(float v){
  #pragma unroll
  for (int s=1;s<64;s<<=1) v += __shfl_xor(v, s);
  return v;
}
__device__ inline float g8_max(float v){
  v = fmaxf(v, __shfl_xor(v,1)); v = fmaxf(v, __shfl_xor(v,2)); v = fmaxf(v, __shfl_xor(v,4));
  return v;
}
__device__ inline float g8_sum(float v){
  v += __shfl_xor(v,1); v += __shfl_xor(v,2); v += __shfl_xor(v,4);
  return v;
}
// Swin region id for an image coordinate (0..191): [0,184)=0, [184,188)=1, [188,192)=2
__device__ inline int regionc(int y){ return (y < IMG-8) ? 0 : ((y < IMG-4) ? 1 : 2); }

// v layout [h][n][i][c32]
__device__ inline size_t widx(int h,int n,int i,int c){
  return (((size_t)h*NWIN + n)*KK + i)*CHW + c;
}
// q/k b+l layout [h][n][i][c16]
__device__ inline size_t widx16(int h,int n,int i,int c){
  return (((size_t)h*NWIN + n)*KK + i)*16 + c;
}
// g layout [h][i][n][c8]
__device__ inline size_t gidx(int h,int i,int n,int c){
  return (((size_t)(h*KK + i))*NWIN + n)*CB + c;
}
// r layout [h][c][n][i]
__device__ inline size_t ridx(int h,int c,int n,int i){
  return (((size_t)(h*CB + c))*NWIN + n)*KK + i;
}

// ---------------- K1: projections -> q/k/v (split layouts) + u,z (spatial) ----------------
// grid IMG*12 (16-px tiles), 256 threads. Stores vectorized per destination layout.
__global__ __launch_bounds__(256) void k1_proj(
    const float* __restrict__ x, const float* __restrict__ wquz, const float* __restrict__ wkv,
    float* __restrict__ qw, float* __restrict__ kw, float* __restrict__ vw,
    float* __restrict__ qg, float* __restrict__ kg,
    float* __restrict__ qr, float* __restrict__ kr,
    float* __restrict__ u, float* __restrict__ zbuf, int bsel)
{
  __shared__ float xs[64][20];   // padded
  int blk = blockIdx.x;
  int xc = blk % 12, y = blk / 12;
  int x0 = xc*16;
  int t = threadIdx.x;
  {
    int c = t >> 2, p4 = (t & 3)*4;
    float4 v = *(const float4*)&x[((size_t)(bsel*CIN+c)*IMG + y)*IMG + x0 + p4];
    *(float4*)&xs[c][p4] = v;
  }
  // uniform per-block window mapping: tile covers 3 pi-runs [0,4),[4,12),[12,16)
  int py  = (y + IMG - SSH) % IMG;
  int kh  = py & 7, hwq = py >> 3;
  int wwA = ((x0 - SSH + IMG) % IMG) >> 3;
  int wwB = x0 >> 3;
  int wwC = (x0 + 8) >> 3;
  int pnA = hwq*NWS + wwA, pnB = hwq*NWS + wwB, pnC = hwq*NWS + wwC;
  int piA = kh*8 + 4, piB = kh*8, piC = kh*8;
  #define PN_(p) ((p)<4 ? pnA : ((p)<12 ? pnB : pnC))
  #define PI_(p) ((p)<4 ? (piA+(p)) : ((p)<12 ? (piB+(p)-4) : (piC+(p)-12)))
  __syncthreads();

  for (int oi = 0; oi < 3; ++oi){
    if (oi == 2 && t >= 128) break;
    int o = (oi == 0) ? t : (oi == 1 ? t + 384 : t + 256);
    const float* wr = (o < 384) ? (wquz + (size_t)o*CIN) : (wkv + (size_t)(o-384)*CIN);
    float acc[16];
    #pragma unroll
    for (int p = 0; p < 16; ++p) acc[p] = 0.f;
    for (int cc = 0; cc < 64; cc += 4){
      float4 w4 = *(const float4*)(wr + cc);
      #pragma unroll
      for (int p = 0; p < 16; ++p){
        acc[p] += w4.x * xs[cc  ][p];
        acc[p] += w4.y * xs[cc+1][p];
        acc[p] += w4.z * xs[cc+2][p];
        acc[p] += w4.w * xs[cc+3][p];
      }
    }
    if (o < 128){                       // q
      int h = o >> 5, c = o & 31;
      if (c < 16){
        #pragma unroll
        for (int p = 0; p < 16; ++p) qw[widx16(h,PN_(p),PI_(p),c)] = acc[p];
      } else if (c < 24){
        int cg = c - 16;
        #pragma unroll
        for (int p = 0; p < 16; ++p) qg[gidx(h,PI_(p),PN_(p),cg)] = acc[p];
      } else {
        int cr = c - 24;
        *(float4*)&qr[ridx(h,cr,pnA,piA)]   = make_float4(acc[0],acc[1],acc[2],acc[3]);
        *(float4*)&qr[ridx(h,cr,pnB,piB)]   = make_float4(acc[4],acc[5],acc[6],acc[7]);
        *(float4*)&qr[ridx(h,cr,pnB,piB+4)] = make_float4(acc[8],acc[9],acc[10],acc[11]);
        *(float4*)&qr[ridx(h,cr,pnC,piC)]   = make_float4(acc[12],acc[13],acc[14],acc[15]);
      }
    } else if (o < 256){                // u: per-lane contiguous x -> float4 x4
      size_t ub = ((size_t)(o-128)*IMG + y)*IMG + x0;
      *(float4*)&u[ub+ 0] = make_float4(acc[0],acc[1],acc[2],acc[3]);
      *(float4*)&u[ub+ 4] = make_float4(acc[4],acc[5],acc[6],acc[7]);
      *(float4*)&u[ub+ 8] = make_float4(acc[8],acc[9],acc[10],acc[11]);
      *(float4*)&u[ub+12] = make_float4(acc[12],acc[13],acc[14],acc[15]);
    } else if (o < 384){                // z
      size_t zb = ((size_t)(o-256)*IMG + y)*IMG + x0;
      *(float4*)&zbuf[zb+ 0] = make_float4(acc[0],acc[1],acc[2],acc[3]);
      *(float4*)&zbuf[zb+ 4] = make_float4(acc[4],acc[5],acc[6],acc[7]);
      *(float4*)&zbuf[zb+ 8] = make_float4(acc[8],acc[9],acc[10],acc[11]);
      *(float4*)&zbuf[zb+12] = make_float4(acc[12],acc[13],acc[14],acc[15]);
    } else if (o < 512){                // k
      int oc = o - 384; int h = oc >> 5, c = oc & 31;
      if (c < 16){
        #pragma unroll
        for (int p = 0; p < 16; ++p) kw[widx16(h,PN_(p),PI_(p),c)] = acc[p];
      } else if (c < 24){
        int cg = c - 16;
        #pragma unroll
        for (int p = 0; p < 16; ++p) kg[gidx(h,PI_(p),PN_(p),cg)] = acc[p];
      } else {
        int cr = c - 24;
        *(float4*)&kr[ridx(h,cr,pnA,piA)]   = make_float4(acc[0],acc[1],acc[2],acc[3]);
        *(float4*)&kr[ridx(h,cr,pnB,piB)]   = make_float4(acc[4],acc[5],acc[6],acc[7]);
        *(float4*)&kr[ridx(h,cr,pnB,piB+4)] = make_float4(acc[8],acc[9],acc[10],acc[11]);
        *(float4*)&kr[ridx(h,cr,pnC,piC)]   = make_float4(acc[12],acc[13],acc[14],acc[15]);
      }
    } else {                            // v
      int oc = o - 512; int h = oc >> 5, c = oc & 31;
      #pragma unroll
      for (int p = 0; p < 16; ++p) vw[widx(h,PN_(p),PI_(p),c)] = acc[p];
    }
  }
  #undef PN_
  #undef PI_
}

// ---------------- kNg: inverse L2 norms over n for g-branch ----------------
// grid NH*KK (h,i), 64 threads
__global__ __launch_bounds__(64) void kNg(
    const float* __restrict__ qg, const float* __restrict__ kg,
    float* __restrict__ invqg, float* __restrict__ invkg)
{
  int i = blockIdx.x & 63, h = blockIdx.x >> 6;
  size_t base = ((size_t)(h*KK+i))*NWIN*CB;
  int t = threadIdx.x, c = t & 7, ng = t >> 3;
  float sq = 0.f, sk2 = 0.f;
  for (int n = ng; n < NWIN; n += 8){
    float a = qg[base + (size_t)n*CB + c]; sq  += a*a;
    float b = kg[base + (size_t)n*CB + c]; sk2 += b*b;
  }
  #pragma unroll
  for (int m = 8; m < 64; m <<= 1){ sq += __shfl_xor(sq,m); sk2 += __shfl_xor(sk2,m); }
  if (t < 8){
    invqg[(h*KK+i)*CB + c] = 1.f/fmaxf(sqrtf(sq), 1e-12f);
    invkg[(h*KK+i)*CB + c] = 1.f/fmaxf(sqrtf(sk2),1e-12f);
  }
}

// ---------------- kNr: inverse L2 norms over n for r-branch ----------------
// grid NH*CB (h,c), 256 threads
__global__ __launch_bounds__(256) void kNr(
    const float* __restrict__ qr, const float* __restrict__ kr,
    float* __restrict__ invqr, float* __restrict__ invkr)
{
  int hc = blockIdx.x;
  size_t base = (size_t)hc*NWIN*KK;
  int t = threadIdx.x, i = t & 63, ng = t >> 6;
  float sq = 0.f, sk2 = 0.f;
  for (int n = ng; n < NWIN; n += 4){
    float a = qr[base + (size_t)n*KK + i]; sq  += a*a;
    float b = kr[base + (size_t)n*KK + i]; sk2 += b*b;
  }
  __shared__ float rq[4][64], rk[4][64];
  rq[ng][i] = sq; rk[ng][i] = sk2;
  __syncthreads();
  if (t < 64){
    float s = rq[0][t]+rq[1][t]+rq[2][t]+rq[3][t];
    invqr[hc*KK + t] = 1.f/fmaxf(sqrtf(s),1e-12f);
  } else if (t < 128){
    int i2 = t - 64;
    float s = rk[0][i2]+rk[1][i2]+rk[2][i2]+rk[3][i2];
    invkr[hc*KK + i2] = 1.f/fmaxf(sqrtf(s),1e-12f);
  }
}

// ---------------- K3: attn_b = norm(qb)@norm(kb)^T * temp (norm fused) ----------------
// grid NH*NWIN/4 = 576, 256 threads (one window per wave)
__global__ __launch_bounds__(256) void k3_attnb(
    const float* __restrict__ qw, const float* __restrict__ kw,
    const float* __restrict__ temp, float* __restrict__ attnB)
{
  __shared__ float qs[4][KK][CB];
  int t = threadIdx.x;
  int wv = t >> 6, j = t & 63;
  int gid = blockIdx.x*4 + wv;      // == h*NWIN + n
  int n = gid % NWIN, h = gid / NWIN;
  size_t base = widx16(h,n,j,0);
  float q8[CB], k8[CB];
  float sq = 0.f, sk2 = 0.f;
  #pragma unroll
  for (int c = 0; c < CB; ++c){
    q8[c] = qw[base+c]; sq += q8[c]*q8[c];
    k8[c] = kw[base+c]; sk2 += k8[c]*k8[c];
  }
  float invq = 1.f/fmaxf(sqrtf(sq),1e-12f), invk = 1.f/fmaxf(sqrtf(sk2),1e-12f);
  #pragma unroll
  for (int c = 0; c < CB; ++c){ qs[wv][j][c] = q8[c]*invq; k8[c] *= invk; }
  __syncthreads();
  float tmp = temp[h];
  float* orow = attnB + (size_t)gid*KK*KK;
  for (int i = 0; i < KK; ++i){
    float a = 0.f;
    #pragma unroll
    for (int c = 0; c < CB; ++c) a += qs[wv][i][c]*k8[c];
    orow[(size_t)i*KK + j] = a * tmp;
  }
}

// ---------------- K4: b-branch talk-conv + mask + softmax + PV, fused ----------------
// grid 16*NWIN (i-group SLOW, n fast for L2 locality), 256 threads
__global__ __launch_bounds__(256) void k4_bconv(
    const float* __restrict__ attnB, const float* __restrict__ wtalk,
    const float* __restrict__ vw, float* __restrict__ outa)
{
  int ig = blockIdx.x / NWIN, n = blockIdx.x % NWIN;
  int i0 = ig*4;
  int hw = n / NWS, ww = n % NWS;
  __shared__ float rows[4][9][4][64];   // [h][nb][i_local][j]
  __shared__ float pbuf[4][4][66];      // [wv][i_local][j] padded
  __shared__ float vv[4][8][66];        // [wv][c][j] padded
  int t = threadIdx.x;
  int w = t >> 6, l = t & 63;

  // Phase 1a: load 9-neighbor rows (wave = input head h = w)
  {
    int li = l >> 4, j4 = (l & 15)*4;
    #pragma unroll
    for (int nb = 0; nb < 9; ++nb){
      const int dy = nb/3 - 1, dx = nb%3 - 1;
      int hw2 = hw + dy, ww2 = ww + dx;
      float4 v = {0.f,0.f,0.f,0.f};
      if (hw2 >= 0 && hw2 < NWS && ww2 >= 0 && ww2 < NWS){
        int n2 = hw2*NWS + ww2;
        v = *(const float4*)&attnB[((size_t)(w*NWIN + n2)*KK + i0 + li)*KK + j4];
      }
      *(float4*)&rows[w][nb][li][j4] = v;
    }
  }
  // Phase 1b: stage V (wave = head)
  {
    size_t vb = widx(w, n, l, 0);
    float4 va = *(const float4*)&vw[vb];
    float4 vb4 = *(const float4*)&vw[vb + 4];
    vv[w][0][l] = va.x;  vv[w][1][l] = va.y;  vv[w][2][l] = va.z;  vv[w][3][l] = va.w;
    vv[w][4][l] = vb4.x; vv[w][5][l] = vb4.y; vv[w][6][l] = vb4.z; vv[w][7][l] = vb4.w;
  }
  __syncthreads();

  // Phase 2: conv (wave = local i); thread computes all 4 output heads
  int i = i0 + w;
  float a0 = 0.f, a1 = 0.f, a2 = 0.f, a3 = 0.f;
  #pragma unroll
  for (int h = 0; h < 4; ++h){
    #pragma unroll
    for (int nb = 0; nb < 9; ++nb){
      float r = rows[h][nb][w][l];
      a0 += wtalk[(0*4 + h)*9 + nb] * r;   // uniform -> scalar loads
      a1 += wtalk[(1*4 + h)*9 + nb] * r;
      a2 += wtalk[(2*4 + h)*9 + nb] * r;
      a3 += wtalk[(3*4 + h)*9 + nb] * r;
    }
  }
  // Phase 3: analytic shifted-window mask + per-head wave softmax
  int kh = i >> 3, kwd = i & 7;
  int cntI = regionc(hw*8 + kh)*3 + regionc(ww*8 + kwd);
  int cntJ = regionc(hw*8 + (l>>3))*3 + regionc(ww*8 + (l&7));
  float mval = (cntI != cntJ) ? -100.f : 0.f;
  a0 += mval; a1 += mval; a2 += mval; a3 += mval;
  {
    float m0 = wave_max(a0); float e0 = __expf(a0 - m0); pbuf[0][w][l] = e0 / wave_sum(e0);
    float m1 = wave_max(a1); float e1 = __expf(a1 - m1); pbuf[1][w][l] = e1 / wave_sum(e1);
    float m2 = wave_max(a2); float e2 = __expf(a2 - m2); pbuf[2][w][l] = e2 / wave_sum(e2);
    float m3 = wave_max(a3); float e3 = __expf(a3 - m3); pbuf[3][w][l] = e3 / wave_sum(e3);
  }
  __syncthreads();

  // Phase 4: PV as tiny GEMM; thread = (wv=w, i2, c, jq)
  {
    int i2 = l >> 4, c = (l >> 1) & 7, jq = l & 1;
    const float* pr = &pbuf[w][i2][jq*32];
    const float* vr = &vv[w][c][jq*32];
    float s = 0.f;
    #pragma unroll
    for (int q = 0; q < 32; ++q) s += pr[q] * vr[q];
    s += __shfl_xor(s, 1);
    if (jq == 0){
      int ii = i0 + i2;
      int khh = ii >> 3, kww = ii & 7;
      int Y = (hw*8 + khh + SSH) % IMG;
      int X = (ww*8 + kww + SSH) % IMG;
      outa[((size_t)(w*CB + c)*HWP) + (size_t)Y*IMG + X] = s;
    }
  }
}

// ---------------- K5a: attn_l (norm factored out) ----------------
// grid 576, 256 threads (one window per wave)
__global__ __launch_bounds__(256) void k5a(
    const float* __restrict__ qw, const float* __restrict__ kw,
    const float* __restrict__ temp, float* __restrict__ attnL)
{
  __shared__ float qs[4][KK][CB], ks[4][KK][CB];
  __shared__ float invqA[4][CB], invkA[4][CB];
  int t = threadIdx.x;
  int wv = t >> 6, tl = t & 63;
  int gid = blockIdx.x*4 + wv;      // == h*NWIN + n
  int n = gid % NWIN, h = gid / NWIN;
  size_t base = widx16(h,n,tl,8);
  #pragma unroll
  for (int c = 0; c < CB; ++c){ qs[wv][tl][c] = qw[base+c]; ks[wv][tl][c] = kw[base+c]; }
  __syncthreads();
  int c8 = tl & 7, ig = tl >> 3;
  float sq = 0.f, sk2 = 0.f;
  for (int i = ig; i < KK; i += 8){
    float a = qs[wv][i][c8]; sq += a*a;
    float b = ks[wv][i][c8]; sk2 += b*b;
  }
  #pragma unroll
  for (int m = 8; m < 64; m <<= 1){ sq += __shfl_xor(sq,m); sk2 += __shfl_xor(sk2,m); }
  if (tl < 8){ invqA[wv][tl] = 1.f/fmaxf(sqrtf(sq),1e-12f); invkA[wv][tl] = 1.f/fmaxf(sqrtf(sk2),1e-12f); }
  __syncthreads();
  int c = tl >> 3, d = tl & 7;
  float a = 0.f;
  for (int i = 0; i < KK; ++i) a += qs[wv][i][c]*ks[wv][i][d];
  attnL[(size_t)gid*64 + tl] = a * invqA[wv][c] * invkA[wv][d] * temp[NH + h];
}

// ---------------- K5b: l-branch talk-conv + softmax(d) + PV ----------------
__global__ __launch_bounds__(256) void k5b(
    const float* __restrict__ attnL, const float* __restrict__ wtalk,
    const float* __restrict__ vw, float* __restrict__ outa)
{
  int n = blockIdx.x;
  int hw = n/NWS, ww = n%NWS;
  __shared__ float rows[NH][9][64];
  __shared__ float wt[NH*NH*9];
  __shared__ float P[NH][CB][CB];
  int t = threadIdx.x;
  if (t < NH*NH*9) wt[t] = wtalk[t];
  for (int l = t; l < NH*9*64; l += 256){
    int h = l/(9*64); int nb = (l/64)%9; int cd = l & 63;
    int dy = nb/3-1, dx = nb%3-1; int hw2 = hw+dy, ww2 = ww+dx;
    float v = 0.f;
    if (hw2>=0 && hw2<NWS && ww2>=0 && ww2<NWS)
      v = attnL[((size_t)h*NWIN + hw2*NWS + ww2)*64 + cd];
    rows[h][nb][cd] = v;
  }
  __syncthreads();
  int tt = t >> 6; int cd = t & 63; int c = cd >> 3, d = cd & 7;
  float a = 0.f;
  #pragma unroll
  for (int h = 0; h < NH; ++h)
    #pragma unroll
    for (int nb = 0; nb < 9; ++nb)
      a += wt[(tt*NH + h)*9 + nb] * rows[h][nb][cd];
  float m = g8_max(a);
  float e = __expf(a - m);
  P[tt][c][d] = e / g8_sum(e);
  __syncthreads();
  int i = t & 63;
  size_t vbase = widx(tt, n, i, 8);
  float vl[CB];
  #pragma unroll
  for (int d2 = 0; d2 < CB; ++d2) vl[d2] = vw[vbase + d2];
  int kh = i>>3, kwd = i&7;
  int Y = (hw*8+kh+SSH)%IMG, X = (ww*8+kwd+SSH)%IMG;
  #pragma unroll
  for (int c2 = 0; c2 < CB; ++c2){
    float o = 0.f;
    #pragma unroll
    for (int d2 = 0; d2 < CB; ++d2) o += P[tt][c2][d2]*vl[d2];
    outa[((size_t)(32 + tt*CB + c2)*IMG + Y)*IMG + X] = o;
  }
}

// ---------------- K6a: attn_g[h,i,c,d] = sum_n qg*kg (coalesced layout) ----------------
// grid NH*KK, 256 threads
__global__ __launch_bounds__(256) void k6a(
    const float* __restrict__ qg, const float* __restrict__ kg,
    const float* __restrict__ invqg, const float* __restrict__ invkg,
    const float* __restrict__ temp, float* __restrict__ attnG)
{
  int i = blockIdx.x & 63, h = blockIdx.x >> 6;
  __shared__ float sq[64*8], sk[64*8];
  __shared__ float red[4][64];
  int t = threadIdx.x;
  size_t base = ((size_t)(h*KK+i))*NWIN*CB;
  int np = t >> 6, cd = t & 63, c = cd >> 3, d = cd & 7;
  float a = 0.f;
  for (int n0 = 0; n0 < NWIN; n0 += 64){
    __syncthreads();
    for (int idx = t; idx < 512; idx += 256){
      sq[idx] = qg[base + (size_t)n0*CB + idx];
      sk[idx] = kg[base + (size_t)n0*CB + idx];
    }
    __syncthreads();
    for (int nn = np; nn < 64; nn += 4) a += sq[nn*8+c]*sk[nn*8+d];
  }
  __syncthreads();
  red[np][cd] = a;
  __syncthreads();
  if (t < 64){
    float tot = red[0][t]+red[1][t]+red[2][t]+red[3][t];
    tot *= invqg[(h*KK+i)*CB + (t>>3)] * invkg[(h*KK+i)*CB + (t&7)] * temp[2*NH + h];
    attnG[(size_t)(h*KK+i)*64 + t] = tot;
  }
}

// ---------------- K6b: g talking + softmax(d) ----------------
__global__ __launch_bounds__(64) void k6b(
    const float* __restrict__ attnG, const float* __restrict__ gtalk, float* __restrict__ attnGp)
{
  int l = blockIdx.x % KK; int t2 = blockIdx.x / KK;
  int cd = threadIdx.x;
  float a = 0.f;
  for (int h = 0; h < NH; ++h)
    for (int k = 0; k < KK; ++k)
      a += gtalk[((size_t)(h*KK + k)*KK + l)*NH + t2] * attnG[((size_t)h*KK + k)*64 + cd];
  float m = g8_max(a);
  float e = __expf(a - m);
  attnGp[((size_t)t2*KK + l)*64 + cd] = e / g8_sum(e);
}

// ---------------- K6c: out_g PV ----------------
__global__ __launch_bounds__(256) void k6c(
    const float* __restrict__ attnGp, const float* __restrict__ vw, float* __restrict__ outa)
{
  int n = blockIdx.x % NWIN; int t2 = blockIdx.x / NWIN;
  __shared__ float P[KK*64];
  int t = threadIdx.x;
  for (int l = t; l < KK*64; l += 256) P[l] = attnGp[(size_t)t2*KK*64 + l];
  __syncthreads();
  int i = t >> 2; int c0 = (t & 3)*2;
  size_t vbase = widx(t2, n, i, 16);
  float vg[8];
  #pragma unroll
  for (int d = 0; d < 8; ++d) vg[d] = vw[vbase + d];
  int hw = n/NWS, ww = n%NWS; int kh = i>>3, kwd = i&7;
  int Y = (hw*8+kh+SSH)%IMG, X = (ww*8+kwd+SSH)%IMG;
  for (int c = c0; c < c0+2; ++c){
    float o = 0.f;
    #pragma unroll
    for (int d = 0; d < 8; ++d) o += P[(i*8 + c)*8 + d]*vg[d];
    outa[((size_t)(64 + t2*CB + c)*IMG + Y)*IMG + X] = o;
  }
}

// ---------------- K7a: r-branch Gram partials over n-chunks ----------------
// grid 8 chunks x NH*CB, 256 threads
__global__ __launch_bounds__(256) void k7a(
    const float* __restrict__ qr, const float* __restrict__ kr, float* __restrict__ part)
{
  int chunk = blockIdx.x >> 5, hc = blockIdx.x & 31;
  int n0 = chunk*72;
  __shared__ float sq[72*64], sk[72*64];
  int t = threadIdx.x;
  size_t base = (size_t)hc*NWIN*KK + (size_t)n0*KK;
  for (int idx = t; idx < 72*64/4; idx += 256){
    *(float4*)&sq[idx*4] = *(const float4*)&qr[base + (size_t)idx*4];
    *(float4*)&sk[idx*4] = *(const float4*)&kr[base + (size_t)idx*4];
  }
  __syncthreads();
  int j = t & 63, ig = t >> 6;
  float acc[16];
  #pragma unroll
  for (int p = 0; p < 16; ++p) acc[p] = 0.f;
  for (int nn = 0; nn < 72; ++nn){
    float kv = sk[nn*64+j];
    #pragma unroll
    for (int p = 0; p < 16; ++p) acc[p] += sq[nn*64 + ig*16 + p]*kv;
  }
  float* ob = part + (size_t)blockIdx.x*4096;
  #pragma unroll
  for (int p = 0; p < 16; ++p) ob[(size_t)(ig*16+p)*64 + j] = acc[p];
}

// ---------------- kRed: sum partials * norms * temp -> attnR ----------------
// grid 512, 256 threads
__global__ __launch_bounds__(256) void kRed(
    const float* __restrict__ part, const float* __restrict__ invqr,
    const float* __restrict__ invkr, const float* __restrict__ temp,
    float* __restrict__ attnR)
{
  int e = blockIdx.x*256 + threadIdx.x;
  float s = 0.f;
  #pragma unroll
  for (int ch = 0; ch < 8; ++ch) s += part[(size_t)ch*NATTNR + e];
  int hc = e >> 12, ij = e & 4095, i = ij >> 6, j = ij & 63;
  attnR[e] = s * invqr[hc*64+i] * invkr[hc*64+j] * temp[3*NH + (hc>>3)];
}

// ---------------- K7b: r talking + softmax(j) ----------------
__global__ __launch_bounds__(256) void k7b(
    const float* __restrict__ attnR, const float* __restrict__ rtalk, float* __restrict__ attnRp)
{
  int d = blockIdx.x % CB; int t2 = blockIdx.x / CB;
  __shared__ float S[64][64];
  __shared__ float wr2[32];
  int t = threadIdx.x;
  if (t < 32){ int h = t >> 3, c = t & 7; wr2[t] = rtalk[((size_t)(h*CB + c)*CB + d)*NH + t2]; }
  __syncthreads();
  int j = t & 63; int ig = t >> 6;
  float acc[16];
  #pragma unroll
  for (int p = 0; p < 16; ++p) acc[p] = 0.f;
  for (int hc = 0; hc < 32; ++hc){
    float w = wr2[hc];
    const float* Ar = attnR + (size_t)hc*KK*KK;
    #pragma unroll
    for (int p = 0; p < 16; ++p) acc[p] += w * Ar[(size_t)(ig*16+p)*KK + j];
  }
  #pragma unroll
  for (int p = 0; p < 16; ++p) S[ig*16+p][j] = acc[p];
  __syncthreads();
  for (int r = ig; r < 64; r += 4){
    float a = S[r][j];
    float m = wave_max(a);
    float e = __expf(a - m);
    attnRp[(((size_t)t2*CB + d)*KK + r)*KK + j] = e / wave_sum(e);
  }
}

// ---------------- K7c: out_r PV ----------------
__global__ __launch_bounds__(256) void k7c(
    const float* __restrict__ attnRp, const float* __restrict__ vw, float* __restrict__ outa)
{
  int n = blockIdx.x % NWIN; int t2 = blockIdx.x / NWIN;
  __shared__ float vr[KK][CB];
  int t = threadIdx.x;
  for (int l = t; l < KK*CB; l += 256){
    int j = l >> 3, c = l & 7;
    vr[j][c] = vw[widx(t2, n, j, 24 + c)];
  }
  __syncthreads();
  int i = t & 63; int cg = t >> 6;
  int hw = n/NWS, ww = n%NWS; int kh = i>>3, kwd = i&7;
  int Y = (hw*8+kh+SSH)%IMG, X = (ww*8+kwd+SSH)%IMG;
  for (int c = cg*2; c < cg*2+2; ++c){
    const float* Pr = attnRp + (((size_t)t2*CB + c)*KK + i)*KK;
    float o = 0.f;
    for (int j = 0; j < KK; ++j) o += Pr[j]*vr[j][c];
    outa[((size_t)(96 + t2*CB + c)*IMG + Y)*IMG + X] = o;
  }
}

// ---------------- K_dw: depthwise 3x3 over u -> dwu ----------------
__global__ __launch_bounds__(256) void k_dw(
    const float* __restrict__ u, const float* __restrict__ dww, float* __restrict__ dwu)
{
  int ch = blockIdx.x / 48; int y0 = (blockIdx.x % 48) * 4;
  __shared__ float rows[6][192];
  int t = threadIdx.x;
  for (int idx = t; idx < 6*48; idx += 256){
    int r = idx / 48, px4 = (idx % 48)*4;
    int yy = y0 - 1 + r;
    float4 v = {0.f,0.f,0.f,0.f};
    if (yy >= 0 && yy < IMG) v = *(const float4*)&u[(size_t)ch*HWP + (size_t)yy*IMG + px4];
    rows[r][px4] = v.x; rows[r][px4+1] = v.y; rows[r][px4+2] = v.z; rows[r][px4+3] = v.w;
  }
  float kw9[9];
  #pragma unroll
  for (int q = 0; q < 9; ++q) kw9[q] = dww[ch*9 + q];
  __syncthreads();
  int r = t >> 6, lane = t & 63;
  for (int kx = 0; kx < 3; ++kx){
    int px = lane + kx*64;
    float s = 0.f;
    #pragma unroll
    for (int dy = 0; dy < 3; ++dy){
      #pragma unroll
      for (int dx = -1; dx <= 1; ++dx){
        int xx = px + dx;
        if (xx >= 0 && xx < IMG) s += kw9[dy*3 + dx + 1] * rows[r+dy][xx];
      }
    }
    dwu[(size_t)ch*HWP + (size_t)(y0+r)*IMG + px] = s;
  }
}

// ---------------- K8: channel means ----------------
__global__ __launch_bounds__(256) void k8_mean(const float* __restrict__ outa, float* __restrict__ meanb){
  int ch = blockIdx.x;
  const float4* p = (const float4*)(outa + (size_t)ch*HWP);
  float s = 0.f;
  for (int l = threadIdx.x; l < HWP/4; l += 256){
    float4 v = p[l]; s += v.x+v.y+v.z+v.w;
  }
  __shared__ float red[256];
  red[threadIdx.x] = s; __syncthreads();
  for (int k = 128; k > 0; k >>= 1){
    if (threadIdx.x < k) red[threadIdx.x] += red[threadIdx.x + k];
    __syncthreads();
  }
  if (threadIdx.x == 0) meanb[ch] = red[0] / (float)HWP;
}

// ---------------- K9a: out2z = (projw @ (outa*svec) + dwu) * zbuf (svec computed in-block) ----------------
#define PADX 68
__global__ __launch_bounds__(256) void k9a(
    const float* __restrict__ outa, const float* __restrict__ meanb,
    const float* __restrict__ scaw, const float* __restrict__ scab,
    const float* __restrict__ projw, const float* __restrict__ dwu,
    const float* __restrict__ zbuf, float* __restrict__ out2z)
{
  __shared__ float WT[128][128];
  __shared__ float xsv[128][PADX];
  __shared__ float sv[128];
  int t = threadIdx.x;
  // svec = scab + scaw @ meanb (redundant per block; 16K FMA)
  if (t < 128){
    float s = scab[t];
    const float* srow = scaw + (size_t)t*HD;
    for (int c = 0; c < HD; c += 4){
      float4 w = *(const float4*)&srow[c];
      float4 mm = *(const float4*)&meanb[c];
      s += w.x*mm.x + w.y*mm.y + w.z*mm.z + w.w*mm.w;
    }
    sv[t] = s;
  }
  for (int idx = t; idx < 4096; idx += 256){
    int o = idx & 127; int c4 = (idx >> 7) * 4;
    float4 w = *(const float4*)&projw[(size_t)o*HD + c4];
    WT[c4][o] = w.x; WT[c4+1][o] = w.y; WT[c4+2][o] = w.z; WT[c4+3][o] = w.w;
  }
  int px4 = (t & 15) * 4; int og8 = (t >> 4) * 8;
  for (int tile = 0; tile < 2; ++tile){
    int tid = blockIdx.x * 2 + tile;
    int y = tid / 3, x0 = (tid % 3) * 64;
    size_t sb = (size_t)y*IMG + x0;
    __syncthreads();
    for (int idx = t; idx < 2048; idx += 256){
      int c = idx >> 4; int p4 = (idx & 15) * 4;
      float4 v = *(const float4*)&outa[(size_t)c*HWP + sb + p4];
      float s = sv[c];
      xsv[c][p4] = v.x*s; xsv[c][p4+1] = v.y*s; xsv[c][p4+2] = v.z*s; xsv[c][p4+3] = v.w*s;
    }
    __syncthreads();
    float acc[8][4];
    #pragma unroll
    for (int a = 0; a < 8; ++a){ acc[a][0]=0.f; acc[a][1]=0.f; acc[a][2]=0.f; acc[a][3]=0.f; }
    for (int c = 0; c < 128; ++c){
      float4 xv = *(const float4*)&xsv[c][px4];
      float4 wA = *(const float4*)&WT[c][og8];
      float4 wB = *(const float4*)&WT[c][og8+4];
      float w8[8] = {wA.x,wA.y,wA.z,wA.w,wB.x,wB.y,wB.z,wB.w};
      #pragma unroll
      for (int a = 0; a < 8; ++a){
        acc[a][0] += w8[a]*xv.x; acc[a][1] += w8[a]*xv.y;
        acc[a][2] += w8[a]*xv.z; acc[a][3] += w8[a]*xv.w;
      }
    }
    #pragma unroll
    for (int oo = 0; oo < 8; ++oo){
      int o = og8 + oo;
      size_t off = (size_t)o*HWP + sb + px4;
      float4 d = *(const float4*)&dwu[off];
      float4 z = *(const float4*)&zbuf[off];
      float4 r;
      r.x = (acc[oo][0]+d.x)*z.x; r.y = (acc[oo][1]+d.y)*z.y;
      r.z = (acc[oo][2]+d.z)*z.z; r.w = (acc[oo][3]+d.w)*z.w;
      *(float4*)&out2z[off] = r;
    }
  }
}

// ---------------- K9b: dout = projow @ out2z ----------------
__global__ __launch_bounds__(256) void k9b(
    const float* __restrict__ out2z, const float* __restrict__ projow,
    float* __restrict__ dout, int bsel)
{
  __shared__ float WT2[128][64];
  __shared__ float xsv[128][PADX];
  int t = threadIdx.x;
  for (int idx = t; idx < 2048; idx += 256){
    int o = idx & 63; int c4 = (idx >> 6) * 4;
    float4 w = *(const float4*)&projow[(size_t)o*HD + c4];
    WT2[c4][o] = w.x; WT2[c4+1][o] = w.y; WT2[c4+2][o] = w.z; WT2[c4+3][o] = w.w;
  }
  int px4 = (t & 15) * 4; int og4 = (t >> 4) * 4;
  for (int tile = 0; tile < 2; ++tile){
    int tid = blockIdx.x * 2 + tile;
    int y = tid / 3, x0 = (tid % 3) * 64;
    size_t sb = (size_t)y*IMG + x0;
    __syncthreads();
    for (int idx = t; idx < 2048; idx += 256){
      int c = idx >> 4; int p4 = (idx & 15) * 4;
      float4 v = *(const float4*)&out2z[(size_t)c*HWP + sb + p4];
      xsv[c][p4] = v.x; xsv[c][p4+1] = v.y; xsv[c][p4+2] = v.z; xsv[c][p4+3] = v.w;
    }
    __syncthreads();
    float acc[4][4];
    #pragma unroll
    for (int a = 0; a < 4; ++a){ acc[a][0]=0.f; acc[a][1]=0.f; acc[a][2]=0.f; acc[a][3]=0.f; }
    for (int c = 0; c < 128; ++c){
      float4 xv = *(const float4*)&xsv[c][px4];
      float4 w4 = *(const float4*)&WT2[c][og4];
      float w4a[4] = {w4.x,w4.y,w4.z,w4.w};
      #pragma unroll
      for (int a = 0; a < 4; ++a){
        acc[a][0] += w4a[a]*xv.x; acc[a][1] += w4a[a]*xv.y;
        acc[a][2] += w4a[a]*xv.z; acc[a][3] += w4a[a]*xv.w;
      }
    }
    #pragma unroll
    for (int oo = 0; oo < 4; ++oo){
      int o = og4 + oo;
      float4 r; r.x = acc[oo][0]; r.y = acc[oo][1]; r.z = acc[oo][2]; r.w = acc[oo][3];
      *(float4*)&dout[(size_t)(bsel*CIN + o)*HWP + sb + px4] = r;
    }
  }
}

// ---------------- launch ----------------
extern "C" void kernel_launch(void* const* d_in, const int* in_sizes, int n_in,
                              void* d_out, int out_size, void* d_ws, size_t ws_size,
                              hipStream_t stream)
{
  const float* x     = (const float*)d_in[0];
  const float* wquz  = (const float*)d_in[1];
  const float* wkv   = (const float*)d_in[2];
  const float* temp  = (const float*)d_in[3];
  const float* rtalk = (const float*)d_in[4];
  const float* gtalk = (const float*)d_in[5];
  const float* btw   = (const float*)d_in[6];
  const float* ltw   = (const float*)d_in[7];
  const float* dww   = (const float*)d_in[8];
  const float* projw = (const float*)d_in[9];
  const float* projow= (const float*)d_in[10];
  const float* scaw  = (const float*)d_in[11];
  const float* scab  = (const float*)d_in[12];
  float* dout = (float*)d_out;

  float* ws = (float*)d_ws;
  float* qw    = ws;                  // NQK16
  float* kw    = qw + NQK16;          // NQK16
  float* vw    = kw + NQK16;          // NV32
  float* qg    = vw + NV32;           // NGR
  float* kg    = qg + NGR;            // NGR
  float* qr    = kg + NGR;            // NGR
  float* kr    = qr + NGR;            // NGR
  float* u     = kr + NGR;            // NSP
  float* zbuf  = u + NSP;             // NSP
  float* outa  = zbuf + NSP;          // NSP
  float* attnB = outa + NSP;          // NATTNB (aliased by dwu/out2z after k4)
  float* dwu   = attnB;               // NSP alias
  float* out2z = attnB + NSP;         // NSP alias
  float* attnL = attnB + NATTNB;      // NATTNL
  float* attnG = attnL + NATTNL;      // NATTNG
  float* attnGp= attnG + NATTNG;      // NATTNG
  float* part  = attnGp + NATTNG;     // NPART
  float* attnR = part + NPART;        // NATTNR
  float* attnRp= attnR + NATTNR;      // NATTNR
  float* invqg = attnRp + NATTNR;     // 2048
  float* invkg = invqg + 2048;        // 2048
  float* invqr = invkg + 2048;        // 2048
  float* invkr = invqr + 2048;        // 2048
  float* meanb = invkr + 2048;        // 128

  for (int b = 0; b < BB; ++b){
    k1_proj<<<IMG*12, 256, 0, stream>>>(x, wquz, wkv, qw, kw, vw, qg, kg, qr, kr, u, zbuf, b);

    kNg<<<NH*KK, 64, 0, stream>>>(qg, kg, invqg, invkg);
    kNr<<<NH*CB, 256, 0, stream>>>(qr, kr, invqr, invkr);

    k3_attnb<<<NH*NWIN/4, 256, 0, stream>>>(qw, kw, temp, attnB);
    k4_bconv<<<16*NWIN, 256, 0, stream>>>(attnB, btw, vw, outa);

    k5a<<<NH*NWIN/4, 256, 0, stream>>>(qw, kw, temp, attnL);
    k5b<<<NWIN, 256, 0, stream>>>(attnL, ltw, vw, outa);

    k6a<<<NH*KK, 256, 0, stream>>>(qg, kg, invqg, invkg, temp, attnG);
    k6b<<<NH*KK, 64, 0, stream>>>(attnG, gtalk, attnGp);
    k6c<<<NH*NWIN, 256, 0, stream>>>(attnGp, vw, outa);

    k7a<<<8*NH*CB, 256, 0, stream>>>(qr, kr, part);
    kRed<<<512, 256, 0, stream>>>(part, invqr, invkr, temp, attnR);
    k7b<<<NH*CB, 256, 0, stream>>>(attnR, rtalk, attnRp);
    k7c<<<NH*NWIN, 256, 0, stream>>>(attnRp, vw, outa);

    k_dw<<<HD*48, 256, 0, stream>>>(u, dww, dwu);

    k8_mean<<<HD, 256, 0, stream>>>(outa, meanb);

    k9a<<<288, 256, 0, stream>>>(outa, meanb, scaw, scab, projw, dwu, zbuf, out2z);
    k9b<<<288, 256, 0, stream>>>(out2z, projow, dout, b);
  }
}

// Round 8
// 1471.437 us; speedup vs baseline: 2.8096x; 1.1813x over previous
//
#include <hip/hip_runtime.h>
#include <cstdint>
#include <cstddef>

// ---------------- problem constants ----------------
#define BB   4      // batch
#define CIN  64     // input channels
#define HD   128    // h_dim
#define NH   4      // heads
#define CHW  32     // channels per head
#define CB   8      // channels per branch
#define IMG  192    // H = W
#define SSH  4      // shift
#define NWS  24     // windows per side
#define NWIN 576    // windows total
#define KK   64     // window elements (8x8)
#define HWP  (IMG*IMG)

// per-batch buffer sizes (floats)
static const size_t NQK16  = (size_t)NH*NWIN*KK*16;   // 2,359,296
static const size_t NV32   = (size_t)NH*NWIN*KK*CHW;  // 4,718,592
static const size_t NGR    = (size_t)NH*KK*NWIN*CB;   // 1,179,648
static const size_t NSP    = (size_t)HD*HWP;          // 4,718,592
static const size_t NATTNB = (size_t)NH*NWIN*KK*KK;   // 9,437,184
static const size_t NATTNL = (size_t)NH*NWIN*64;      // 147,456
static const size_t NATTNG = (size_t)NH*KK*64;        // 16,384
static const size_t NATTNR = (size_t)NH*CB*KK*KK;     // 131,072
static const size_t NPART  = (size_t)8*NATTNR;        // 1,048,576

// ---------------- helpers ----------------
__device__ inline float wave_max(float v){
  #pragma unroll
  for (int s=1;s<64;s<<=1) v = fmaxf(v, __shfl_xor(v, s));
  return v;
}
__device__ inline float wave_sum(float v){
  #pragma unroll
  for (int s=1;s<64;s<<=1) v += __shfl_xor(v, s);
  return v;
}
__device__ inline float g8_max(float v){
  v = fmaxf(v, __shfl_xor(v,1)); v = fmaxf(v, __shfl_xor(v,2)); v = fmaxf(v, __shfl_xor(v,4));
  return v;
}
__device__ inline float g8_sum(float v){
  v += __shfl_xor(v,1); v += __shfl_xor(v,2); v += __shfl_xor(v,4);
  return v;
}
__device__ inline int regionc(int y){ return (y < IMG-8) ? 0 : ((y < IMG-4) ? 1 : 2); }

__device__ inline size_t widx(int h,int n,int i,int c){
  return (((size_t)h*NWIN + n)*KK + i)*CHW + c;
}
__device__ inline size_t widx16(int h,int n,int i,int c){
  return (((size_t)h*NWIN + n)*KK + i)*16 + c;
}
__device__ inline size_t gidx(int h,int i,int n,int c){
  return (((size_t)(h*KK + i))*NWIN + n)*CB + c;
}
__device__ inline size_t ridx(int h,int c,int n,int i){
  return (((size_t)(h*CB + c))*NWIN + n)*KK + i;
}

// ---------------- K1: projections, fused single pass ----------------
// grid IMG*12 (16-px tiles), 256 threads.
// waves 0,1 (t<128): q(row t), k(row t), z(row t+256).  waves 2,3: u(row t), v(row t).
__global__ __launch_bounds__(256) void k1_proj(
    const float* __restrict__ x, const float* __restrict__ wquz, const float* __restrict__ wkv,
    float* __restrict__ qw, float* __restrict__ kw, float* __restrict__ vw,
    float* __restrict__ qg, float* __restrict__ kg,
    float* __restrict__ qr, float* __restrict__ kr,
    float* __restrict__ u, float* __restrict__ zbuf, int bsel)
{
  __shared__ float xs[64][16];   // 64B row stride -> aligned b128 reads, broadcast
  int blk = blockIdx.x;
  int xc = blk % 12, y = blk / 12;
  int x0 = xc*16;
  int t = threadIdx.x;
  {
    int c = t >> 2, p4 = (t & 3)*4;
    float4 v = *(const float4*)&x[((size_t)(bsel*CIN+c)*IMG + y)*IMG + x0 + p4];
    *(float4*)&xs[c][p4] = v;
  }
  int py  = (y + IMG - SSH) % IMG;
  int kh  = py & 7, hwq = py >> 3;
  int wwA = ((x0 - SSH + IMG) % IMG) >> 3;
  int wwB = x0 >> 3;
  int wwC = (x0 + 8) >> 3;
  int pnA = hwq*NWS + wwA, pnB = hwq*NWS + wwB, pnC = hwq*NWS + wwC;
  int piA = kh*8 + 4, piB = kh*8, piC = kh*8;
  #define PN_(p) ((p)<4 ? pnA : ((p)<12 ? pnB : pnC))
  #define PI_(p) ((p)<4 ? (piA+(p)) : ((p)<12 ? (piB+(p)-4) : (piC+(p)-12)))
  __syncthreads();

  bool qkz = (t < 128);
  const float* wr1 = wquz + (size_t)t*CIN;
  const float* wr2 = wkv  + (size_t)t*CIN;

  float acc1[16], acc2[16], acc3[16];
  #pragma unroll
  for (int p = 0; p < 16; ++p){ acc1[p]=0.f; acc2[p]=0.f; acc3[p]=0.f; }

  if (qkz){
    const float* wr3 = wquz + (size_t)(t+256)*CIN;
    for (int cc4 = 0; cc4 < 64; cc4 += 4){
      float4 w1 = *(const float4*)(wr1+cc4);
      float4 w2 = *(const float4*)(wr2+cc4);
      float4 w3 = *(const float4*)(wr3+cc4);
      float w1a[4]={w1.x,w1.y,w1.z,w1.w};
      float w2a[4]={w2.x,w2.y,w2.z,w2.w};
      float w3a[4]={w3.x,w3.y,w3.z,w3.w};
      #pragma unroll
      for (int j = 0; j < 4; ++j){
        #pragma unroll
        for (int q = 0; q < 4; ++q){
          float4 xv = *(const float4*)&xs[cc4+j][q*4];
          acc1[q*4+0]+=w1a[j]*xv.x; acc1[q*4+1]+=w1a[j]*xv.y; acc1[q*4+2]+=w1a[j]*xv.z; acc1[q*4+3]+=w1a[j]*xv.w;
          acc2[q*4+0]+=w2a[j]*xv.x; acc2[q*4+1]+=w2a[j]*xv.y; acc2[q*4+2]+=w2a[j]*xv.z; acc2[q*4+3]+=w2a[j]*xv.w;
          acc3[q*4+0]+=w3a[j]*xv.x; acc3[q*4+1]+=w3a[j]*xv.y; acc3[q*4+2]+=w3a[j]*xv.z; acc3[q*4+3]+=w3a[j]*xv.w;
        }
      }
    }
    // q from acc1, k from acc2 (same h,c), z from acc3
    int h = t >> 5, c = t & 31;
    if (c < 16){
      #pragma unroll
      for (int p = 0; p < 16; ++p) qw[widx16(h,PN_(p),PI_(p),c)] = acc1[p];
      #pragma unroll
      for (int p = 0; p < 16; ++p) kw[widx16(h,PN_(p),PI_(p),c)] = acc2[p];
    } else if (c < 24){
      int cg = c - 16;
      #pragma unroll
      for (int p = 0; p < 16; ++p) qg[gidx(h,PI_(p),PN_(p),cg)] = acc1[p];
      #pragma unroll
      for (int p = 0; p < 16; ++p) kg[gidx(h,PI_(p),PN_(p),cg)] = acc2[p];
    } else {
      int cr = c - 24;
      *(float4*)&qr[ridx(h,cr,pnA,piA)]   = make_float4(acc1[0],acc1[1],acc1[2],acc1[3]);
      *(float4*)&qr[ridx(h,cr,pnB,piB)]   = make_float4(acc1[4],acc1[5],acc1[6],acc1[7]);
      *(float4*)&qr[ridx(h,cr,pnB,piB+4)] = make_float4(acc1[8],acc1[9],acc1[10],acc1[11]);
      *(float4*)&qr[ridx(h,cr,pnC,piC)]   = make_float4(acc1[12],acc1[13],acc1[14],acc1[15]);
      *(float4*)&kr[ridx(h,cr,pnA,piA)]   = make_float4(acc2[0],acc2[1],acc2[2],acc2[3]);
      *(float4*)&kr[ridx(h,cr,pnB,piB)]   = make_float4(acc2[4],acc2[5],acc2[6],acc2[7]);
      *(float4*)&kr[ridx(h,cr,pnB,piB+4)] = make_float4(acc2[8],acc2[9],acc2[10],acc2[11]);
      *(float4*)&kr[ridx(h,cr,pnC,piC)]   = make_float4(acc2[12],acc2[13],acc2[14],acc2[15]);
    }
    size_t zb = ((size_t)t*IMG + y)*IMG + x0;
    *(float4*)&zbuf[zb+ 0] = make_float4(acc3[0],acc3[1],acc3[2],acc3[3]);
    *(float4*)&zbuf[zb+ 4] = make_float4(acc3[4],acc3[5],acc3[6],acc3[7]);
    *(float4*)&zbuf[zb+ 8] = make_float4(acc3[8],acc3[9],acc3[10],acc3[11]);
    *(float4*)&zbuf[zb+12] = make_float4(acc3[12],acc3[13],acc3[14],acc3[15]);
  } else {
    for (int cc4 = 0; cc4 < 64; cc4 += 4){
      float4 w1 = *(const float4*)(wr1+cc4);
      float4 w2 = *(const float4*)(wr2+cc4);
      float w1a[4]={w1.x,w1.y,w1.z,w1.w};
      float w2a[4]={w2.x,w2.y,w2.z,w2.w};
      #pragma unroll
      for (int j = 0; j < 4; ++j){
        #pragma unroll
        for (int q = 0; q < 4; ++q){
          float4 xv = *(const float4*)&xs[cc4+j][q*4];
          acc1[q*4+0]+=w1a[j]*xv.x; acc1[q*4+1]+=w1a[j]*xv.y; acc1[q*4+2]+=w1a[j]*xv.z; acc1[q*4+3]+=w1a[j]*xv.w;
          acc2[q*4+0]+=w2a[j]*xv.x; acc2[q*4+1]+=w2a[j]*xv.y; acc2[q*4+2]+=w2a[j]*xv.z; acc2[q*4+3]+=w2a[j]*xv.w;
        }
      }
    }
    int ch = t - 128;
    size_t ub = ((size_t)ch*IMG + y)*IMG + x0;
    *(float4*)&u[ub+ 0] = make_float4(acc1[0],acc1[1],acc1[2],acc1[3]);
    *(float4*)&u[ub+ 4] = make_float4(acc1[4],acc1[5],acc1[6],acc1[7]);
    *(float4*)&u[ub+ 8] = make_float4(acc1[8],acc1[9],acc1[10],acc1[11]);
    *(float4*)&u[ub+12] = make_float4(acc1[12],acc1[13],acc1[14],acc1[15]);
    int h = ch >> 5, c = ch & 31;
    #pragma unroll
    for (int p = 0; p < 16; ++p) vw[widx(h,PN_(p),PI_(p),c)] = acc2[p];
  }
  #undef PN_
  #undef PI_
}

// ---------------- kA umbrella: k3 | k5a | k6a(+g-norm) | k7a | kNr ----------------
// grid 1696 blocks, 256 threads
__global__ __launch_bounds__(256) void kA(
    const float* __restrict__ qw, const float* __restrict__ kw,
    const float* __restrict__ qg, const float* __restrict__ kg,
    const float* __restrict__ qr, const float* __restrict__ kr,
    const float* __restrict__ temp,
    float* __restrict__ attnB, float* __restrict__ attnL,
    float* __restrict__ attnG, float* __restrict__ part,
    float* __restrict__ invqr, float* __restrict__ invkr)
{
  __shared__ __align__(16) char smem[36864];
  int blk = blockIdx.x;
  int t = threadIdx.x;

  if (blk < 576){
    // ---- k3: attn_b = norm(qb)@norm(kb)^T * temp ----
    float (*qs)[64][8] = (float(*)[64][8])smem;
    int wv = t >> 6, j = t & 63;
    int gid = blk*4 + wv;
    int n = gid % NWIN, h = gid / NWIN;
    size_t base = widx16(h,n,j,0);
    float q8[CB], k8[CB];
    float sq = 0.f, sk2 = 0.f;
    #pragma unroll
    for (int c = 0; c < CB; ++c){
      q8[c] = qw[base+c]; sq += q8[c]*q8[c];
      k8[c] = kw[base+c]; sk2 += k8[c]*k8[c];
    }
    float invq = 1.f/fmaxf(sqrtf(sq),1e-12f), invk = 1.f/fmaxf(sqrtf(sk2),1e-12f);
    #pragma unroll
    for (int c = 0; c < CB; ++c){ qs[wv][j][c] = q8[c]*invq; k8[c] *= invk; }
    __syncthreads();
    float tmp = temp[h];
    float* orow = attnB + (size_t)gid*KK*KK;
    for (int i = 0; i < KK; ++i){
      float a = 0.f;
      #pragma unroll
      for (int c = 0; c < CB; ++c) a += qs[wv][i][c]*k8[c];
      orow[(size_t)i*KK + j] = a * tmp;
    }
  } else if (blk < 1152){
    // ---- k5a: attn_l ----
    int b2 = blk - 576;
    float (*qs)[64][8] = (float(*)[64][8])smem;
    float (*ks)[64][8] = (float(*)[64][8])(smem + 8192);
    float (*invqA)[8] = (float(*)[8])(smem + 16384);
    float (*invkA)[8] = (float(*)[8])(smem + 16384 + 128);
    int wv = t >> 6, tl = t & 63;
    int gid = b2*4 + wv;
    int n = gid % NWIN, h = gid / NWIN;
    size_t base = widx16(h,n,tl,8);
    #pragma unroll
    for (int c = 0; c < CB; ++c){ qs[wv][tl][c] = qw[base+c]; ks[wv][tl][c] = kw[base+c]; }
    __syncthreads();
    int c8 = tl & 7, ig = tl >> 3;
    float sq = 0.f, sk2 = 0.f;
    for (int i = ig; i < KK; i += 8){
      float a = qs[wv][i][c8]; sq += a*a;
      float b = ks[wv][i][c8]; sk2 += b*b;
    }
    #pragma unroll
    for (int m = 8; m < 64; m <<= 1){ sq += __shfl_xor(sq,m); sk2 += __shfl_xor(sk2,m); }
    if (tl < 8){ invqA[wv][tl] = 1.f/fmaxf(sqrtf(sq),1e-12f); invkA[wv][tl] = 1.f/fmaxf(sqrtf(sk2),1e-12f); }
    __syncthreads();
    int c = tl >> 3, d = tl & 7;
    float a = 0.f;
    for (int i = 0; i < KK; ++i) a += qs[wv][i][c]*ks[wv][i][d];
    attnL[(size_t)gid*64 + tl] = a * invqA[wv][c] * invkA[wv][d] * temp[NH + h];
  } else if (blk < 1408){
    // ---- k6a: attn_g with fused n-norms ----
    int b2 = blk - 1152;
    int i = b2 & 63, h = b2 >> 6;
    float* sq = (float*)smem;               // 512
    float* sk = sq + 512;                   // 512
    float (*redA)[64] = (float(*)[64])(smem + 4096);
    float (*redQ)[64] = (float(*)[64])(smem + 4096 + 1024);
    float (*redK)[64] = (float(*)[64])(smem + 4096 + 2048);
    size_t base = ((size_t)(h*KK+i))*NWIN*CB;
    int np = t >> 6, cd = t & 63, c = cd >> 3, d = cd & 7;
    float a = 0.f, qs2 = 0.f, ks2 = 0.f;
    for (int n0 = 0; n0 < NWIN; n0 += 64){
      __syncthreads();
      for (int idx = t; idx < 512; idx += 256){
        sq[idx] = qg[base + (size_t)n0*CB + idx];
        sk[idx] = kg[base + (size_t)n0*CB + idx];
      }
      __syncthreads();
      for (int nn = np; nn < 64; nn += 4){
        float qv = sq[nn*8+c], kv = sk[nn*8+d];
        a += qv*kv; qs2 += qv*qv; ks2 += kv*kv;
      }
    }
    __syncthreads();
    redA[np][cd] = a; redQ[np][cd] = qs2; redK[np][cd] = ks2;
    __syncthreads();
    if (t < 64){
      float at = redA[0][t]+redA[1][t]+redA[2][t]+redA[3][t];
      float qt = redQ[0][t]+redQ[1][t]+redQ[2][t]+redQ[3][t];
      float kt = redK[0][t]+redK[1][t]+redK[2][t]+redK[3][t];
      at *= (1.f/fmaxf(sqrtf(qt),1e-12f)) * (1.f/fmaxf(sqrtf(kt),1e-12f)) * temp[2*NH + h];
      attnG[(size_t)(h*KK+i)*64 + t] = at;
    }
  } else if (blk < 1664){
    // ---- k7a: r-branch Gram partials ----
    int b2 = blk - 1408;
    int chunk = b2 >> 5, hc = b2 & 31;
    int n0 = chunk*72;
    float* sq = (float*)smem;               // 72*64
    float* sk = sq + 72*64;
    size_t base = (size_t)hc*NWIN*KK + (size_t)n0*KK;
    for (int idx = t; idx < 72*64/4; idx += 256){
      *(float4*)&sq[idx*4] = *(const float4*)&qr[base + (size_t)idx*4];
      *(float4*)&sk[idx*4] = *(const float4*)&kr[base + (size_t)idx*4];
    }
    __syncthreads();
    int j = t & 63, ig = t >> 6;
    float acc[16];
    #pragma unroll
    for (int p = 0; p < 16; ++p) acc[p] = 0.f;
    for (int nn = 0; nn < 72; ++nn){
      float kv = sk[nn*64+j];
      #pragma unroll
      for (int p = 0; p < 16; ++p) acc[p] += sq[nn*64 + ig*16 + p]*kv;
    }
    float* ob = part + (size_t)b2*4096;
    #pragma unroll
    for (int p = 0; p < 16; ++p) ob[(size_t)(ig*16+p)*64 + j] = acc[p];
  } else {
    // ---- kNr: inverse L2 norms for r-branch ----
    int hc = blk - 1664;
    float (*rq)[64] = (float(*)[64])smem;
    float (*rk)[64] = (float(*)[64])(smem + 1024);
    size_t base = (size_t)hc*NWIN*KK;
    int i = t & 63, ng = t >> 6;
    float sq = 0.f, sk2 = 0.f;
    for (int n = ng; n < NWIN; n += 4){
      float a = qr[base + (size_t)n*KK + i]; sq  += a*a;
      float b = kr[base + (size_t)n*KK + i]; sk2 += b*b;
    }
    rq[ng][i] = sq; rk[ng][i] = sk2;
    __syncthreads();
    if (t < 64){
      float s = rq[0][t]+rq[1][t]+rq[2][t]+rq[3][t];
      invqr[hc*KK + t] = 1.f/fmaxf(sqrtf(s),1e-12f);
    } else if (t < 128){
      int i2 = t - 64;
      float s = rk[0][i2]+rk[1][i2]+rk[2][i2]+rk[3][i2];
      invkr[hc*KK + i2] = 1.f/fmaxf(sqrtf(s),1e-12f);
    }
  }
}

// ---------------- kB umbrella: k4 | k5b | k6b | kRed | k_dw ----------------
// grid 16512 blocks, 256 threads
__global__ __launch_bounds__(256) void kB(
    const float* __restrict__ attnB, const float* __restrict__ btw,
    const float* __restrict__ vw, float* __restrict__ outa,
    const float* __restrict__ attnL, const float* __restrict__ ltw,
    const float* __restrict__ attnG, const float* __restrict__ gtalk,
    float* __restrict__ attnGp,
    const float* __restrict__ part, const float* __restrict__ invqr,
    const float* __restrict__ invkr, const float* __restrict__ temp,
    float* __restrict__ attnR,
    const float* __restrict__ u, const float* __restrict__ dww,
    float* __restrict__ dwu)
{
  __shared__ __align__(16) char smem[49536];
  int blk = blockIdx.x;
  int t = threadIdx.x;

  if (blk < 9216){
    // ---- k4: b-branch talk-conv + mask + softmax + PV ----
    float (*rows)[9][4][64] = (float(*)[9][4][64])smem;      // 36864B
    float (*pbuf)[4][66]    = (float(*)[4][66])(smem + 36864);  // 4224B
    float (*vv)[8][66]      = (float(*)[8][66])(smem + 36864 + 4224); // 8448B
    int ig = blk / NWIN, n = blk % NWIN;
    int i0 = ig*4;
    int hw = n / NWS, ww = n % NWS;
    int w = t >> 6, l = t & 63;
    {
      int li = l >> 4, j4 = (l & 15)*4;
      #pragma unroll
      for (int nb = 0; nb < 9; ++nb){
        const int dy = nb/3 - 1, dx = nb%3 - 1;
        int hw2 = hw + dy, ww2 = ww + dx;
        float4 v = {0.f,0.f,0.f,0.f};
        if (hw2 >= 0 && hw2 < NWS && ww2 >= 0 && ww2 < NWS){
          int n2 = hw2*NWS + ww2;
          v = *(const float4*)&attnB[((size_t)(w*NWIN + n2)*KK + i0 + li)*KK + j4];
        }
        *(float4*)&rows[w][nb][li][j4] = v;
      }
    }
    {
      size_t vb = widx(w, n, l, 0);
      float4 va = *(const float4*)&vw[vb];
      float4 vb4 = *(const float4*)&vw[vb + 4];
      vv[w][0][l] = va.x;  vv[w][1][l] = va.y;  vv[w][2][l] = va.z;  vv[w][3][l] = va.w;
      vv[w][4][l] = vb4.x; vv[w][5][l] = vb4.y; vv[w][6][l] = vb4.z; vv[w][7][l] = vb4.w;
    }
    __syncthreads();
    int i = i0 + w;
    float a0 = 0.f, a1 = 0.f, a2 = 0.f, a3 = 0.f;
    #pragma unroll
    for (int h = 0; h < 4; ++h){
      #pragma unroll
      for (int nb = 0; nb < 9; ++nb){
        float r = rows[h][nb][w][l];
        a0 += btw[(0*4 + h)*9 + nb] * r;
        a1 += btw[(1*4 + h)*9 + nb] * r;
        a2 += btw[(2*4 + h)*9 + nb] * r;
        a3 += btw[(3*4 + h)*9 + nb] * r;
      }
    }
    int kh = i >> 3, kwd = i & 7;
    int cntI = regionc(hw*8 + kh)*3 + regionc(ww*8 + kwd);
    int cntJ = regionc(hw*8 + (l>>3))*3 + regionc(ww*8 + (l&7));
    float mval = (cntI != cntJ) ? -100.f : 0.f;
    a0 += mval; a1 += mval; a2 += mval; a3 += mval;
    {
      float m0 = wave_max(a0); float e0 = __expf(a0 - m0); pbuf[0][w][l] = e0 / wave_sum(e0);
      float m1 = wave_max(a1); float e1 = __expf(a1 - m1); pbuf[1][w][l] = e1 / wave_sum(e1);
      float m2 = wave_max(a2); float e2 = __expf(a2 - m2); pbuf[2][w][l] = e2 / wave_sum(e2);
      float m3 = wave_max(a3); float e3 = __expf(a3 - m3); pbuf[3][w][l] = e3 / wave_sum(e3);
    }
    __syncthreads();
    {
      int i2 = l >> 4, c = (l >> 1) & 7, jq = l & 1;
      const float* pr = &pbuf[w][i2][jq*32];
      const float* vr = &vv[w][c][jq*32];
      float s = 0.f;
      #pragma unroll
      for (int q = 0; q < 32; ++q) s += pr[q] * vr[q];
      s += __shfl_xor(s, 1);
      if (jq == 0){
        int ii = i0 + i2;
        int khh = ii >> 3, kww = ii & 7;
        int Y = (hw*8 + khh + SSH) % IMG;
        int X = (ww*8 + kww + SSH) % IMG;
        outa[((size_t)(w*CB + c)*HWP) + (size_t)Y*IMG + X] = s;
      }
    }
  } else if (blk < 9792){
    // ---- k5b: l-branch talk-conv + softmax(d) + PV ----
    int n = blk - 9216;
    int hw = n/NWS, ww = n%NWS;
    float (*rows)[9][64] = (float(*)[9][64])smem;         // 9216B
    float* wt = (float*)(smem + 9216);                    // 576B
    float (*P)[8][8] = (float(*)[8][8])(smem + 9792);     // 1024B
    if (t < NH*NH*9) wt[t] = ltw[t];
    for (int l = t; l < NH*9*64; l += 256){
      int h = l/(9*64); int nb = (l/64)%9; int cd = l & 63;
      int dy = nb/3-1, dx = nb%3-1; int hw2 = hw+dy, ww2 = ww+dx;
      float v = 0.f;
      if (hw2>=0 && hw2<NWS && ww2>=0 && ww2<NWS)
        v = attnL[((size_t)h*NWIN + hw2*NWS + ww2)*64 + cd];
      rows[h][nb][cd] = v;
    }
    __syncthreads();
    int tt = t >> 6; int cd = t & 63; int c = cd >> 3, d = cd & 7;
    float a = 0.f;
    #pragma unroll
    for (int h = 0; h < NH; ++h)
      #pragma unroll
      for (int nb = 0; nb < 9; ++nb)
        a += wt[(tt*NH + h)*9 + nb] * rows[h][nb][cd];
    float m = g8_max(a);
    float e = __expf(a - m);
    P[tt][c][d] = e / g8_sum(e);
    __syncthreads();
    int i = t & 63;
    size_t vbase = widx(tt, n, i, 8);
    float vl[CB];
    #pragma unroll
    for (int d2 = 0; d2 < CB; ++d2) vl[d2] = vw[vbase + d2];
    int kh = i>>3, kwd = i&7;
    int Y = (hw*8+kh+SSH)%IMG, X = (ww*8+kwd+SSH)%IMG;
    #pragma unroll
    for (int c2 = 0; c2 < CB; ++c2){
      float o = 0.f;
      #pragma unroll
      for (int d2 = 0; d2 < CB; ++d2) o += P[tt][c2][d2]*vl[d2];
      outa[((size_t)(32 + tt*CB + c2)*IMG + Y)*IMG + X] = o;
    }
  } else if (blk < 9856){
    // ---- k6b: g talking + softmax(d), one (t2,l) per wave ----
    int bb = blk - 9792;
    int w = t >> 6, cd = t & 63;
    int idx = bb*4 + w;
    int l = idx & 63, t2 = idx >> 6;
    float a = 0.f;
    for (int h = 0; h < NH; ++h)
      for (int k = 0; k < KK; ++k)
        a += gtalk[((size_t)(h*KK + k)*KK + l)*NH + t2] * attnG[((size_t)h*KK + k)*64 + cd];
    float m = g8_max(a);
    float e = __expf(a - m);
    attnGp[((size_t)t2*KK + l)*64 + cd] = e / g8_sum(e);
  } else if (blk < 10368){
    // ---- kRed ----
    int e = (blk - 9856)*256 + t;
    float s = 0.f;
    #pragma unroll
    for (int ch = 0; ch < 8; ++ch) s += part[(size_t)ch*NATTNR + e];
    int hc = e >> 12, ij = e & 4095, i = ij >> 6, j = ij & 63;
    attnR[e] = s * invqr[hc*64+i] * invkr[hc*64+j] * temp[3*NH + (hc>>3)];
  } else {
    // ---- k_dw: depthwise 3x3 ----
    int bb = blk - 10368;
    int ch = bb / 48; int y0 = (bb % 48) * 4;
    float (*rows)[192] = (float(*)[192])smem;   // 4608B
    for (int idx = t; idx < 6*48; idx += 256){
      int r = idx / 48, px4 = (idx % 48)*4;
      int yy = y0 - 1 + r;
      float4 v = {0.f,0.f,0.f,0.f};
      if (yy >= 0 && yy < IMG) v = *(const float4*)&u[(size_t)ch*HWP + (size_t)yy*IMG + px4];
      rows[r][px4] = v.x; rows[r][px4+1] = v.y; rows[r][px4+2] = v.z; rows[r][px4+3] = v.w;
    }
    float kw9[9];
    #pragma unroll
    for (int q = 0; q < 9; ++q) kw9[q] = dww[ch*9 + q];
    __syncthreads();
    int r = t >> 6, lane = t & 63;
    for (int kx = 0; kx < 3; ++kx){
      int px = lane + kx*64;
      float s = 0.f;
      #pragma unroll
      for (int dy = 0; dy < 3; ++dy){
        #pragma unroll
        for (int dx = -1; dx <= 1; ++dx){
          int xx = px + dx;
          if (xx >= 0 && xx < IMG) s += kw9[dy*3 + dx + 1] * rows[r+dy][xx];
        }
      }
      dwu[(size_t)ch*HWP + (size_t)(y0+r)*IMG + px] = s;
    }
  }
}

// ---------------- kC umbrella: k6c | k7b ----------------
// grid 2336 blocks, 256 threads
__global__ __launch_bounds__(256) void kC(
    const float* __restrict__ attnGp, const float* __restrict__ vw,
    float* __restrict__ outa,
    const float* __restrict__ attnR, const float* __restrict__ rtalk,
    float* __restrict__ attnRp)
{
  __shared__ __align__(16) char smem[16512];
  int blk = blockIdx.x;
  int t = threadIdx.x;

  if (blk < 2304){
    // ---- k6c: out_g PV ----
    float* P = (float*)smem;   // 4096 floats
    int n = blk % NWIN; int t2 = blk / NWIN;
    for (int l = t; l < KK*64; l += 256) P[l] = attnGp[(size_t)t2*KK*64 + l];
    __syncthreads();
    int i = t >> 2; int c0 = (t & 3)*2;
    size_t vbase = widx(t2, n, i, 16);
    float vg[8];
    #pragma unroll
    for (int d = 0; d < 8; ++d) vg[d] = vw[vbase + d];
    int hw = n/NWS, ww = n%NWS; int kh = i>>3, kwd = i&7;
    int Y = (hw*8+kh+SSH)%IMG, X = (ww*8+kwd+SSH)%IMG;
    for (int c = c0; c < c0+2; ++c){
      float o = 0.f;
      #pragma unroll
      for (int d = 0; d < 8; ++d) o += P[(i*8 + c)*8 + d]*vg[d];
      outa[((size_t)(64 + t2*CB + c)*IMG + Y)*IMG + X] = o;
    }
  } else {
    // ---- k7b: r talking + softmax(j) ----
    int bb = blk - 2304;
    int d = bb % CB; int t2 = bb / CB;
    float (*S)[64] = (float(*)[64])smem;          // 16384B
    float* wr2 = (float*)(smem + 16384);          // 128B
    if (t < 32){ int h = t >> 3, c = t & 7; wr2[t] = rtalk[((size_t)(h*CB + c)*CB + d)*NH + t2]; }
    __syncthreads();
    int j = t & 63; int ig = t >> 6;
    float acc[16];
    #pragma unroll
    for (int p = 0; p < 16; ++p) acc[p] = 0.f;
    for (int hc = 0; hc < 32; ++hc){
      float w = wr2[hc];
      const float* Ar = attnR + (size_t)hc*KK*KK;
      #pragma unroll
      for (int p = 0; p < 16; ++p) acc[p] += w * Ar[(size_t)(ig*16+p)*KK + j];
    }
    #pragma unroll
    for (int p = 0; p < 16; ++p) S[ig*16+p][j] = acc[p];
    __syncthreads();
    for (int r = ig; r < 64; r += 4){
      float a = S[r][j];
      float m = wave_max(a);
      float e = __expf(a - m);
      attnRp[(((size_t)t2*CB + d)*KK + r)*KK + j] = e / wave_sum(e);
    }
  }
}

// ---------------- K7c: out_r PV ----------------
__global__ __launch_bounds__(256) void k7c(
    const float* __restrict__ attnRp, const float* __restrict__ vw, float* __restrict__ outa)
{
  int n = blockIdx.x % NWIN; int t2 = blockIdx.x / NWIN;
  __shared__ float vr[KK][CB];
  int t = threadIdx.x;
  for (int l = t; l < KK*CB; l += 256){
    int j = l >> 3, c = l & 7;
    vr[j][c] = vw[widx(t2, n, j, 24 + c)];
  }
  __syncthreads();
  int i = t & 63; int cg = t >> 6;
  int hw = n/NWS, ww = n%NWS; int kh = i>>3, kwd = i&7;
  int Y = (hw*8+kh+SSH)%IMG, X = (ww*8+kwd+SSH)%IMG;
  for (int c = cg*2; c < cg*2+2; ++c){
    const float* Pr = attnRp + (((size_t)t2*CB + c)*KK + i)*KK;
    float o = 0.f;
    for (int j = 0; j < KK; ++j) o += Pr[j]*vr[j][c];
    outa[((size_t)(96 + t2*CB + c)*IMG + Y)*IMG + X] = o;
  }
}

// ---------------- K8: channel means ----------------
__global__ __launch_bounds__(256) void k8_mean(const float* __restrict__ outa, float* __restrict__ meanb){
  int ch = blockIdx.x;
  const float4* p = (const float4*)(outa + (size_t)ch*HWP);
  float s = 0.f;
  for (int l = threadIdx.x; l < HWP/4; l += 256){
    float4 v = p[l]; s += v.x+v.y+v.z+v.w;
  }
  __shared__ float red[256];
  red[threadIdx.x] = s; __syncthreads();
  for (int k = 128; k > 0; k >>= 1){
    if (threadIdx.x < k) red[threadIdx.x] += red[threadIdx.x + k];
    __syncthreads();
  }
  if (threadIdx.x == 0) meanb[ch] = red[0] / (float)HWP;
}

// ---------------- K9a: out2z = (projw @ (outa*svec) + dwu) * zbuf ----------------
#define PADX 68
__global__ __launch_bounds__(256) void k9a(
    const float* __restrict__ outa, const float* __restrict__ meanb,
    const float* __restrict__ scaw, const float* __restrict__ scab,
    const float* __restrict__ projw, const float* __restrict__ dwu,
    const float* __restrict__ zbuf, float* __restrict__ out2z)
{
  __shared__ float WT[128][128];
  __shared__ float xsv[128][PADX];
  __shared__ float sv[128];
  int t = threadIdx.x;
  if (t < 128){
    float s = scab[t];
    const float* srow = scaw + (size_t)t*HD;
    for (int c = 0; c < HD; c += 4){
      float4 w = *(const float4*)&srow[c];
      float4 mm = *(const float4*)&meanb[c];
      s += w.x*mm.x + w.y*mm.y + w.z*mm.z + w.w*mm.w;
    }
    sv[t] = s;
  }
  for (int idx = t; idx < 4096; idx += 256){
    int o = idx & 127; int c4 = (idx >> 7) * 4;
    float4 w = *(const float4*)&projw[(size_t)o*HD + c4];
    WT[c4][o] = w.x; WT[c4+1][o] = w.y; WT[c4+2][o] = w.z; WT[c4+3][o] = w.w;
  }
  int px4 = (t & 15) * 4; int og8 = (t >> 4) * 8;
  for (int tile = 0; tile < 2; ++tile){
    int tid = blockIdx.x * 2 + tile;
    int y = tid / 3, x0 = (tid % 3) * 64;
    size_t sb = (size_t)y*IMG + x0;
    __syncthreads();
    for (int idx = t; idx < 2048; idx += 256){
      int c = idx >> 4; int p4 = (idx & 15) * 4;
      float4 v = *(const float4*)&outa[(size_t)c*HWP + sb + p4];
      float s = sv[c];
      xsv[c][p4] = v.x*s; xsv[c][p4+1] = v.y*s; xsv[c][p4+2] = v.z*s; xsv[c][p4+3] = v.w*s;
    }
    __syncthreads();
    float acc[8][4];
    #pragma unroll
    for (int a = 0; a < 8; ++a){ acc[a][0]=0.f; acc[a][1]=0.f; acc[a][2]=0.f; acc[a][3]=0.f; }
    for (int c = 0; c < 128; ++c){
      float4 xv = *(const float4*)&xsv[c][px4];
      float4 wA = *(const float4*)&WT[c][og8];
      float4 wB = *(const float4*)&WT[c][og8+4];
      float w8[8] = {wA.x,wA.y,wA.z,wA.w,wB.x,wB.y,wB.z,wB.w};
      #pragma unroll
      for (int a = 0; a < 8; ++a){
        acc[a][0] += w8[a]*xv.x; acc[a][1] += w8[a]*xv.y;
        acc[a][2] += w8[a]*xv.z; acc[a][3] += w8[a]*xv.w;
      }
    }
    #pragma unroll
    for (int oo = 0; oo < 8; ++oo){
      int o = og8 + oo;
      size_t off = (size_t)o*HWP + sb + px4;
      float4 d = *(const float4*)&dwu[off];
      float4 z = *(const float4*)&zbuf[off];
      float4 r;
      r.x = (acc[oo][0]+d.x)*z.x; r.y = (acc[oo][1]+d.y)*z.y;
      r.z = (acc[oo][2]+d.z)*z.z; r.w = (acc[oo][3]+d.w)*z.w;
      *(float4*)&out2z[off] = r;
    }
  }
}

// ---------------- K9b: dout = projow @ out2z ----------------
__global__ __launch_bounds__(256) void k9b(
    const float* __restrict__ out2z, const float* __restrict__ projow,
    float* __restrict__ dout, int bsel)
{
  __shared__ float WT2[128][64];
  __shared__ float xsv[128][PADX];
  int t = threadIdx.x;
  for (int idx = t; idx < 2048; idx += 256){
    int o = idx & 63; int c4 = (idx >> 6) * 4;
    float4 w = *(const float4*)&projow[(size_t)o*HD + c4];
    WT2[c4][o] = w.x; WT2[c4+1][o] = w.y; WT2[c4+2][o] = w.z; WT2[c4+3][o] = w.w;
  }
  int px4 = (t & 15) * 4; int og4 = (t >> 4) * 4;
  for (int tile = 0; tile < 2; ++tile){
    int tid = blockIdx.x * 2 + tile;
    int y = tid / 3, x0 = (tid % 3) * 64;
    size_t sb = (size_t)y*IMG + x0;
    __syncthreads();
    for (int idx = t; idx < 2048; idx += 256){
      int c = idx >> 4; int p4 = (idx & 15) * 4;
      float4 v = *(const float4*)&out2z[(size_t)c*HWP + sb + p4];
      xsv[c][p4] = v.x; xsv[c][p4+1] = v.y; xsv[c][p4+2] = v.z; xsv[c][p4+3] = v.w;
    }
    __syncthreads();
    float acc[4][4];
    #pragma unroll
    for (int a = 0; a < 4; ++a){ acc[a][0]=0.f; acc[a][1]=0.f; acc[a][2]=0.f; acc[a][3]=0.f; }
    for (int c = 0; c < 128; ++c){
      float4 xv = *(const float4*)&xsv[c][px4];
      float4 w4 = *(const float4*)&WT2[c][og4];
      float w4a[4] = {w4.x,w4.y,w4.z,w4.w};
      #pragma unroll
      for (int a = 0; a < 4; ++a){
        acc[a][0] += w4a[a]*xv.x; acc[a][1] += w4a[a]*xv.y;
        acc[a][2] += w4a[a]*xv.z; acc[a][3] += w4a[a]*xv.w;
      }
    }
    #pragma unroll
    for (int oo = 0; oo < 4; ++oo){
      int o = og4 + oo;
      float4 r; r.x = acc[oo][0]; r.y = acc[oo][1]; r.z = acc[oo][2]; r.w = acc[oo][3];
      *(float4*)&dout[(size_t)(bsel*CIN + o)*HWP + sb + px4] = r;
    }
  }
}

// ---------------- launch ----------------
extern "C" void kernel_launch(void* const* d_in, const int* in_sizes, int n_in,
                              void* d_out, int out_size, void* d_ws, size_t ws_size,
                              hipStream_t stream)
{
  const float* x     = (const float*)d_in[0];
  const float* wquz  = (const float*)d_in[1];
  const float* wkv   = (const float*)d_in[2];
  const float* temp  = (const float*)d_in[3];
  const float* rtalk = (const float*)d_in[4];
  const float* gtalk = (const float*)d_in[5];
  const float* btw   = (const float*)d_in[6];
  const float* ltw   = (const float*)d_in[7];
  const float* dww   = (const float*)d_in[8];
  const float* projw = (const float*)d_in[9];
  const float* projow= (const float*)d_in[10];
  const float* scaw  = (const float*)d_in[11];
  const float* scab  = (const float*)d_in[12];
  float* dout = (float*)d_out;

  float* ws = (float*)d_ws;
  float* qw    = ws;                  // NQK16
  float* kw    = qw + NQK16;          // NQK16
  float* vw    = kw + NQK16;          // NV32
  float* qg    = vw + NV32;           // NGR
  float* kg    = qg + NGR;            // NGR
  float* qr    = kg + NGR;            // NGR
  float* kr    = qr + NGR;            // NGR
  float* u     = kr + NGR;            // NSP
  float* zbuf  = u + NSP;             // NSP
  float* outa  = zbuf + NSP;          // NSP
  float* attnB = outa + NSP;          // NATTNB (aliased by dwu/out2z after kB's k4)
  float* dwu   = attnB;               // NSP alias
  float* out2z = attnB + NSP;         // NSP alias
  float* attnL = attnB + NATTNB;      // NATTNL
  float* attnG = attnL + NATTNL;      // NATTNG
  float* attnGp= attnG + NATTNG;      // NATTNG
  float* part  = attnGp + NATTNG;     // NPART
  float* attnR = part + NPART;        // NATTNR
  float* attnRp= attnR + NATTNR;      // NATTNR
  float* invqr = attnRp + NATTNR;     // 2048
  float* invkr = invqr + 2048;        // 2048
  float* meanb = invkr + 2048;        // 128

  for (int b = 0; b < BB; ++b){
    k1_proj<<<IMG*12, 256, 0, stream>>>(x, wquz, wkv, qw, kw, vw, qg, kg, qr, kr, u, zbuf, b);

    kA<<<1696, 256, 0, stream>>>(qw, kw, qg, kg, qr, kr, temp,
                                 attnB, attnL, attnG, part, invqr, invkr);

    // NOTE: kB's k_dw writes dwu which aliases attnB — but k4 (same kernel) reads attnB.
    // dwu = attnB base, k_dw blocks may run before/with k4 blocks -> RACE. Avoid: dwu moved to out2z+NSP region? No:
    // keep safe by pointing dwu at a non-aliased scratch after attnRp instead.
    kB<<<16512, 256, 0, stream>>>(attnB, btw, vw, outa, attnL, ltw,
                                  attnG, gtalk, attnGp, part, invqr, invkr, temp, attnR,
                                  u, dww, out2z /*dwu: use out2z region (free until k9a)*/);

    kC<<<2336, 256, 0, stream>>>(attnGp, vw, outa, attnR, rtalk, attnRp);

    k7c<<<NH*NWIN, 256, 0, stream>>>(attnRp, vw, outa);

    k8_mean<<<HD, 256, 0, stream>>>(outa, meanb);

    k9a<<<288, 256, 0, stream>>>(outa, meanb, scaw, scab, projw, out2z /*dwu*/, zbuf, dwu /*out2z -> attnB region, free now*/);
    k9b<<<288, 256, 0, stream>>>(dwu /*out2z*/, projow, dout, b);
  }
}